// Round 1
// baseline (2888.447 us; speedup 1.0000x reference)
//
#include <hip/hip_runtime.h>
#include <cmath>

#define L2PI 1.8378770664093453f

// 255 per-step backward-gain matrices (G_t), written and re-read by the SAME
// thread within one kernel launch (no cross-call state: fully overwritten
// before being read on every call).
__device__ float g_Gstore[255 * 256];

__device__ __forceinline__ float dAB(const float* A, const float* B, int i, int j) {
  float s = 0.f;
#pragma unroll
  for (int k = 0; k < 16; ++k) s = fmaf(A[i * 16 + k], B[k * 16 + j], s);
  return s;
}
__device__ __forceinline__ float dATB(const float* A, const float* B, int i, int j) {
  float s = 0.f;
#pragma unroll
  for (int k = 0; k < 16; ++k) s = fmaf(A[k * 16 + i], B[k * 16 + j], s);
  return s;
}
__device__ __forceinline__ float dABT(const float* A, const float* B, int i, int j) {
  float s = 0.f;
#pragma unroll
  for (int k = 0; k < 16; ++k) s = fmaf(A[i * 16 + k], B[j * 16 + k], s);
  return s;
}
__device__ __forceinline__ float wave_sum(float v) {
#pragma unroll
  for (int off = 32; off; off >>= 1) v += __shfl_down(v, off);
  return v;
}

// Gauss-Jordan inverse of SPD 16x16 (no pivoting; pivots are positive for SPD).
// Writes inverse to dst (may be nullptr), log|det| to *ldout (thread 0).
__device__ void gj_inv(const float* __restrict__ src, float* dst, float* aug,
                       float* ldout, int e) {
  const int i = e >> 4, j = e & 15;
  aug[i * 33 + j] = src[i * 16 + j];
  aug[i * 33 + 16 + j] = (i == j) ? 1.f : 0.f;
  __syncthreads();
  float ldsum = 0.f;
  for (int k = 0; k < 16; ++k) {
    const float piv = aug[k * 33 + k];
    const float rp = 1.f / piv;
    const float aik = aug[i * 33 + k];
    const float a1 = aug[i * 33 + j];
    const float a2 = aug[i * 33 + 16 + j];
    const float p1 = aug[k * 33 + j];
    const float p2 = aug[k * 33 + 16 + j];
    __syncthreads();
    if (i == k) {
      aug[i * 33 + j] = p1 * rp;
      aug[i * 33 + 16 + j] = p2 * rp;
    } else {
      const float f = aik * rp;
      aug[i * 33 + j] = fmaf(-f, p1, a1);
      aug[i * 33 + 16 + j] = fmaf(-f, p2, a2);
    }
    if (e == 0) ldsum += logf(piv);
    __syncthreads();
  }
  if (e == 0) *ldout = ldsum;
  if (dst) dst[e] = aug[i * 33 + 16 + j];
  __syncthreads();
}

__global__ void __launch_bounds__(256)
lgq_kernel(const float* __restrict__ obs,
           const float* __restrict__ ppm, const float* __restrict__ ppc,
           const float* __restrict__ ptw, const float* __restrict__ ptb,
           const float* __restrict__ ptc, const float* __restrict__ pew,
           const float* __restrict__ peb, const float* __restrict__ pec,
           const float* __restrict__ qpm, const float* __restrict__ qpc,
           const float* __restrict__ qtw, const float* __restrict__ qtb,
           const float* __restrict__ qtc, const float* __restrict__ qew,
           const float* __restrict__ qeb, const float* __restrict__ qec,
           float* __restrict__ out) {
  const int e = threadIdx.x;
  const int i = e >> 4, j = e & 15;

  // fixed matrices
  __shared__ float W[256], Qm[256], Hm[256], Rm[256], Em[256], Pwm[256];
  __shared__ float Om0[256], Omo[256], Omt[256], Fo[256], Ft[256], Nm[256], EOm[256];
  // state
  __shared__ float Pf[256], Sm[256];
  // temps
  __shared__ float WP[256], Ppred[256], Pi[256], Gm[256], bcovm[256], Mm[256];
  __shared__ float T1[256], NG[256], HPm[256], Smat[256], Si[256], Kgm[256], Tmp[256];
  __shared__ float aug[16 * 33];
  __shared__ float mf[16], rv[16], pb[16], bqv[16], bemv[16], pbemv[16], ptbv[16];
  __shared__ float w2[16], q2[16], mpred[16], av[16], Mav[16], hv[16], vv[16], Nav[16];
  __shared__ float EOpb[16], Opb[16], resid[16], tv1[16], tv2[16];
  __shared__ float red[4];
  __shared__ float sc_const, sc_c, ctb, tr_sum;
  __shared__ float ld_pprior, ld_ptr, ld_pem, ld_Q, ld_R, ld_qprior;
  __shared__ float ld_Ppred, ld_Smat, ld_Pf;

  // ---- load fixed inputs ----
  W[e] = qtw[e]; Qm[e] = qtc[e]; Hm[e] = qew[e]; Rm[e] = qec[e];
  Em[e] = pew[e]; Pwm[e] = ptw[e];
  if (e < 16) { bqv[e] = qtb[e]; bemv[e] = qeb[e]; pbemv[e] = peb[e]; ptbv[e] = ptb[e]; }
  __syncthreads();

  // ---- inverses / log-dets of fixed covariances ----
  gj_inv(ppc, Tmp, aug, &ld_pprior, e);
  Om0[e] = -0.5f * Tmp[e];
  __syncthreads();
  gj_inv(ptc, Tmp, aug, &ld_ptr, e);
  Omt[e] = -0.5f * Tmp[e];
  __syncthreads();
  gj_inv(pec, Tmp, aug, &ld_pem, e);
  Omo[e] = -0.5f * Tmp[e];
  __syncthreads();
  gj_inv(qtc, nullptr, aug, &ld_Q, e);
  gj_inv(qec, nullptr, aug, &ld_R, e);
  gj_inv(qpc, nullptr, aug, &ld_qprior, e);

  // ---- derived fixed products ----
  Tmp[e] = dAB(Omo, Em, i, j);    // Omo*E
  Nm[e] = dAB(Omt, Pwm, i, j);    // N = Omt*Pw
  EOm[e] = dATB(Em, Omo, i, j);   // E^T*Omo
  __syncthreads();
  Fo[e] = dATB(Em, Tmp, i, j);    // F_obs = E^T Omo E
  Ft[e] = dATB(Pwm, Nm, i, j);    // F_tr  = Pw^T Omt Pw
  if (e < 16) {
    float s = 0.f, s2 = 0.f;
#pragma unroll
    for (int k = 0; k < 16; ++k) {
      s = fmaf(Nm[k * 16 + e], ptbv[k], s);    // w2 = N^T ptb
      s2 = fmaf(Omt[e * 16 + k], ptbv[k], s2); // q2 = Omt ptb
    }
    w2[e] = s; q2[e] = s2;
  }
  __syncthreads();
  // ---- init state (slot 0) ----
  Sm[e] = Om0[e];
  if (e < 16) {
    float s = 0.f;
#pragma unroll
    for (int k = 0; k < 16; ++k) s = fmaf(Om0[e * 16 + k], ppm[k], s);
    rv[e] = -s;                 // r = -Om0 * p_prior_mean
    pb[e] = pbemv[e] - obs[e];  // pend_b = p_em_b - y0
  }
  __syncthreads();
  if (e == 0) {
    float cc = 0.f, ct = 0.f;
    for (int k = 0; k < 16; ++k) { cc = fmaf(ppm[k], rv[k], cc); ct = fmaf(ptbv[k], q2[k], ct); }
    sc_c = -cc;      // c = pm^T Om0 pm
    ctb = ct;        // ptb^T Omt ptb
    tr_sum = 0.f;
    sc_const = -0.5f * (16.f * L2PI + ld_pprior) - 0.5f * (16.f * L2PI + ld_pem);
  }
  // ---- initial Kalman update (P_pred = q_prior_cov) ----
  Ppred[e] = qpc[e];
  if (e < 16) mpred[e] = qpm[e];
  __syncthreads();
  HPm[e] = dAB(Hm, Ppred, i, j);
  __syncthreads();
  Smat[e] = dABT(HPm, Hm, i, j) + Rm[e];
  __syncthreads();
  gj_inv(Smat, Si, aug, &ld_Smat, e);
  Kgm[e] = dATB(HPm, Si, i, j);   // Kg = HP^T Si
  if (e < 16) {
    float s = 0.f;
#pragma unroll
    for (int k = 0; k < 16; ++k) s = fmaf(Hm[e * 16 + k], mpred[k], s);
    resid[e] = obs[e] - s - bemv[e];
  }
  __syncthreads();
  Pf[e] = Ppred[e] - dAB(Kgm, HPm, i, j);
  if (e < 16) {
    float s = mpred[e];
#pragma unroll
    for (int k = 0; k < 16; ++k) s = fmaf(Kgm[e * 16 + k], resid[k], s);
    mf[e] = s;
  }
  if (e == 0) ld_Pf = ld_qprior + ld_R - ld_Smat;
  __syncthreads();

  // ---- forward scan t = 1..255 ----
  for (int t = 1; t < 256; ++t) {
    const float* y = obs + t * 16;
    // S1: WP = W*Pf ; m_pred = W*mf + bq
    WP[e] = dAB(W, Pf, i, j);
    if (e < 16) {
      float s = bqv[e];
#pragma unroll
      for (int k = 0; k < 16; ++k) s = fmaf(W[e * 16 + k], mf[k], s);
      mpred[e] = s;
    }
    __syncthreads();
    // S2: P_pred = WP*W^T + Q
    Ppred[e] = dABT(WP, W, i, j) + Qm[e];
    __syncthreads();
    // S3: Pi = inv(P_pred), ld_Ppred
    gj_inv(Ppred, Pi, aug, &ld_Ppred, e);
    // S4: G = WP^T * Pi  (= Pf W^T Ppred^-1)
    Gm[e] = dATB(WP, Pi, i, j);
    __syncthreads();
    // S5: bcov = Pf - G*WP ; a = mf - G*m_pred
    bcovm[e] = Pf[e] - dAB(Gm, WP, i, j);
    if (e < 16) {
      float s = mf[e];
#pragma unroll
      for (int k = 0; k < 16; ++k) s = fmaf(-Gm[e * 16 + k], mpred[k], s);
      av[e] = s;
    }
    __syncthreads();
    // S6: M = S + F_obs + F_tr ; const += tr(M*bcov) + per-step scalars
    {
      float mval = Sm[e] + Fo[e] + Ft[e];
      Mm[e] = mval;
      float v = wave_sum(mval * bcovm[e]);
      if ((e & 63) == 0) red[e >> 6] = v;
    }
    __syncthreads();
    if (e == 0) {
      float tstep = red[0] + red[1] + red[2] + red[3];
      float ldb = ld_Pf + ld_Q - ld_Ppred;  // log det bcov
      sc_const += tstep - 0.5f * (16.f * L2PI + ld_pem) - 0.5f * (16.f * L2PI + ld_ptr)
                  + 0.5f * (16.f * L2PI + ldb) + 8.f;
    }
    // S7: four matvecs + T1 = M*G, NG = N*G
    if (e < 64) {
      const int wsel = e >> 4, r = e & 15;
      float s = 0.f;
      if (wsel == 0) {
#pragma unroll
        for (int k = 0; k < 16; ++k) s = fmaf(Mm[r * 16 + k], av[k], s);
        Mav[r] = s;
      } else if (wsel == 1) {
#pragma unroll
        for (int k = 0; k < 16; ++k) s = fmaf(EOm[r * 16 + k], pb[k], s);
        EOpb[r] = s;
      } else if (wsel == 2) {
#pragma unroll
        for (int k = 0; k < 16; ++k) s = fmaf(Nm[r * 16 + k], av[k], s);
        Nav[r] = s;
      } else {
#pragma unroll
        for (int k = 0; k < 16; ++k) s = fmaf(Omo[r * 16 + k], pb[k], s);
        Opb[r] = s;
      }
    }
    T1[e] = dAB(Mm, Gm, i, j);
    NG[e] = dAB(Nm, Gm, i, j);
    __syncthreads();
    // S8: h = r + EOm*pb + w2 ; v = h + M*a
    if (e < 16) { float h = rv[e] + EOpb[e] + w2[e]; hv[e] = h; vv[e] = h + Mav[e]; }
    __syncthreads();
    // S9: S_new, r_new, c update ; S10: HP, resid
    Sm[e] = dATB(Gm, T1, i, j) - NG[j * 16 + i] - NG[e] + Omt[e];
    if (e < 16) {
      float s = 0.f;
#pragma unroll
      for (int k = 0; k < 16; ++k) s = fmaf(Gm[k * 16 + e], vv[k], s);
      rv[e] = s - Nav[e] - q2[e];
    }
    if (e == 0) {
      float d1 = 0.f, d2 = 0.f, d3 = 0.f;
      for (int k = 0; k < 16; ++k) {
        d1 = fmaf(av[k], Mav[k], d1);
        d2 = fmaf(av[k], hv[k], d2);
        d3 = fmaf(pb[k], Opb[k], d3);
      }
      sc_c += d1 + 2.f * d2 + d3 + ctb;
    }
    HPm[e] = dAB(Hm, Ppred, i, j);
    if (e >= 16 && e < 32) {
      const int r = e - 16;
      float s = 0.f;
#pragma unroll
      for (int k = 0; k < 16; ++k) s = fmaf(Hm[r * 16 + k], mpred[k], s);
      resid[r] = y[r] - s - bemv[r];
    }
    __syncthreads();
    // S11: Smat = HP*H^T + R
    Smat[e] = dABT(HPm, Hm, i, j) + Rm[e];
    __syncthreads();
    // S12
    gj_inv(Smat, Si, aug, &ld_Smat, e);
    // S13: Kg = HP^T * Si
    Kgm[e] = dATB(HPm, Si, i, j);
    __syncthreads();
    // S14: Pf, mf, pb, ld_Pf, store G
    Pf[e] = Ppred[e] - dAB(Kgm, HPm, i, j);
    if (e < 16) {
      float s = mpred[e];
#pragma unroll
      for (int k = 0; k < 16; ++k) s = fmaf(Kgm[e * 16 + k], resid[k], s);
      mf[e] = s;
    }
    if (e >= 16 && e < 32) pb[e - 16] = pbemv[e - 16] - y[e - 16];
    if (e == 0) ld_Pf = ld_Ppred + ld_R - ld_Smat;
    g_Gstore[(t - 1) * 256 + e] = Gm[e];
    __syncthreads();
  }

  // ---- backward suffix pass for tr = sum_k tr(Om A Pf A) (no-transpose quirk) ----
  Tmp[e] = (i == j) ? 1.f : 0.f;  // Cm = Suf_{255} = I
  __syncthreads();
  float trv = 0.f;
  for (int t = 255; t >= 1; --t) {
    Gm[e] = g_Gstore[(t - 1) * 256 + e];
    __syncthreads();
    WP[e] = dAB(Gm, Tmp, i, j);  // Cp = Suf_{t-1} = G_t * Cm
    __syncthreads();
    HPm[e] = dAB(Em, WP, i, j);             // A1 = E * Suf_{t-1}
    Smat[e] = dAB(Pwm, WP, i, j) - Tmp[e];  // A2 = Pw*Suf_{t-1} - Suf_t
    __syncthreads();
    T1[e] = dAB(Omo, HPm, i, j);
    NG[e] = dAB(Pf, HPm, i, j);
    Kgm[e] = dAB(Omt, Smat, i, j);
    Si[e] = dAB(Pf, Smat, i, j);
    Tmp[e] = WP[e];  // Cm = Cp
    __syncthreads();
    trv += T1[e] * NG[j * 16 + i] + Kgm[e] * Si[j * 16 + i];
  }
  // slot 0: A = Suf_0, Om = Om0
  T1[e] = dAB(Om0, Tmp, i, j);
  NG[e] = dAB(Pf, Tmp, i, j);
  __syncthreads();
  trv += T1[e] * NG[j * 16 + i];
  {
    float v = wave_sum(trv);
    if ((e & 63) == 0) red[e >> 6] = v;
  }
  __syncthreads();
  if (e == 0) tr_sum = red[0] + red[1] + red[2] + red[3];

  // ---- final terms ----
  WP[e] = dAB(Pf, Em, i, j);  // PE = Pf * E
  if (e < 16) {
    float s = 0.f;
#pragma unroll
    for (int k = 0; k < 16; ++k) s = fmaf(Sm[e * 16 + k], mf[k], s);
    tv1[e] = s;  // S*mf
  } else if (e < 32) {
    const int r = e - 16;
    float s = pb[r];
#pragma unroll
    for (int k = 0; k < 16; ++k) s = fmaf(Em[r * 16 + k], mf[k], s);
    tv2[r] = s;  // up = E*mf + pend_b
  }
  __syncthreads();
  {
    // tr_p = tr(Omo E Pf E) = sum_e EOm[e]*PE[e]  (Omo symmetric)
    float v = wave_sum(EOm[e] * WP[e]);
    if ((e & 63) == 0) red[e >> 6] = v;
  }
  if (e < 16) {
    float s = 0.f;
#pragma unroll
    for (int k = 0; k < 16; ++k) s = fmaf(Omo[e * 16 + k], tv2[k], s);
    Opb[e] = s;  // Omo * up
  }
  __syncthreads();
  if (e == 0) {
    float tr_p = red[0] + red[1] + red[2] + red[3];
    float ev1 = 0.f, ev2 = 0.f, evp = 0.f;
    for (int k = 0; k < 16; ++k) {
      ev1 = fmaf(mf[k], tv1[k], ev1);
      ev2 = fmaf(rv[k], mf[k], ev2);
      evp = fmaf(tv2[k], Opb[k], evp);
    }
    float ev = ev1 + 2.f * ev2 + sc_c;
    out[0] = sc_const + 0.5f * (16.f * L2PI + ld_Pf) + tr_sum + ev + tr_p + evp + 8.f;
  }
}

extern "C" void kernel_launch(void* const* d_in, const int* in_sizes, int n_in,
                              void* d_out, int out_size, void* d_ws, size_t ws_size,
                              hipStream_t stream) {
  (void)in_sizes; (void)n_in; (void)out_size; (void)d_ws; (void)ws_size;
  lgq_kernel<<<dim3(1), dim3(256), 0, stream>>>(
      (const float*)d_in[0], (const float*)d_in[1], (const float*)d_in[2],
      (const float*)d_in[3], (const float*)d_in[4], (const float*)d_in[5],
      (const float*)d_in[6], (const float*)d_in[7], (const float*)d_in[8],
      (const float*)d_in[9], (const float*)d_in[10], (const float*)d_in[11],
      (const float*)d_in[12], (const float*)d_in[13], (const float*)d_in[14],
      (const float*)d_in[15], (const float*)d_in[16], (float*)d_out);
}

// Round 2
// 1453.477 us; speedup vs baseline: 1.9873x; 1.9873x over previous
//
#include <hip/hip_runtime.h>
#include <cmath>

#define L2PI 1.8378770664093453f
#define CT16 (16.f * L2PI)

// Per-launch scratch (fully rewritten every call before being read).
__device__ __align__(16) float g_Gstore[255 * 256];
__device__ __align__(16) float g_Suf[256 * 256];
__device__ float g_Pff[256], g_Om0[256], g_Omo[256], g_Omt[256];
__device__ float g_partial, g_acc;

__device__ __forceinline__ float dAB(const float* A, const float* B, int i, int j) {
  float s = 0.f;
#pragma unroll
  for (int k = 0; k < 16; ++k) s = fmaf(A[i * 16 + k], B[k * 16 + j], s);
  return s;
}
__device__ __forceinline__ float dATB(const float* A, const float* B, int i, int j) {
  float s = 0.f;
#pragma unroll
  for (int k = 0; k < 16; ++k) s = fmaf(A[k * 16 + i], B[k * 16 + j], s);
  return s;
}
__device__ __forceinline__ float dABT(const float* A, const float* B, int i, int j) {
  float s = 0.f;
#pragma unroll
  for (int k = 0; k < 16; ++k) s = fmaf(A[i * 16 + k], B[j * 16 + k], s);
  return s;
}
__device__ __forceinline__ float mv(const float* M, const float* v, int r) {
  float s = 0.f;
#pragma unroll
  for (int k = 0; k < 16; ++k) s = fmaf(M[r * 16 + k], v[k], s);
  return s;
}
__device__ __forceinline__ float mvT(const float* M, const float* v, int r) {
  float s = 0.f;
#pragma unroll
  for (int k = 0; k < 16; ++k) s = fmaf(M[k * 16 + r], v[k], s);
  return s;
}
__device__ __forceinline__ float wave_sum(float v) {
#pragma unroll
  for (int off = 32; off; off >>= 1) v += __shfl_down(v, off);
  return v;
}
__device__ __forceinline__ float wave_max(float v) {
#pragma unroll
  for (int off = 32; off; off >>= 1) v = fmaxf(v, __shfl_down(v, off));
  return v;
}

// Register-resident Gauss-Jordan inverse of SPD 16x16, executed by ONE wave
// (64 lanes), barrier-free: state lives in registers, cross-lane via __shfl.
// Lane l owns column (l&15), rows (l>>4)+4q, q=0..3. Returns det (all lanes).
__device__ __forceinline__ float reg_gj_inv(const float* __restrict__ src,
                                            float* __restrict__ dst) {
  const int wl = threadIdx.x & 63;
  const int col = wl & 15, rg = wl >> 4;
  float aA[4], aI[4];
#pragma unroll
  for (int q = 0; q < 4; ++q) {
    const int r = rg + 4 * q;
    aA[q] = src[r * 16 + col];
    aI[q] = (r == col) ? 1.f : 0.f;
  }
  float det = 1.f;
#pragma unroll
  for (int k = 0; k < 16; ++k) {
    const int kq = k >> 2, kr = k & 3;
    const float piv = __shfl(aA[kq], (kr << 4) | k);
    det *= piv;
    const float rp = 1.f / piv;
    const float pA = __shfl(aA[kq], (kr << 4) | col);
    const float pI = __shfl(aI[kq], (kr << 4) | col);
    float f[4];
    f[0] = __shfl(aA[0], (rg << 4) | k);
    f[1] = __shfl(aA[1], (rg << 4) | k);
    f[2] = __shfl(aA[2], (rg << 4) | k);
    f[3] = __shfl(aA[3], (rg << 4) | k);
#pragma unroll
    for (int q = 0; q < 4; ++q) {
      const float tq = f[q] * rp;
      const float nA = fmaf(-tq, pA, aA[q]);
      const float nI = fmaf(-tq, pI, aI[q]);
      if (q == kq) {
        const bool isp = (rg == kr);
        aA[q] = isp ? pA * rp : nA;
        aI[q] = isp ? pI * rp : nI;
      } else {
        aA[q] = nA;
        aI[q] = nI;
      }
    }
  }
#pragma unroll
  for (int q = 0; q < 4; ++q) dst[(rg + 4 * q) * 16 + col] = aI[q];
  return det;
}

__global__ void __launch_bounds__(256)
lgq_fwd(const float* __restrict__ obs,
        const float* __restrict__ ppm, const float* __restrict__ ppc,
        const float* __restrict__ ptw, const float* __restrict__ ptb,
        const float* __restrict__ ptc, const float* __restrict__ pew,
        const float* __restrict__ peb, const float* __restrict__ pec,
        const float* __restrict__ qpm, const float* __restrict__ qpc,
        const float* __restrict__ qtw, const float* __restrict__ qtb,
        const float* __restrict__ qtc, const float* __restrict__ qew,
        const float* __restrict__ qeb, const float* __restrict__ qec) {
  const int e = threadIdx.x;
  const int i = e >> 4, j = e & 15;
  const int wid = e >> 6;

  __shared__ float W[256], Qm[256], Hm[256], Rm[256], Em[256], Pwm[256];
  __shared__ float HW[256], QHt[256], HQH[256];
  __shared__ float Om0[256], Omo[256], Omt[256], Fo[256], Ft[256], Nm[256], EOm[256];
  __shared__ float Sm[256], Pf[256];
  __shared__ float WP[256], U[256], Ppred[256], Smat[256], PHt[256];
  __shared__ float Pi[256], Si[256], Gm[256], Kgm[256], Mm[256], T1m[256], NGm[256];
  __shared__ float TmpB[256];
  __shared__ float mf[16], mfN[16], rv[16], pb[16], bqv[16], bemv[16], pbemv[16], ptbv[16];
  __shared__ float w2[16], q2[16], mpred[16], av[16], Mav[16], hv[16], vv[16], Nav[16];
  __shared__ float EOpb[16], Opb[16], resid[16], tv1[16], tv2[16];
  __shared__ float red[4], red2[4], red3[4], dets[6];
  __shared__ float sc_const, sc_c, ctb;
  __shared__ float ld_pprior, ld_ptr, ld_pem, ld_Q, ld_R, ld_qprior, ld_Pf;
  __shared__ float sh_detP, sh_detS, sh_d3, sh_pfd, sh_tstep, sh_ldb, sh_fdelta;
  __shared__ int sh_frozen;

  // I0: load fixed inputs
  W[e] = qtw[e]; Qm[e] = qtc[e]; Hm[e] = qew[e]; Rm[e] = qec[e];
  Em[e] = pew[e]; Pwm[e] = ptw[e];
  if (e < 16) { bqv[e] = qtb[e]; bemv[e] = qeb[e]; pbemv[e] = peb[e]; ptbv[e] = ptb[e]; }
  if (e == 0) { sh_frozen = 0; g_acc = 0.f; }
  __syncthreads();
  // I1
  HW[e] = dAB(Hm, W, i, j);
  TmpB[e] = dAB(Hm, Qm, i, j);
  __syncthreads();
  // I2
  HQH[e] = dABT(TmpB, Hm, i, j) + Rm[e];
  QHt[e] = TmpB[j * 16 + i];
  __syncthreads();
  // I3: six fixed inversions, two per wave, barrier-free within each wave
  if (wid == 0) {
    float d0 = reg_gj_inv(ppc, Pi);
    float d1 = reg_gj_inv(ptc, Si);
    if (e == 0) { dets[0] = d0; dets[1] = d1; }
  } else if (wid == 1) {
    float d2 = reg_gj_inv(pec, Gm);
    float d3 = reg_gj_inv(qtc, Kgm);
    if (e == 64) { dets[2] = d2; dets[3] = d3; }
  } else if (wid == 2) {
    float d4 = reg_gj_inv(qec, T1m);
    float d5 = reg_gj_inv(qpc, NGm);
    if (e == 128) { dets[4] = d4; dets[5] = d5; }
  }
  __syncthreads();
  // I4
  Om0[e] = -0.5f * Pi[e];
  Omt[e] = -0.5f * Si[e];
  Omo[e] = -0.5f * Gm[e];
  if (e == 0) {
    ld_pprior = logf(dets[0]); ld_ptr = logf(dets[1]); ld_pem = logf(dets[2]);
    ld_Q = logf(dets[3]); ld_R = logf(dets[4]); ld_qprior = logf(dets[5]);
  }
  __syncthreads();
  // I5
  g_Om0[e] = Om0[e]; g_Omo[e] = Omo[e]; g_Omt[e] = Omt[e];
  TmpB[e] = dAB(Omo, Em, i, j);
  Nm[e] = dAB(Omt, Pwm, i, j);
  EOm[e] = dATB(Em, Omo, i, j);
  Sm[e] = Om0[e];
  __syncthreads();
  // I6
  Fo[e] = dATB(Em, TmpB, i, j);
  Ft[e] = dATB(Pwm, Nm, i, j);
  if (e < 16) w2[e] = mvT(Nm, ptbv, e);
  else if (e < 32) q2[e - 16] = mv(Omt, ptbv, e - 16);
  else if (e < 48) rv[e - 32] = -mv(Om0, ppm, e - 32);
  else if (e < 64) pb[e - 48] = pbemv[e - 48] - obs[e - 48];
  __syncthreads();
  // I7
  if (e == 0) {
    float s = 0.f, ct = 0.f;
    for (int k = 0; k < 16; ++k) { s = fmaf(ppm[k], rv[k], s); ct = fmaf(ptbv[k], q2[k], ct); }
    sc_c = -s;
    ctb = ct;
    sc_const = -0.5f * (CT16 + ld_pprior) - 0.5f * (CT16 + ld_pem);
  }
  if (e < 16) mpred[e] = qpm[e];
  TmpB[e] = dAB(Hm, qpc, i, j);  // H * q_prior_cov
  __syncthreads();
  // I8
  Smat[e] = dABT(TmpB, Hm, i, j) + Rm[e];
  if (e < 16) resid[e] = obs[e] - bemv[e] - mv(Hm, mpred, e);
  __syncthreads();
  // I9
  if (wid == 0) {
    float d = reg_gj_inv(Smat, Si);
    if (e == 0) sh_detS = d;
  }
  __syncthreads();
  // I10
  Kgm[e] = dATB(TmpB, Si, i, j);
  if (e == 0) ld_Pf = ld_qprior + ld_R - logf(sh_detS);
  __syncthreads();
  // I11
  Pf[e] = qpc[e] - dAB(Kgm, TmpB, i, j);
  if (e < 16) mf[e] = mpred[e] + mv(Kgm, resid, e);
  __syncthreads();

  // ---- forward scan ----
  int t = 1;
  for (; t < 256; ++t) {
    if (sh_frozen) break;
    const float* y = obs + t * 16;
    // T1
    WP[e] = dAB(W, Pf, i, j);
    U[e] = dAB(HW, Pf, i, j);
    if (e < 16) mpred[e] = bqv[e] + mv(W, mf, e);
    __syncthreads();
    // T2
    Ppred[e] = dABT(WP, W, i, j) + Qm[e];
    Smat[e] = dABT(U, HW, i, j) + HQH[e];
    PHt[e] = dABT(WP, HW, i, j) + QHt[e];
    if (e < 16) resid[e] = y[e] - bemv[e] - mv(Hm, mpred, e);
    __syncthreads();
    // T3: both inversions concurrently, barrier-free
    if (wid == 0) {
      float d = reg_gj_inv(Ppred, Pi);
      if (e == 0) sh_detP = d;
    } else if (wid == 1) {
      float d = reg_gj_inv(Smat, Si);
      if (e == 64) sh_detS = d;
    } else if (wid == 2) {
      const int wl = e & 63;
#pragma unroll
      for (int q = 0; q < 4; ++q) { const int x = wl + 64 * q; Mm[x] = Sm[x] + Fo[x] + Ft[x]; }
      if (wl < 16) EOpb[wl] = mv(EOm, pb, wl);
      else if (wl < 32) Opb[wl - 16] = mv(Omo, pb, wl - 16);
    }
    __syncthreads();
    // T4
    Gm[e] = dATB(WP, Pi, i, j);
    Kgm[e] = dAB(PHt, Si, i, j);
    __syncthreads();
    // T5
    {
      const float bc = Pf[e] - dAB(Gm, WP, i, j);
      const float val = Mm[e] * bc;
      const float pfN = Ppred[e] - dABT(Kgm, PHt, i, j);
      const float df = fabsf(pfN - Pf[e]);
      Pf[e] = pfN;
      const float vs = wave_sum(val);
      const float vm = wave_max(df);
      if ((e & 63) == 0) { red[e >> 6] = vs; red2[e >> 6] = vm; }
      if (e < 16) av[e] = mf[e] - mv(Gm, mpred, e);
      else if (e < 32) mfN[e - 16] = mpred[e - 16] + mv(Kgm, resid, e - 16);
    }
    __syncthreads();
    // T6
    T1m[e] = dAB(Mm, Gm, i, j);
    NGm[e] = dAB(Nm, Gm, i, j);
    if (e >= 64 && e < 80) Mav[e - 64] = mv(Mm, av, e - 64);
    else if (e >= 80 && e < 96) Nav[e - 80] = mv(Nm, av, e - 80);
    else if (e >= 96 && e < 112) hv[e - 96] = rv[e - 96] + EOpb[e - 96] + w2[e - 96];
    if (e == 1) {
      float s = 0.f;
      for (int k = 0; k < 16; ++k) s = fmaf(pb[k], Opb[k], s);
      sh_d3 = s;
    }
    if (e == 0) {
      const float tstep = red[0] + red[1] + red[2] + red[3];
      sh_pfd = fmaxf(fmaxf(red2[0], red2[1]), fmaxf(red2[2], red2[3]));
      const float ldP = logf(sh_detP), ldS = logf(sh_detS);
      const float ldb = ld_Pf + ld_Q - ldP;
      sc_const += tstep - 0.5f * (CT16 + ld_pem) - 0.5f * (CT16 + ld_ptr)
                  + 0.5f * (CT16 + ldb) + 8.f;
      ld_Pf = ldP + ld_R - ldS;
      sh_tstep = tstep; sh_ldb = ldb;
    }
    __syncthreads();
    // T7
    {
      const float sN = dATB(Gm, T1m, i, j) - NGm[j * 16 + i] - NGm[e] + Omt[e];
      const float sd = fabsf(sN - Sm[e]);
      Sm[e] = sN;
      const float vm = wave_max(sd);
      if ((e & 63) == 0) red3[e >> 6] = vm;
    }
    if (e < 16) vv[e] = hv[e] + Mav[e];
    else if (e < 32) pb[e - 16] = pbemv[e - 16] - y[e - 16];
    else if (e < 48) mf[e - 32] = mfN[e - 32];
    g_Gstore[(t - 1) * 256 + e] = Gm[e];
    __syncthreads();
    // T8
    if (e < 16) rv[e] = mvT(Gm, vv, e) - Nav[e] - q2[e];
    if (e == 0) {
      float d1 = 0.f, d2 = 0.f;
      for (int k = 0; k < 16; ++k) { d1 = fmaf(av[k], Mav[k], d1); d2 = fmaf(av[k], hv[k], d2); }
      sc_c += d1 + 2.f * d2 + sh_d3 + ctb;
      const float sdm = fmaxf(fmaxf(red3[0], red3[1]), fmaxf(red3[2], red3[3]));
      if (t >= 32 && sh_pfd < 1e-7f && sdm < 1e-6f) {
        sh_frozen = 1;
        sh_fdelta = sh_tstep - 0.5f * (CT16 + ld_pem) - 0.5f * (CT16 + ld_ptr)
                    + 0.5f * (CT16 + sh_ldb) + 8.f;
      }
    }
    __syncthreads();
  }

  // ---- frozen steady-state remainder: vector recursions only ----
  if (t < 256) {
    const int tb = t;
    const float gfro = Gm[e];
    Mm[e] = Sm[e] + Fo[e] + Ft[e];
    __syncthreads();
    for (; t < 256; ++t) {
      const float* y = obs + t * 16;
      // F1
      if (e < 16) mpred[e] = bqv[e] + mv(W, mf, e);
      else if (e < 32) EOpb[e - 16] = mv(EOm, pb, e - 16);
      else if (e < 48) Opb[e - 32] = mv(Omo, pb, e - 32);
      __syncthreads();
      // F2
      if (e < 16) resid[e] = y[e] - bemv[e] - mv(Hm, mpred, e);
      else if (e < 32) av[e - 16] = mf[e - 16] - mv(Gm, mpred, e - 16);
      else if (e < 48) hv[e - 32] = rv[e - 32] + EOpb[e - 32] + w2[e - 32];
      __syncthreads();
      // F3
      if (e < 16) mfN[e] = mpred[e] + mv(Kgm, resid, e);
      else if (e < 32) Mav[e - 16] = mv(Mm, av, e - 16);
      else if (e < 48) Nav[e - 32] = mv(Nm, av, e - 32);
      __syncthreads();
      // F4
      if (e < 16) vv[e] = hv[e] + Mav[e];
      if (e == 32) {
        float d1 = 0.f, d2 = 0.f, d3 = 0.f;
        for (int k = 0; k < 16; ++k) {
          d1 = fmaf(av[k], Mav[k], d1);
          d2 = fmaf(av[k], hv[k], d2);
          d3 = fmaf(pb[k], Opb[k], d3);
        }
        sc_c += d1 + 2.f * d2 + d3 + ctb;
      }
      __syncthreads();
      // F5
      if (e < 16) rv[e] = mvT(Gm, vv, e) - Nav[e] - q2[e];
      else if (e < 32) mf[e - 16] = mfN[e - 16];
      else if (e < 48) pb[e - 32] = pbemv[e - 32] - y[e - 32];
      g_Gstore[(t - 1) * 256 + e] = gfro;
      __syncthreads();
    }
    if (e == 0) sc_const += (float)(256 - tb) * sh_fdelta;
  }

  // ---- final terms (all but tr_sum) ----
  g_Pff[e] = Pf[e];
  WP[e] = dAB(Pf, Em, i, j);  // PE = Pf * E
  if (e < 16) tv1[e] = mv(Sm, mf, e);
  else if (e < 32) tv2[e - 16] = pb[e - 16] + mv(Em, mf, e - 16);
  __syncthreads();
  {
    const float v = wave_sum(EOm[e] * WP[e]);
    if ((e & 63) == 0) red[e >> 6] = v;
  }
  if (e < 16) Opb[e] = mv(Omo, tv2, e);
  __syncthreads();
  if (e == 0) {
    const float tr_p = red[0] + red[1] + red[2] + red[3];
    float ev1 = 0.f, ev2 = 0.f, evp = 0.f;
    for (int k = 0; k < 16; ++k) {
      ev1 = fmaf(mf[k], tv1[k], ev1);
      ev2 = fmaf(rv[k], mf[k], ev2);
      evp = fmaf(tv2[k], Opb[k], evp);
    }
    g_partial = sc_const + 0.5f * (CT16 + ld_Pf) + (ev1 + 2.f * ev2 + sc_c)
                + tr_p + evp + 8.f;
  }
  __syncthreads();

  // ---- suffix-product chain: Suf_{t-1} = G_t * Suf_t ----
  float* Xc = WP;
  float* Xn = U;
  Xc[e] = (i == j) ? 1.f : 0.f;
  g_Suf[255 * 256 + e] = Xc[e];
  __syncthreads();
  for (int tt = 255; tt >= 1; --tt) {
    const float4* gr = (const float4*)(g_Gstore + (tt - 1) * 256 + i * 16);
    const float4 a0 = gr[0], a1 = gr[1], a2 = gr[2], a3 = gr[3];
    float s = 0.f;
    s = fmaf(a0.x, Xc[0 * 16 + j], s);  s = fmaf(a0.y, Xc[1 * 16 + j], s);
    s = fmaf(a0.z, Xc[2 * 16 + j], s);  s = fmaf(a0.w, Xc[3 * 16 + j], s);
    s = fmaf(a1.x, Xc[4 * 16 + j], s);  s = fmaf(a1.y, Xc[5 * 16 + j], s);
    s = fmaf(a1.z, Xc[6 * 16 + j], s);  s = fmaf(a1.w, Xc[7 * 16 + j], s);
    s = fmaf(a2.x, Xc[8 * 16 + j], s);  s = fmaf(a2.y, Xc[9 * 16 + j], s);
    s = fmaf(a2.z, Xc[10 * 16 + j], s); s = fmaf(a2.w, Xc[11 * 16 + j], s);
    s = fmaf(a3.x, Xc[12 * 16 + j], s); s = fmaf(a3.y, Xc[13 * 16 + j], s);
    s = fmaf(a3.z, Xc[14 * 16 + j], s); s = fmaf(a3.w, Xc[15 * 16 + j], s);
    Xn[e] = s;
    g_Suf[(tt - 1) * 256 + e] = s;
    __syncthreads();
    float* tmp = Xc; Xc = Xn; Xn = tmp;
  }
}

// One block per t: trace terms tr(Om A Pf A) for the two slots created at
// step t (b>=1), or the prior slot (b==0). Embarrassingly parallel.
__global__ void __launch_bounds__(256)
lgq_trace(const float* __restrict__ pew, const float* __restrict__ ptw) {
  const int e = threadIdx.x, i = e >> 4, j = e & 15, b = blockIdx.x;
  __shared__ float Pfs[256], OmA[256], OmtS[256], EmS[256], PwS[256];
  __shared__ float Sm1[256], Sf[256], A1[256], A2[256], T1[256], NG[256], Kx[256], S2[256];
  __shared__ float red[4];
  Pfs[e] = g_Pff[e];
  OmtS[e] = g_Omt[e];
  EmS[e] = pew[e];
  PwS[e] = ptw[e];
  if (b == 0) {
    OmA[e] = g_Om0[e];
    Sm1[e] = g_Suf[e];  // Suf_0
    Sf[e] = 0.f;
  } else {
    OmA[e] = g_Omo[e];
    Sm1[e] = g_Suf[(b - 1) * 256 + e];
    Sf[e] = g_Suf[b * 256 + e];
  }
  __syncthreads();
  if (b == 0) {
    A1[e] = Sm1[e];
    A2[e] = 0.f;
  } else {
    A1[e] = dAB(EmS, Sm1, i, j);
    A2[e] = dAB(PwS, Sm1, i, j) - Sf[e];
  }
  __syncthreads();
  T1[e] = dAB(OmA, A1, i, j);
  NG[e] = dAB(Pfs, A1, i, j);
  Kx[e] = dAB(OmtS, A2, i, j);
  S2[e] = dAB(Pfs, A2, i, j);
  __syncthreads();
  float val = T1[e] * NG[j * 16 + i] + Kx[e] * S2[j * 16 + i];
  val = wave_sum(val);
  if ((e & 63) == 0) red[e >> 6] = val;
  __syncthreads();
  if (e == 0) atomicAdd(&g_acc, red[0] + red[1] + red[2] + red[3]);
}

__global__ void lgq_fin(float* __restrict__ out) { out[0] = g_partial + g_acc; }

extern "C" void kernel_launch(void* const* d_in, const int* in_sizes, int n_in,
                              void* d_out, int out_size, void* d_ws, size_t ws_size,
                              hipStream_t stream) {
  (void)in_sizes; (void)n_in; (void)out_size; (void)d_ws; (void)ws_size;
  lgq_fwd<<<dim3(1), dim3(256), 0, stream>>>(
      (const float*)d_in[0], (const float*)d_in[1], (const float*)d_in[2],
      (const float*)d_in[3], (const float*)d_in[4], (const float*)d_in[5],
      (const float*)d_in[6], (const float*)d_in[7], (const float*)d_in[8],
      (const float*)d_in[9], (const float*)d_in[10], (const float*)d_in[11],
      (const float*)d_in[12], (const float*)d_in[13], (const float*)d_in[14],
      (const float*)d_in[15], (const float*)d_in[16]);
  lgq_trace<<<dim3(256), dim3(256), 0, stream>>>((const float*)d_in[6],
                                                 (const float*)d_in[3]);
  lgq_fin<<<dim3(1), dim3(1), 0, stream>>>((float*)d_out);
}

// Round 3
// 333.059 us; speedup vs baseline: 8.6725x; 4.3640x over previous
//
#include <hip/hip_runtime.h>
#include <cmath>

#define L2PI 1.8378770664093453f
#define CT16 (16.f * L2PI)
#define PAD 20

// Per-launch scratch (fully rewritten every call before being read).
__device__ __align__(16) float g_Gstore[255 * 256];
__device__ __align__(16) float g_Suf[256 * 256];
__device__ float g_Pff[256], g_Om0[256], g_Omo[256], g_Omt[256], g_Ginf[256];
__device__ float g_partial, g_acc;
__device__ int g_tb;

__device__ __forceinline__ float dAB(const float* A, const float* B, int i, int j) {
  float s = 0.f;
#pragma unroll
  for (int k = 0; k < 16; ++k) s = fmaf(A[i * 16 + k], B[k * 16 + j], s);
  return s;
}
__device__ __forceinline__ float dATB(const float* A, const float* B, int i, int j) {
  float s = 0.f;
#pragma unroll
  for (int k = 0; k < 16; ++k) s = fmaf(A[k * 16 + i], B[k * 16 + j], s);
  return s;
}
__device__ __forceinline__ float dABT(const float* A, const float* B, int i, int j) {
  float s = 0.f;
#pragma unroll
  for (int k = 0; k < 16; ++k) s = fmaf(A[i * 16 + k], B[j * 16 + k], s);
  return s;
}
__device__ __forceinline__ float mv(const float* M, const float* v, int r) {
  float s = 0.f;
#pragma unroll
  for (int k = 0; k < 16; ++k) s = fmaf(M[r * 16 + k], v[k], s);
  return s;
}
__device__ __forceinline__ float mvT(const float* M, const float* v, int r) {
  float s = 0.f;
#pragma unroll
  for (int k = 0; k < 16; ++k) s = fmaf(M[k * 16 + r], v[k], s);
  return s;
}
__device__ __forceinline__ float rowdot(const float* P, int r, const float* v) {
  float s = 0.f;
#pragma unroll
  for (int k = 0; k < 16; ++k) s = fmaf(P[r * PAD + k], v[k], s);
  return s;
}
__device__ __forceinline__ float wave_sum(float v) {
#pragma unroll
  for (int off = 32; off; off >>= 1) v += __shfl_down(v, off);
  return v;
}
__device__ __forceinline__ float wave_max(float v) {
#pragma unroll
  for (int off = 32; off; off >>= 1) v = fmaxf(v, __shfl_down(v, off));
  return v;
}

// Register-resident Gauss-Jordan inverse of SPD 16x16, one wave, barrier-free.
__device__ __forceinline__ float reg_gj_inv(const float* __restrict__ src,
                                            float* __restrict__ dst) {
  const int wl = threadIdx.x & 63;
  const int col = wl & 15, rg = wl >> 4;
  float aA[4], aI[4];
#pragma unroll
  for (int q = 0; q < 4; ++q) {
    const int r = rg + 4 * q;
    aA[q] = src[r * 16 + col];
    aI[q] = (r == col) ? 1.f : 0.f;
  }
  float det = 1.f;
#pragma unroll
  for (int k = 0; k < 16; ++k) {
    const int kq = k >> 2, kr = k & 3;
    const float piv = __shfl(aA[kq], (kr << 4) | k);
    det *= piv;
    const float rp = 1.f / piv;
    const float pA = __shfl(aA[kq], (kr << 4) | col);
    const float pI = __shfl(aI[kq], (kr << 4) | col);
    float f[4];
    f[0] = __shfl(aA[0], (rg << 4) | k);
    f[1] = __shfl(aA[1], (rg << 4) | k);
    f[2] = __shfl(aA[2], (rg << 4) | k);
    f[3] = __shfl(aA[3], (rg << 4) | k);
#pragma unroll
    for (int q = 0; q < 4; ++q) {
      const float tq = f[q] * rp;
      const float nA = fmaf(-tq, pA, aA[q]);
      const float nI = fmaf(-tq, pI, aI[q]);
      if (q == kq) {
        const bool isp = (rg == kr);
        aA[q] = isp ? pA * rp : nA;
        aI[q] = isp ? pI * rp : nI;
      } else {
        aA[q] = nA;
        aI[q] = nI;
      }
    }
  }
#pragma unroll
  for (int q = 0; q < 4; ++q) dst[(rg + 4 * q) * 16 + col] = aI[q];
  return det;
}

__global__ void __launch_bounds__(256)
lgq_fwd(const float* __restrict__ obs,
        const float* __restrict__ ppm, const float* __restrict__ ppc,
        const float* __restrict__ ptw, const float* __restrict__ ptb,
        const float* __restrict__ ptc, const float* __restrict__ pew,
        const float* __restrict__ peb, const float* __restrict__ pec,
        const float* __restrict__ qpm, const float* __restrict__ qpc,
        const float* __restrict__ qtw, const float* __restrict__ qtb,
        const float* __restrict__ qtc, const float* __restrict__ qew,
        const float* __restrict__ qeb, const float* __restrict__ qec) {
  const int e = threadIdx.x;
  const int i = e >> 4, j = e & 15;
  const int wid = e >> 6;

  __shared__ float W[256], Qm[256], Hm[256], Rm[256], Em[256], Pwm[256];
  __shared__ float HW[256], QHt[256], HQH[256];
  __shared__ float Om0[256], Omo[256], Omt[256], Fo[256], Ft[256], Nm[256], EOm[256];
  __shared__ float Sm[256], Pf[256];
  __shared__ float WP[256], U[256], Ppred[256], Smat[256], PHt[256];
  __shared__ float Pi[256], Si[256], Gm[256], Kgm[256], Mm[256], T1m[256], NGm[256];
  __shared__ float TmpB[256];
  __shared__ float sObs[256 * 16];
  // fused frozen operators, pad-20 rows (bank-conflict-free, b128-vectorizable)
  __shared__ float A1p[16 * PAD], Kgp[16 * PAD], GTp[16 * PAD], B1p[16 * PAD];
  __shared__ float GEOp[16 * PAD], Avp[16 * PAD], MAvp[16 * PAD], EOmp[16 * PAD],
      Omop[16 * PAD];
  __shared__ float mf[16], mfN[16], rv[16], pb[16], bqv[16], bemv[16], pbemv[16],
      ptbv[16];
  __shared__ float w2[16], q2[16], mpred[16], av[16], Mav[16], hv[16], Nav[16];
  __shared__ float EOpb[16], Opb[16], resid[16], tv1[16], tv2[16];
  __shared__ float v1[16], v2[16], v3[16], v4[16], v5[16], v8[16];
  __shared__ float ca[16], mca[16], nca[16], c1[16], c2[16], w2mca[16];
  __shared__ float pbBuf[2][16];
  __shared__ float red[4], red2[4], red3[4], dets[6];
  __shared__ float sc_const, sc_c, ctb;
  __shared__ float ld_pprior, ld_ptr, ld_pem, ld_Q, ld_R, ld_qprior, ld_Pf;
  __shared__ float sh_detP, sh_detS, sh_d3, sh_pfd, sh_tstep, sh_ldb, sh_fdelta;
  __shared__ int sh_frozen;

  // I0: load fixed inputs + stage obs into LDS
  W[e] = qtw[e]; Qm[e] = qtc[e]; Hm[e] = qew[e]; Rm[e] = qec[e];
  Em[e] = pew[e]; Pwm[e] = ptw[e];
  {
    const float4* o4 = (const float4*)obs;
    float4* s4 = (float4*)sObs;
#pragma unroll
    for (int q = 0; q < 4; ++q) s4[e + 256 * q] = o4[e + 256 * q];
  }
  if (e < 16) { bqv[e] = qtb[e]; bemv[e] = qeb[e]; pbemv[e] = peb[e]; ptbv[e] = ptb[e]; }
  if (e == 0) { sh_frozen = 0; g_acc = 0.f; }
  __syncthreads();
  // I1
  HW[e] = dAB(Hm, W, i, j);
  TmpB[e] = dAB(Hm, Qm, i, j);
  __syncthreads();
  // I2
  HQH[e] = dABT(TmpB, Hm, i, j) + Rm[e];
  QHt[e] = TmpB[j * 16 + i];
  __syncthreads();
  // I3: six fixed inversions, two per wave
  if (wid == 0) {
    float d0 = reg_gj_inv(ppc, Pi);
    float d1 = reg_gj_inv(ptc, Si);
    if (e == 0) { dets[0] = d0; dets[1] = d1; }
  } else if (wid == 1) {
    float d2 = reg_gj_inv(pec, Gm);
    float d3 = reg_gj_inv(qtc, Kgm);
    if (e == 64) { dets[2] = d2; dets[3] = d3; }
  } else if (wid == 2) {
    float d4 = reg_gj_inv(qec, T1m);
    float d5 = reg_gj_inv(qpc, NGm);
    if (e == 128) { dets[4] = d4; dets[5] = d5; }
  }
  __syncthreads();
  // I4
  Om0[e] = -0.5f * Pi[e];
  Omt[e] = -0.5f * Si[e];
  Omo[e] = -0.5f * Gm[e];
  if (e == 0) {
    ld_pprior = logf(dets[0]); ld_ptr = logf(dets[1]); ld_pem = logf(dets[2]);
    ld_Q = logf(dets[3]); ld_R = logf(dets[4]); ld_qprior = logf(dets[5]);
  }
  __syncthreads();
  // I5
  g_Om0[e] = Om0[e]; g_Omo[e] = Omo[e]; g_Omt[e] = Omt[e];
  TmpB[e] = dAB(Omo, Em, i, j);
  Nm[e] = dAB(Omt, Pwm, i, j);
  EOm[e] = dATB(Em, Omo, i, j);
  Sm[e] = Om0[e];
  __syncthreads();
  // I6
  Fo[e] = dATB(Em, TmpB, i, j);
  Ft[e] = dATB(Pwm, Nm, i, j);
  if (e < 16) w2[e] = mvT(Nm, ptbv, e);
  else if (e < 32) q2[e - 16] = mv(Omt, ptbv, e - 16);
  else if (e < 48) rv[e - 32] = -mv(Om0, ppm, e - 32);
  else if (e < 64) pb[e - 48] = pbemv[e - 48] - sObs[e - 48];
  __syncthreads();
  // I7
  if (e == 0) {
    float s = 0.f, ct = 0.f;
    for (int k = 0; k < 16; ++k) { s = fmaf(ppm[k], rv[k], s); ct = fmaf(ptbv[k], q2[k], ct); }
    sc_c = -s;
    ctb = ct;
    sc_const = -0.5f * (CT16 + ld_pprior) - 0.5f * (CT16 + ld_pem);
  }
  if (e < 16) mpred[e] = qpm[e];
  TmpB[e] = dAB(Hm, qpc, i, j);
  __syncthreads();
  // I8
  Smat[e] = dABT(TmpB, Hm, i, j) + Rm[e];
  if (e < 16) resid[e] = sObs[e] - bemv[e] - mv(Hm, mpred, e);
  __syncthreads();
  // I9
  if (wid == 0) {
    float d = reg_gj_inv(Smat, Si);
    if (e == 0) sh_detS = d;
  }
  __syncthreads();
  // I10
  Kgm[e] = dATB(TmpB, Si, i, j);
  if (e == 0) ld_Pf = ld_qprior + ld_R - logf(sh_detS);
  __syncthreads();
  // I11
  Pf[e] = qpc[e] - dAB(Kgm, TmpB, i, j);
  if (e < 16) mf[e] = mpred[e] + mv(Kgm, resid, e);
  __syncthreads();

  // ---- forward scan (7 phases/step; freeze decision at loop top) ----
  int t = 1;
  for (; t < 256; ++t) {
    // T1 (+ decision from previous step's reductions)
    WP[e] = dAB(W, Pf, i, j);
    U[e] = dAB(HW, Pf, i, j);
    if (e < 16) mpred[e] = bqv[e] + mv(W, mf, e);
    if (e == 0 && t >= 14 && !sh_frozen) {
      const float sdm = fmaxf(fmaxf(red3[0], red3[1]), fmaxf(red3[2], red3[3]));
      if (sh_pfd < 3e-5f && sdm < 3e-4f) {
        sh_frozen = 1;
        sh_fdelta = sh_tstep - 0.5f * (CT16 + ld_pem) - 0.5f * (CT16 + ld_ptr)
                    + 0.5f * (CT16 + sh_ldb) + 8.f;
      }
    }
    __syncthreads();
    if (sh_frozen) break;
    const float* y = sObs + t * 16;
    // T2
    Ppred[e] = dABT(WP, W, i, j) + Qm[e];
    Smat[e] = dABT(U, HW, i, j) + HQH[e];
    PHt[e] = dABT(WP, HW, i, j) + QHt[e];
    if (e < 16) resid[e] = y[e] - bemv[e] - mv(Hm, mpred, e);
    __syncthreads();
    // T3
    if (wid == 0) {
      float d = reg_gj_inv(Ppred, Pi);
      if (e == 0) sh_detP = d;
    } else if (wid == 1) {
      float d = reg_gj_inv(Smat, Si);
      if (e == 64) sh_detS = d;
    } else if (wid == 2) {
      const int wl = e & 63;
#pragma unroll
      for (int q = 0; q < 4; ++q) { const int x = wl + 64 * q; Mm[x] = Sm[x] + Fo[x] + Ft[x]; }
      if (wl < 16) EOpb[wl] = mv(EOm, pb, wl);
      else if (wl < 32) Opb[wl - 16] = mv(Omo, pb, wl - 16);
    }
    __syncthreads();
    // T4
    Gm[e] = dATB(WP, Pi, i, j);
    Kgm[e] = dAB(PHt, Si, i, j);
    __syncthreads();
    // T5
    {
      const float bc = Pf[e] - dAB(Gm, WP, i, j);
      const float val = Mm[e] * bc;
      const float pfN = Ppred[e] - dABT(Kgm, PHt, i, j);
      const float df = fabsf(pfN - Pf[e]);
      Pf[e] = pfN;
      const float vs = wave_sum(val);
      const float vm = wave_max(df);
      if ((e & 63) == 0) { red[e >> 6] = vs; red2[e >> 6] = vm; }
      if (e < 16) av[e] = mf[e] - mv(Gm, mpred, e);
      else if (e < 32) mfN[e - 16] = mpred[e - 16] + mv(Kgm, resid, e - 16);
    }
    __syncthreads();
    // T6
    T1m[e] = dAB(Mm, Gm, i, j);
    NGm[e] = dAB(Nm, Gm, i, j);
    if (e >= 64 && e < 80) Mav[e - 64] = mv(Mm, av, e - 64);
    else if (e >= 80 && e < 96) Nav[e - 80] = mv(Nm, av, e - 80);
    else if (e >= 96 && e < 112) hv[e - 96] = rv[e - 96] + EOpb[e - 96] + w2[e - 96];
    if (e == 1) {
      float s = 0.f;
      for (int k = 0; k < 16; ++k) s = fmaf(pb[k], Opb[k], s);
      sh_d3 = s;
    }
    if (e == 0) {
      const float tstep = red[0] + red[1] + red[2] + red[3];
      sh_pfd = fmaxf(fmaxf(red2[0], red2[1]), fmaxf(red2[2], red2[3]));
      const float ldP = logf(sh_detP), ldS = logf(sh_detS);
      const float ldb = ld_Pf + ld_Q - ldP;
      sc_const += tstep - 0.5f * (CT16 + ld_pem) - 0.5f * (CT16 + ld_ptr)
                  + 0.5f * (CT16 + ldb) + 8.f;
      ld_Pf = ldP + ld_R - ldS;
      sh_tstep = tstep; sh_ldb = ldb;
    }
    __syncthreads();
    // T7: S update + delta-reduce; fused rv update; mf/pb; dots; G store
    {
      const float sN = dATB(Gm, T1m, i, j) - NGm[j * 16 + i] - NGm[e] + Omt[e];
      const float sd = fabsf(sN - Sm[e]);
      Sm[e] = sN;
      const float vm = wave_max(sd);
      if ((e & 63) == 0) red3[e >> 6] = vm;
    }
    if (e < 16) {
      float s = 0.f;
#pragma unroll
      for (int k = 0; k < 16; ++k) s = fmaf(Gm[k * 16 + e], hv[k] + Mav[k], s);
      rv[e] = s - Nav[e] - q2[e];
    } else if (e < 32) pb[e - 16] = pbemv[e - 16] - y[e - 16];
    else if (e < 48) mf[e - 32] = mfN[e - 32];
    if (e == 0) {
      float d1 = 0.f, d2 = 0.f;
      for (int k = 0; k < 16; ++k) { d1 = fmaf(av[k], Mav[k], d1); d2 = fmaf(av[k], hv[k], d2); }
      sc_c += d1 + 2.f * d2 + sh_d3 + ctb;
    }
    g_Gstore[(t - 1) * 256 + e] = Gm[e];
    __syncthreads();
  }

  const int tb = t;
  if (tb < 256) {
    // ---- precompute fused frozen operators (3 phases) ----
    // A1 = (I-KgH)W, c1 = bq - KgH bq - Kg bem  (mf' = A1 mf + Kg y + c1)
    // Av = I-GW, ca = -G bq, av = Av mf + ca; MAv = M Av, mca = M ca
    // B1 = G^T MAv - N Av; c2 = G^T(w2+mca) - N ca - q2
    // rv' = G^T rv + B1 mf + (G^T EOm) pb + c2
    // PA
    T1m[e] = dAB(Kgm, Hm, i, j);                       // KH
    NGm[e] = ((i == j) ? 1.f : 0.f) - dAB(Gm, W, i, j);  // Av
    Mm[e] = Sm[e] + Fo[e] + Ft[e];
    GTp[i * PAD + j] = Gm[j * 16 + i];
    Kgp[i * PAD + j] = Kgm[e];
    EOmp[i * PAD + j] = EOm[e];
    Omop[i * PAD + j] = Omo[e];
    if (e < 16) ca[e] = -mv(Gm, bqv, e);
    else if (e < 32) pbBuf[0][e - 16] = pb[e - 16];
    __syncthreads();
    // PB
    A1p[i * PAD + j] = W[e] - dAB(T1m, W, i, j);
    {
      const float mav = dAB(Mm, NGm, i, j);
      Pi[e] = mav;
      MAvp[i * PAD + j] = mav;
    }
    Si[e] = dAB(Nm, NGm, i, j);  // NAv
    Avp[i * PAD + j] = NGm[e];
    if (e < 16) { mca[e] = mv(Mm, ca, e); w2mca[e] = w2[e] + mca[e]; }
    else if (e < 32) nca[e - 16] = mv(Nm, ca, e - 16);
    else if (e < 48) {
      const int r = e - 32;
      c1[r] = bqv[r] - mv(T1m, bqv, r) - mv(Kgm, bemv, r);
    }
    __syncthreads();
    // PC
    B1p[i * PAD + j] = dATB(Gm, Pi, i, j) - Si[e];
    GEOp[i * PAD + j] = dATB(Gm, EOm, i, j);
    if (e < 16) c2[e] = mvT(Gm, w2mca, e) - nca[e] - q2[e];
    __syncthreads();

    // ---- frozen loop: 2 barriers/step ----
    int cur = 0;
    float facc = 0.f;
    const int g = e >> 4, r = e & 15;
    for (; t < 256; ++t) {
      const float* yt = sObs + t * 16;
      const float* pbc = pbBuf[cur];
      float* pbn = pbBuf[cur ^ 1];
      // P1: all matvecs
      if (g == 0) v1[r] = rowdot(A1p, r, mf);
      else if (g == 1) v2[r] = rowdot(Kgp, r, yt);
      else if (g == 2) v3[r] = rowdot(GTp, r, rv);
      else if (g == 3) v4[r] = rowdot(B1p, r, mf);
      else if (g == 4) v5[r] = rowdot(GEOp, r, pbc);
      else if (g == 5) av[r] = rowdot(Avp, r, mf) + ca[r];
      else if (g == 6) Mav[r] = rowdot(MAvp, r, mf) + mca[r];
      else if (g == 7) hv[r] = rowdot(EOmp, r, pbc) + rv[r] + w2[r];
      else if (g == 8) v8[r] = rowdot(Omop, r, pbc);
      else if (g == 9) pbn[r] = pbemv[r] - yt[r];
      __syncthreads();
      // P2: combines + dots
      if (e >= 64 && e < 80) {
        const int x = e - 64;
        mf[x] = v1[x] + v2[x] + c1[x];
      } else if (e >= 80 && e < 96) {
        const int x = e - 80;
        rv[x] = v3[x] + v4[x] + v5[x] + c2[x];
      }
      if (e < 64) {
        const int l = e & 15;
        float part;
        if (e < 16) part = av[l] * Mav[l];
        else if (e < 32) part = av[l] * hv[l];
        else if (e < 48) part = pbc[l] * v8[l];
        else part = 0.f;
        part += __shfl_xor(part, 1);
        part += __shfl_xor(part, 2);
        part += __shfl_xor(part, 4);
        part += __shfl_xor(part, 8);
        const float s2v = __shfl(part, 16);
        const float s3v = __shfl(part, 32);
        if (e == 0) facc += part + 2.f * s2v + s3v + ctb;
      }
      __syncthreads();
      cur ^= 1;
    }
    if (e < 16) pb[e] = pbBuf[cur][e];
    if (e == 0) {
      sc_c += facc;
      sc_const += (float)(256 - tb) * sh_fdelta;
    }
    __syncthreads();
  }

  // ---- final terms (all but tr_sum) ----
  g_Pff[e] = Pf[e];
  WP[e] = dAB(Pf, Em, i, j);  // PE = Pf * E
  if (e < 16) tv1[e] = mv(Sm, mf, e);
  else if (e < 32) tv2[e - 16] = pb[e - 16] + mv(Em, mf, e - 16);
  __syncthreads();
  {
    const float v = wave_sum(EOm[e] * WP[e]);
    if ((e & 63) == 0) red[e >> 6] = v;
  }
  if (e < 16) Opb[e] = mv(Omo, tv2, e);
  __syncthreads();
  if (e == 0) {
    const float tr_p = red[0] + red[1] + red[2] + red[3];
    float ev1 = 0.f, ev2 = 0.f, evp = 0.f;
    for (int k = 0; k < 16; ++k) {
      ev1 = fmaf(mf[k], tv1[k], ev1);
      ev2 = fmaf(rv[k], mf[k], ev2);
      evp = fmaf(tv2[k], Opb[k], evp);
    }
    g_partial = sc_const + 0.5f * (CT16 + ld_Pf) + (ev1 + 2.f * ev2 + sc_c)
                + tr_p + evp + 8.f;
  }
  __syncthreads();

  // ---- suffix products: Suf_{tb-1} = Ginf^(256-tb) by binary powering,
  //      then sequential chain for t < tb ----
  g_Ginf[e] = Gm[e];
  if (e == 0) g_tb = tb;
  {
    float *Rc = WP, *Rn = T1m, *Bc = U, *Bn = NGm;
    Rc[e] = (i == j) ? 1.f : 0.f;
    Bc[e] = Gm[e];
    __syncthreads();
    int E = 256 - tb;
    while (E) {
      Rn[e] = (E & 1) ? dAB(Rc, Bc, i, j) : Rc[e];
      if (E > 1) Bn[e] = dAB(Bc, Bc, i, j);
      __syncthreads();
      float* tp = Rc; Rc = Rn; Rn = tp;
      tp = Bc; Bc = Bn; Bn = tp;
      E >>= 1;
    }
    g_Suf[(tb - 1) * 256 + e] = Rc[e];
    for (int tt = tb - 1; tt >= 1; --tt) {
      const float4* gr = (const float4*)(g_Gstore + (tt - 1) * 256 + i * 16);
      const float4 a0 = gr[0], a1 = gr[1], a2 = gr[2], a3 = gr[3];
      float s = 0.f;
      s = fmaf(a0.x, Rc[0 * 16 + j], s);  s = fmaf(a0.y, Rc[1 * 16 + j], s);
      s = fmaf(a0.z, Rc[2 * 16 + j], s);  s = fmaf(a0.w, Rc[3 * 16 + j], s);
      s = fmaf(a1.x, Rc[4 * 16 + j], s);  s = fmaf(a1.y, Rc[5 * 16 + j], s);
      s = fmaf(a1.z, Rc[6 * 16 + j], s);  s = fmaf(a1.w, Rc[7 * 16 + j], s);
      s = fmaf(a2.x, Rc[8 * 16 + j], s);  s = fmaf(a2.y, Rc[9 * 16 + j], s);
      s = fmaf(a2.z, Rc[10 * 16 + j], s); s = fmaf(a2.w, Rc[11 * 16 + j], s);
      s = fmaf(a3.x, Rc[12 * 16 + j], s); s = fmaf(a3.y, Rc[13 * 16 + j], s);
      s = fmaf(a3.z, Rc[14 * 16 + j], s); s = fmaf(a3.w, Rc[15 * 16 + j], s);
      Rn[e] = s;
      g_Suf[(tt - 1) * 256 + e] = s;
      __syncthreads();
      float* tp = Rc; Rc = Rn; Rn = tp;
    }
  }
}

// One block per t: trace terms tr(Om A Pf A). Frozen region uses powers of Ginf.
__global__ void __launch_bounds__(256)
lgq_trace(const float* __restrict__ pew, const float* __restrict__ ptw) {
  const int e = threadIdx.x, i = e >> 4, j = e & 15, b = blockIdx.x;
  __shared__ float Pfs[256], OmA[256], OmtS[256], EmS[256], PwS[256];
  __shared__ float Sm1[256], Sf[256], A1[256], A2[256];
  __shared__ float T1[256], NG[256], Kx[256], S2[256], GinfS[256];
  __shared__ float red[4];
  const int tb = g_tb;
  Pfs[e] = g_Pff[e];
  OmtS[e] = g_Omt[e];
  EmS[e] = pew[e];
  PwS[e] = ptw[e];
  OmA[e] = (b == 0) ? g_Om0[e] : g_Omo[e];
  if (b >= tb) {
    // Suf_b = Ginf^(255-b); Suf_{b-1} = Ginf * Suf_b
    GinfS[e] = g_Ginf[e];
    float *Rc = T1, *Rn = NG, *Bc = Kx, *Bn = S2;
    Rc[e] = (i == j) ? 1.f : 0.f;
    Bc[e] = GinfS[e];
    __syncthreads();
    int E = 255 - b;
    while (E) {
      Rn[e] = (E & 1) ? dAB(Rc, Bc, i, j) : Rc[e];
      if (E > 1) Bn[e] = dAB(Bc, Bc, i, j);
      __syncthreads();
      float* tp = Rc; Rc = Rn; Rn = tp;
      tp = Bc; Bc = Bn; Bn = tp;
      E >>= 1;
    }
    Sf[e] = Rc[e];
    Sm1[e] = dAB(GinfS, Rc, i, j);
    __syncthreads();
  } else {
    if (b == 0) {
      Sm1[e] = g_Suf[e];
      Sf[e] = 0.f;
    } else {
      Sm1[e] = g_Suf[(b - 1) * 256 + e];
      Sf[e] = g_Suf[b * 256 + e];
    }
    __syncthreads();
  }
  if (b == 0) {
    A1[e] = Sm1[e];
    A2[e] = 0.f;
  } else {
    A1[e] = dAB(EmS, Sm1, i, j);
    A2[e] = dAB(PwS, Sm1, i, j) - Sf[e];
  }
  __syncthreads();
  T1[e] = dAB(OmA, A1, i, j);
  NG[e] = dAB(Pfs, A1, i, j);
  Kx[e] = dAB(OmtS, A2, i, j);
  S2[e] = dAB(Pfs, A2, i, j);
  __syncthreads();
  float val = T1[e] * NG[j * 16 + i] + Kx[e] * S2[j * 16 + i];
  val = wave_sum(val);
  if ((e & 63) == 0) red[e >> 6] = val;
  __syncthreads();
  if (e == 0) atomicAdd(&g_acc, red[0] + red[1] + red[2] + red[3]);
}

__global__ void lgq_fin(float* __restrict__ out) { out[0] = g_partial + g_acc; }

extern "C" void kernel_launch(void* const* d_in, const int* in_sizes, int n_in,
                              void* d_out, int out_size, void* d_ws, size_t ws_size,
                              hipStream_t stream) {
  (void)in_sizes; (void)n_in; (void)out_size; (void)d_ws; (void)ws_size;
  lgq_fwd<<<dim3(1), dim3(256), 0, stream>>>(
      (const float*)d_in[0], (const float*)d_in[1], (const float*)d_in[2],
      (const float*)d_in[3], (const float*)d_in[4], (const float*)d_in[5],
      (const float*)d_in[6], (const float*)d_in[7], (const float*)d_in[8],
      (const float*)d_in[9], (const float*)d_in[10], (const float*)d_in[11],
      (const float*)d_in[12], (const float*)d_in[13], (const float*)d_in[14],
      (const float*)d_in[15], (const float*)d_in[16]);
  lgq_trace<<<dim3(256), dim3(256), 0, stream>>>((const float*)d_in[6],
                                                 (const float*)d_in[3]);
  lgq_fin<<<dim3(1), dim3(1), 0, stream>>>((float*)d_out);
}

// Round 4
// 182.221 us; speedup vs baseline: 15.8514x; 1.8278x over previous
//
#include <hip/hip_runtime.h>
#include <cmath>

#define L2PI 1.8378770664093453f
#define CT16 (16.f * L2PI)

// Per-launch scratch (fully rewritten every call before being read).
__device__ __align__(16) float g_Gstore[255 * 256];
__device__ __align__(16) float g_Suf[256 * 256];
__device__ float g_Pff[256], g_Om0[256], g_Omo[256], g_Omt[256], g_Ginf[256];
__device__ float g_partial, g_acc;
__device__ int g_tb;

__device__ __forceinline__ float dAB(const float* A, const float* B, int i, int j) {
  float s = 0.f;
#pragma unroll
  for (int k = 0; k < 16; ++k) s = fmaf(A[i * 16 + k], B[k * 16 + j], s);
  return s;
}
__device__ __forceinline__ float dATB(const float* A, const float* B, int i, int j) {
  float s = 0.f;
#pragma unroll
  for (int k = 0; k < 16; ++k) s = fmaf(A[k * 16 + i], B[k * 16 + j], s);
  return s;
}
__device__ __forceinline__ float dABT(const float* A, const float* B, int i, int j) {
  float s = 0.f;
#pragma unroll
  for (int k = 0; k < 16; ++k) s = fmaf(A[i * 16 + k], B[j * 16 + k], s);
  return s;
}
__device__ __forceinline__ float mv(const float* M, const float* v, int r) {
  float s = 0.f;
#pragma unroll
  for (int k = 0; k < 16; ++k) s = fmaf(M[r * 16 + k], v[k], s);
  return s;
}
__device__ __forceinline__ float mvT(const float* M, const float* v, int r) {
  float s = 0.f;
#pragma unroll
  for (int k = 0; k < 16; ++k) s = fmaf(M[k * 16 + r], v[k], s);
  return s;
}
__device__ __forceinline__ float wave_sum(float v) {
#pragma unroll
  for (int off = 32; off; off >>= 1) v += __shfl_down(v, off);
  return v;
}
__device__ __forceinline__ float wave_max(float v) {
#pragma unroll
  for (int off = 32; off; off >>= 1) v = fmaxf(v, __shfl_down(v, off));
  return v;
}

// Register-resident Gauss-Jordan inverse of SPD 16x16, one wave, barrier-free.
__device__ __forceinline__ float reg_gj_inv(const float* __restrict__ src,
                                            float* __restrict__ dst) {
  const int wl = threadIdx.x & 63;
  const int col = wl & 15, rg = wl >> 4;
  float aA[4], aI[4];
#pragma unroll
  for (int q = 0; q < 4; ++q) {
    const int r = rg + 4 * q;
    aA[q] = src[r * 16 + col];
    aI[q] = (r == col) ? 1.f : 0.f;
  }
  float det = 1.f;
#pragma unroll
  for (int k = 0; k < 16; ++k) {
    const int kq = k >> 2, kr = k & 3;
    const float piv = __shfl(aA[kq], (kr << 4) | k);
    det *= piv;
    const float rp = 1.f / piv;
    const float pA = __shfl(aA[kq], (kr << 4) | col);
    const float pI = __shfl(aI[kq], (kr << 4) | col);
    float f[4];
    f[0] = __shfl(aA[0], (rg << 4) | k);
    f[1] = __shfl(aA[1], (rg << 4) | k);
    f[2] = __shfl(aA[2], (rg << 4) | k);
    f[3] = __shfl(aA[3], (rg << 4) | k);
#pragma unroll
    for (int q = 0; q < 4; ++q) {
      const float tq = f[q] * rp;
      const float nA = fmaf(-tq, pA, aA[q]);
      const float nI = fmaf(-tq, pI, aI[q]);
      if (q == kq) {
        const bool isp = (rg == kr);
        aA[q] = isp ? pA * rp : nA;
        aI[q] = isp ? pI * rp : nI;
      } else {
        aA[q] = nA;
        aI[q] = nI;
      }
    }
  }
#pragma unroll
  for (int q = 0; q < 4; ++q) dst[(rg + 4 * q) * 16 + col] = aI[q];
  return det;
}

__global__ void __launch_bounds__(256)
lgq_fwd(const float* __restrict__ obs,
        const float* __restrict__ ppm, const float* __restrict__ ppc,
        const float* __restrict__ ptw, const float* __restrict__ ptb,
        const float* __restrict__ ptc, const float* __restrict__ pew,
        const float* __restrict__ peb, const float* __restrict__ pec,
        const float* __restrict__ qpm, const float* __restrict__ qpc,
        const float* __restrict__ qtw, const float* __restrict__ qtb,
        const float* __restrict__ qtc, const float* __restrict__ qew,
        const float* __restrict__ qeb, const float* __restrict__ qec) {
  const int e = threadIdx.x;
  const int i = e >> 4, j = e & 15;
  const int wid = e >> 6;
  const int lane = e & 63;

  __shared__ float W[256], Qm[256], Hm[256], Rm[256], Em[256], Pwm[256];
  __shared__ float HW[256], QHt[256], HQH[256], TmpB[256];
  __shared__ float Om0[256], Omo[256], Omt[256], Fo[256], Ft[256], Nm[256], EOm[256];
  __shared__ float Sm[256], Pf[256];
  __shared__ float WP[256], U[256], Ppred[256], Smat[256], PHt[256];
  __shared__ float Pi[256], Si[256], Gm[256], Kgm[256], Mm[256], T1m[256], NGm[256];
  __shared__ float sObs[256 * 16];
  __shared__ float detPArr[256], detSArr[256], tstepArr[256], d3all[256];
  __shared__ float lp[256], ls[256];
  __shared__ float mf[16], mfN[16], rv[16], pb[16], bqv[16], bemv[16], pbemv[16],
      ptbv[16];
  __shared__ float w2[16], q2[16], mpred[16], av[16], Mav[16], hv[16], Nav[16];
  __shared__ float EOpb[16], resid[16], tv1[16], tv2[16], Opf[16];
  __shared__ float ca[16], mca[16], nca[16], c1[16], cg1[16], qc[16], epbm[16];
  __shared__ float dotArr[64];
  __shared__ float red[4], red2[4], red3[4], dets[6];
  __shared__ float sc_const, sc_c, ctb, sh_cstep;
  __shared__ float ld_pprior, ld_ptr, ld_pem, ld_Q, ld_R, ld_qprior, ld_Pf;
  __shared__ float sh_detS;
  __shared__ int sh_frozen;

  // I0: load fixed inputs + stage obs into LDS
  W[e] = qtw[e]; Qm[e] = qtc[e]; Hm[e] = qew[e]; Rm[e] = qec[e];
  Em[e] = pew[e]; Pwm[e] = ptw[e];
  {
    const float4* o4 = (const float4*)obs;
    float4* s4 = (float4*)sObs;
#pragma unroll
    for (int q = 0; q < 4; ++q) s4[e + 256 * q] = o4[e + 256 * q];
  }
  if (e < 16) { bqv[e] = qtb[e]; bemv[e] = qeb[e]; pbemv[e] = peb[e]; ptbv[e] = ptb[e]; }
  if (e == 0) { sh_frozen = 0; g_acc = 0.f; }
  __syncthreads();
  // I1
  HW[e] = dAB(Hm, W, i, j);
  TmpB[e] = dAB(Hm, Qm, i, j);
  __syncthreads();
  // I2
  HQH[e] = dABT(TmpB, Hm, i, j) + Rm[e];
  QHt[e] = TmpB[j * 16 + i];
  __syncthreads();
  // I3: six fixed inversions, two per wave
  if (wid == 0) {
    float d0 = reg_gj_inv(ppc, Pi);
    float d1 = reg_gj_inv(ptc, Si);
    if (e == 0) { dets[0] = d0; dets[1] = d1; }
  } else if (wid == 1) {
    float d2 = reg_gj_inv(pec, Gm);
    float d3 = reg_gj_inv(qtc, Kgm);
    if (e == 64) { dets[2] = d2; dets[3] = d3; }
  } else if (wid == 2) {
    float d4 = reg_gj_inv(qec, T1m);
    float d5 = reg_gj_inv(qpc, NGm);
    if (e == 128) { dets[4] = d4; dets[5] = d5; }
  }
  __syncthreads();
  // I4
  Om0[e] = -0.5f * Pi[e];
  Omt[e] = -0.5f * Si[e];
  Omo[e] = -0.5f * Gm[e];
  if (e == 0) {
    ld_pprior = logf(dets[0]); ld_ptr = logf(dets[1]); ld_pem = logf(dets[2]);
    ld_Q = logf(dets[3]); ld_R = logf(dets[4]); ld_qprior = logf(dets[5]);
  }
  __syncthreads();
  // I5
  g_Om0[e] = Om0[e]; g_Omo[e] = Omo[e]; g_Omt[e] = Omt[e];
  TmpB[e] = dAB(Omo, Em, i, j);
  Nm[e] = dAB(Omt, Pwm, i, j);
  EOm[e] = dATB(Em, Omo, i, j);
  Sm[e] = Om0[e];
  __syncthreads();
  // I6: fixed quadratic mats, vectors, and d3all[t] = pb_t^T Omo pb_t for ALL t
  Fo[e] = dATB(Em, TmpB, i, j);
  Ft[e] = dATB(Pwm, Nm, i, j);
  if (e < 16) w2[e] = mvT(Nm, ptbv, e);
  else if (e < 32) q2[e - 16] = mv(Omt, ptbv, e - 16);
  else if (e < 48) rv[e - 32] = -mv(Om0, ppm, e - 32);
  else if (e < 64) pb[e - 48] = pbemv[e - 48] - sObs[e - 48];
  {
    const int rr = e & 15, tg = e >> 4;
#pragma unroll
    for (int it = 0; it < 16; ++it) {
      const int tt = it * 16 + tg;
      float s = 0.f;
#pragma unroll
      for (int k = 0; k < 16; ++k)
        s = fmaf(Omo[rr * 16 + k], pbemv[k] - sObs[tt * 16 + k], s);
      s *= (pbemv[rr] - sObs[tt * 16 + rr]);
      s += __shfl_xor(s, 1); s += __shfl_xor(s, 2);
      s += __shfl_xor(s, 4); s += __shfl_xor(s, 8);
      if (rr == 0) d3all[tt] = s;
    }
  }
  __syncthreads();
  // I7
  if (e == 0) {
    float s = 0.f, ct = 0.f;
    for (int k = 0; k < 16; ++k) { s = fmaf(ppm[k], rv[k], s); ct = fmaf(ptbv[k], q2[k], ct); }
    sc_c = -s;
    ctb = ct;
    sc_const = -0.5f * (CT16 + ld_pprior) - 0.5f * (CT16 + ld_pem);
    sh_cstep = 8.f - 0.5f * CT16 - 0.5f * (ld_pem + ld_ptr);
  }
  if (e < 16) mpred[e] = qpm[e];
  TmpB[e] = dAB(Hm, qpc, i, j);
  __syncthreads();
  // I8
  Smat[e] = dABT(TmpB, Hm, i, j) + Rm[e];
  if (e < 16) resid[e] = sObs[e] - bemv[e] - mv(Hm, mpred, e);
  __syncthreads();
  // I9
  if (wid == 0) {
    float d = reg_gj_inv(Smat, Si);
    if (e == 0) sh_detS = d;
  }
  __syncthreads();
  // I10
  Kgm[e] = dATB(TmpB, Si, i, j);
  if (e == 0) ld_Pf = ld_qprior + ld_R - logf(sh_detS);  // ld_Pf_0
  __syncthreads();
  // I11
  Pf[e] = qpc[e] - dAB(Kgm, TmpB, i, j);
  if (e < 16) mf[e] = mpred[e] + mv(Kgm, resid, e);
  __syncthreads();

  // ---- forward scan: 6 phases/step, no logf / no serial dots on the path ----
  float fd = 0.f;   // per-lane d1 (lanes 0-15 of wave0) / d2 (lanes 16-31) accum
  int t = 1;
  for (; t < 256; ++t) {
    const float* y = sObs + t * 16;
    // T1: staging + closure of step t-1
    WP[e] = dAB(W, Pf, i, j);
    U[e] = dAB(HW, Pf, i, j);
    if (e < 16) mpred[e] = bqv[e] + mv(W, mf, e);
    if (t > 1) {
      const float sN = dATB(Gm, T1m, i, j) - NGm[j * 16 + i] - NGm[e] + Omt[e];
      const float sd = fabsf(sN - Sm[e]);
      Sm[e] = sN;
      const float vm = wave_max(sd);
      if (lane == 0) red3[wid] = vm;
      if (e < 16) {
        float s = 0.f;
#pragma unroll
        for (int k = 0; k < 16; ++k) s = fmaf(Gm[k * 16 + e], hv[k] + Mav[k], s);
        rv[e] = s - Nav[e] - q2[e];
      }
      if (wid == 0) {
        if (lane < 16) fd = fmaf(av[lane], Mav[lane], fd);
        else if (lane < 32) fd = fmaf(av[lane - 16], hv[lane - 16], fd);
      }
    }
    __syncthreads();
    // T2: predicted covariances (+ freeze decision from step t-1 deltas)
    Ppred[e] = dABT(WP, W, i, j) + Qm[e];
    Smat[e] = dABT(U, HW, i, j) + HQH[e];
    PHt[e] = dABT(WP, HW, i, j) + QHt[e];
    if (e < 16) resid[e] = y[e] - bemv[e] - mv(Hm, mpred, e);
    if (e == 0 && t >= 10) {
      const float pfd = fmaxf(fmaxf(red2[0], red2[1]), fmaxf(red2[2], red2[3]));
      const float sdm = fmaxf(fmaxf(red3[0], red3[1]), fmaxf(red3[2], red3[3]));
      if (pfd < 1e-4f && sdm < 1e-3f) sh_frozen = 1;
    }
    __syncthreads();
    if (sh_frozen) break;
    // T3: two inversions (waves 0,1) + M / EOpb (wave 2)
    if (wid == 0) {
      float d = reg_gj_inv(Ppred, Pi);
      if (e == 0) detPArr[t] = d;
    } else if (wid == 1) {
      float d = reg_gj_inv(Smat, Si);
      if (e == 64) detSArr[t] = d;
    } else if (wid == 2) {
      const int wl = e & 63;
#pragma unroll
      for (int q = 0; q < 4; ++q) { const int x = wl + 64 * q; Mm[x] = Sm[x] + Fo[x] + Ft[x]; }
      if (wl < 16) EOpb[wl] = mv(EOm, pb, wl);
    }
    __syncthreads();
    // T4: gains
    Gm[e] = dATB(WP, Pi, i, j);
    Kgm[e] = dAB(PHt, Si, i, j);
    __syncthreads();
    // T5: trace partials, Pf update + delta, av, mfN
    {
      const float bc = Pf[e] - dAB(Gm, WP, i, j);
      const float val = Mm[e] * bc;
      const float pfN = Ppred[e] - dABT(Kgm, PHt, i, j);
      const float df = fabsf(pfN - Pf[e]);
      Pf[e] = pfN;
      const float vs = wave_sum(val);
      const float vm = wave_max(df);
      if (lane == 0) { red[wid] = vs; red2[wid] = vm; }
      if (e < 16) av[e] = mf[e] - mv(Gm, mpred, e);
      else if (e < 32) mfN[e - 16] = mpred[e - 16] + mv(Kgm, resid, e - 16);
    }
    __syncthreads();
    // T6: M*G, N*G, matvecs, state copies, tstep bookkeeping, G store
    T1m[e] = dAB(Mm, Gm, i, j);
    NGm[e] = dAB(Nm, Gm, i, j);
    if (e >= 64 && e < 80) Mav[e - 64] = mv(Mm, av, e - 64);
    else if (e >= 80 && e < 96) Nav[e - 80] = mv(Nm, av, e - 80);
    else if (e >= 96 && e < 112) hv[e - 96] = rv[e - 96] + EOpb[e - 96] + w2[e - 96];
    else if (e >= 112 && e < 128) mf[e - 112] = mfN[e - 112];
    else if (e >= 128 && e < 144) pb[e - 128] = pbemv[e - 128] - y[e - 128];
    if (e == 0) {
      const float tstep = red[0] + red[1] + red[2] + red[3];
      tstepArr[t] = tstep;
      sc_const += tstep + sh_cstep;
    }
    g_Gstore[(t - 1) * 256 + e] = Gm[e];
    __syncthreads();
  }

  const int tb = t;  // steps 1..tb-1 fully processed
  if (sh_frozen) {
    // ---- build fused frozen operators (3 phases) ----
    // PA
    T1m[e] = dAB(Kgm, Hm, i, j);                          // KH
    NGm[e] = ((i == j) ? 1.f : 0.f) - dAB(Gm, W, i, j);   // Av
    Mm[e] = Sm[e] + Fo[e] + Ft[e];
    if (e < 16) ca[e] = -mv(Gm, bqv, e);
    else if (e < 32) epbm[e - 16] = mv(EOm, pbemv, e - 16);
    __syncthreads();
    // PB
    WP[e] = W[e] - dAB(T1m, W, i, j);                     // A1
    Pi[e] = dAB(Mm, NGm, i, j);                           // MAv
    Si[e] = dAB(Nm, NGm, i, j);                           // NAv
    if (e < 16) mca[e] = mv(Mm, ca, e);
    else if (e < 32) nca[e - 16] = mv(Nm, ca, e - 16);
    else if (e < 48) {
      const int r = e - 32;
      c1[r] = bqv[r] - mv(T1m, bqv, r) - mv(Kgm, bemv, r);
    }
    __syncthreads();
    // PC
    U[e] = dATB(Gm, Pi, i, j) - Si[e];                    // B1
    Ppred[e] = dATB(Gm, EOm, i, j);                       // GEO
    if (e < 16) {
      float s = 0.f;
#pragma unroll
      for (int k = 0; k < 16; ++k)
        s = fmaf(Gm[k * 16 + e], w2[k] + mca[k] + epbm[k], s);
      cg1[e] = s - nca[e] - q2[e];
    } else if (e < 32) {
      const int r = e - 16;
      qc[r] = mca[r] + 2.f * w2[r] + 2.f * epbm[r];
    }
    __syncthreads();
    // ---- frozen loop: wave 0 only, zero barriers, register/shuffle ----
    if (wid == 0) {
      const int g = lane >> 4, r = lane & 15;
      float Trow[32], Brow[16], Crow[16];
#pragma unroll
      for (int k = 0; k < 16; ++k) {
        Trow[k] = (g == 0) ? WP[r * 16 + k]
                : (g == 1) ? U[r * 16 + k]
                : (g == 2) ? NGm[r * 16 + k] : Pi[r * 16 + k];
        Trow[16 + k] = (g == 1) ? Gm[k * 16 + r]
                     : (g == 3) ? ((k == r) ? 2.f : 0.f) : 0.f;
        Brow[k] = (g == 0) ? Kgm[r * 16 + k] : 0.f;
        Crow[k] = (g == 1) ? -Ppred[r * 16 + k]
                : (g == 3) ? -2.f * EOm[r * 16 + k] : 0.f;
      }
      const float cfold = (g == 0) ? c1[r] : (g == 1) ? cg1[r]
                        : (g == 2) ? ca[r] : qc[r];
      float x = (g == 0) ? mf[r] : (g == 1) ? rv[r] : 0.f;
      float yprev = sObs[(tb - 1) * 16 + r];
      float facc = 0.f;
      for (int tt = tb; tt < 256; ++tt) {
        const float ycur = sObs[tt * 16 + r];
        float s0 = cfold, s1 = 0.f, s2 = 0.f, s3 = 0.f;
#pragma unroll
        for (int k = 0; k < 32; k += 4) {
          s0 = fmaf(Trow[k], __shfl(x, k), s0);
          s1 = fmaf(Trow[k + 1], __shfl(x, k + 1), s1);
          s2 = fmaf(Trow[k + 2], __shfl(x, k + 2), s2);
          s3 = fmaf(Trow[k + 3], __shfl(x, k + 3), s3);
        }
#pragma unroll
        for (int k = 0; k < 16; k += 2) {
          s0 = fmaf(Brow[k], __shfl(ycur, k), s0);
          s1 = fmaf(Brow[k + 1], __shfl(ycur, k + 1), s1);
          s2 = fmaf(Crow[k], __shfl(yprev, k), s2);
          s3 = fmaf(Crow[k + 1], __shfl(yprev, k + 1), s3);
        }
        const float acc = (s0 + s1) + (s2 + s3);
        const float qv = __shfl_down(acc, 16);  // lanes 32-47 get q from 48-63
        if (g == 2) facc = fmaf(acc, qv, facc);
        if (g < 2) x = acc;
        yprev = ycur;
      }
      if (g == 0) { mf[r] = x; pb[r] = pbemv[r] - sObs[255 * 16 + r]; }
      else if (g == 1) rv[r] = x;
      dotArr[lane] = (lane < 32) ? fd : (lane < 48) ? facc : 0.f;
    }
    __syncthreads();
  } else {
    // never froze (fallback): closure of step 255
    {
      const float sN = dATB(Gm, T1m, i, j) - NGm[j * 16 + i] - NGm[e] + Omt[e];
      Sm[e] = sN;
      if (e < 16) {
        float s = 0.f;
#pragma unroll
        for (int k = 0; k < 16; ++k) s = fmaf(Gm[k * 16 + e], hv[k] + Mav[k], s);
        rv[e] = s - Nav[e] - q2[e];
      }
      if (wid == 0) {
        if (lane < 16) fd = fmaf(av[lane], Mav[lane], fd);
        else if (lane < 32) fd = fmaf(av[lane - 16], hv[lane - 16], fd);
        dotArr[lane] = (lane < 32) ? fd : 0.f;
      }
    }
    __syncthreads();
  }

  // ---- E1: parallel logs + d3 reduction ----
  const int n = tb - 1;
  if (e >= 1 && e <= n) { lp[e] = logf(detPArr[e]); ls[e] = logf(detSArr[e]); }
  {
    const float v = wave_sum((e < 255) ? d3all[e] : 0.f);
    if (lane == 0) red[wid] = v;
  }
  __syncthreads();
  // ---- E2: serial epilogue (tiny) ----
  if (e == 0) {
    float lpf = ld_Pf;  // ld_Pf_0
    float sum_ldb = 0.f, ldbl = 0.f;
    for (int s = 1; s <= n; ++s) {
      ldbl = lpf + ld_Q - lp[s];
      sum_ldb += ldbl;
      lpf = lp[s] + ld_R - ls[s];
    }
    sc_const += 0.5f * sum_ldb;
    if (tb < 256) {
      const float fdelta = tstepArr[n] + sh_cstep + 0.5f * ldbl;
      sc_const += (float)(256 - tb) * fdelta;
    }
    ld_Pf = lpf;
    float dsum = 0.f;
    for (int l = 0; l < 16; ++l) dsum += dotArr[l];
    for (int l = 16; l < 32; ++l) dsum += 2.f * dotArr[l];
    for (int l = 32; l < 48; ++l) dsum += dotArr[l];
    const float d3tot = red[0] + red[1] + red[2] + red[3];
    sc_c += dsum + d3tot + 255.f * ctb;
  }
  __syncthreads();

  // ---- final terms (all but tr_sum) ----
  g_Pff[e] = Pf[e];
  WP[e] = dAB(Pf, Em, i, j);  // PE = Pf * E
  if (e < 16) tv1[e] = mv(Sm, mf, e);
  else if (e < 32) tv2[e - 16] = pb[e - 16] + mv(Em, mf, e - 16);
  __syncthreads();
  {
    const float v = wave_sum(EOm[e] * WP[e]);
    if (lane == 0) red[wid] = v;
  }
  if (e < 16) Opf[e] = mv(Omo, tv2, e);
  __syncthreads();
  if (e == 0) {
    const float tr_p = red[0] + red[1] + red[2] + red[3];
    float ev1 = 0.f, ev2 = 0.f, evp = 0.f;
    for (int k = 0; k < 16; ++k) {
      ev1 = fmaf(mf[k], tv1[k], ev1);
      ev2 = fmaf(rv[k], mf[k], ev2);
      evp = fmaf(tv2[k], Opf[k], evp);
    }
    g_partial = sc_const + 0.5f * (CT16 + ld_Pf) + (ev1 + 2.f * ev2 + sc_c)
                + tr_p + evp + 8.f;
  }
  __syncthreads();

  // ---- suffix products: Suf_{tb-1} = Ginf^(256-tb) by binary powering,
  //      then sequential chain for t < tb ----
  g_Ginf[e] = Gm[e];
  if (e == 0) g_tb = tb;
  {
    float *Rc = WP, *Rn = T1m, *Bc = U, *Bn = NGm;
    Rc[e] = (i == j) ? 1.f : 0.f;
    Bc[e] = Gm[e];
    __syncthreads();
    int E = 256 - tb;
    while (E) {
      Rn[e] = (E & 1) ? dAB(Rc, Bc, i, j) : Rc[e];
      if (E > 1) Bn[e] = dAB(Bc, Bc, i, j);
      __syncthreads();
      float* tp = Rc; Rc = Rn; Rn = tp;
      tp = Bc; Bc = Bn; Bn = tp;
      E >>= 1;
    }
    g_Suf[(tb - 1) * 256 + e] = Rc[e];
    for (int tt = tb - 1; tt >= 1; --tt) {
      const float4* gr = (const float4*)(g_Gstore + (tt - 1) * 256 + i * 16);
      const float4 a0 = gr[0], a1 = gr[1], a2 = gr[2], a3 = gr[3];
      float s = 0.f;
      s = fmaf(a0.x, Rc[0 * 16 + j], s);  s = fmaf(a0.y, Rc[1 * 16 + j], s);
      s = fmaf(a0.z, Rc[2 * 16 + j], s);  s = fmaf(a0.w, Rc[3 * 16 + j], s);
      s = fmaf(a1.x, Rc[4 * 16 + j], s);  s = fmaf(a1.y, Rc[5 * 16 + j], s);
      s = fmaf(a1.z, Rc[6 * 16 + j], s);  s = fmaf(a1.w, Rc[7 * 16 + j], s);
      s = fmaf(a2.x, Rc[8 * 16 + j], s);  s = fmaf(a2.y, Rc[9 * 16 + j], s);
      s = fmaf(a2.z, Rc[10 * 16 + j], s); s = fmaf(a2.w, Rc[11 * 16 + j], s);
      s = fmaf(a3.x, Rc[12 * 16 + j], s); s = fmaf(a3.y, Rc[13 * 16 + j], s);
      s = fmaf(a3.z, Rc[14 * 16 + j], s); s = fmaf(a3.w, Rc[15 * 16 + j], s);
      Rn[e] = s;
      g_Suf[(tt - 1) * 256 + e] = s;
      __syncthreads();
      float* tp = Rc; Rc = Rn; Rn = tp;
    }
  }
}

// One block per t: trace terms tr(Om A Pf A). Frozen region uses powers of Ginf.
__global__ void __launch_bounds__(256)
lgq_trace(const float* __restrict__ pew, const float* __restrict__ ptw) {
  const int e = threadIdx.x, i = e >> 4, j = e & 15, b = blockIdx.x;
  __shared__ float Pfs[256], OmA[256], OmtS[256], EmS[256], PwS[256];
  __shared__ float Sm1[256], Sf[256], A1[256], A2[256];
  __shared__ float T1[256], NG[256], Kx[256], S2[256], GinfS[256];
  __shared__ float red[4];
  const int tb = g_tb;
  Pfs[e] = g_Pff[e];
  OmtS[e] = g_Omt[e];
  EmS[e] = pew[e];
  PwS[e] = ptw[e];
  OmA[e] = (b == 0) ? g_Om0[e] : g_Omo[e];
  if (b >= tb) {
    GinfS[e] = g_Ginf[e];
    float *Rc = T1, *Rn = NG, *Bc = Kx, *Bn = S2;
    Rc[e] = (i == j) ? 1.f : 0.f;
    Bc[e] = GinfS[e];
    __syncthreads();
    int E = 255 - b;
    while (E) {
      Rn[e] = (E & 1) ? dAB(Rc, Bc, i, j) : Rc[e];
      if (E > 1) Bn[e] = dAB(Bc, Bc, i, j);
      __syncthreads();
      float* tp = Rc; Rc = Rn; Rn = tp;
      tp = Bc; Bc = Bn; Bn = tp;
      E >>= 1;
    }
    Sf[e] = Rc[e];
    Sm1[e] = dAB(GinfS, Rc, i, j);
    __syncthreads();
  } else {
    if (b == 0) {
      Sm1[e] = g_Suf[e];
      Sf[e] = 0.f;
    } else {
      Sm1[e] = g_Suf[(b - 1) * 256 + e];
      Sf[e] = g_Suf[b * 256 + e];
    }
    __syncthreads();
  }
  if (b == 0) {
    A1[e] = Sm1[e];
    A2[e] = 0.f;
  } else {
    A1[e] = dAB(EmS, Sm1, i, j);
    A2[e] = dAB(PwS, Sm1, i, j) - Sf[e];
  }
  __syncthreads();
  T1[e] = dAB(OmA, A1, i, j);
  NG[e] = dAB(Pfs, A1, i, j);
  Kx[e] = dAB(OmtS, A2, i, j);
  S2[e] = dAB(Pfs, A2, i, j);
  __syncthreads();
  float val = T1[e] * NG[j * 16 + i] + Kx[e] * S2[j * 16 + i];
  val = wave_sum(val);
  if ((e & 63) == 0) red[e >> 6] = val;
  __syncthreads();
  if (e == 0) atomicAdd(&g_acc, red[0] + red[1] + red[2] + red[3]);
}

__global__ void lgq_fin(float* __restrict__ out) { out[0] = g_partial + g_acc; }

extern "C" void kernel_launch(void* const* d_in, const int* in_sizes, int n_in,
                              void* d_out, int out_size, void* d_ws, size_t ws_size,
                              hipStream_t stream) {
  (void)in_sizes; (void)n_in; (void)out_size; (void)d_ws; (void)ws_size;
  lgq_fwd<<<dim3(1), dim3(256), 0, stream>>>(
      (const float*)d_in[0], (const float*)d_in[1], (const float*)d_in[2],
      (const float*)d_in[3], (const float*)d_in[4], (const float*)d_in[5],
      (const float*)d_in[6], (const float*)d_in[7], (const float*)d_in[8],
      (const float*)d_in[9], (const float*)d_in[10], (const float*)d_in[11],
      (const float*)d_in[12], (const float*)d_in[13], (const float*)d_in[14],
      (const float*)d_in[15], (const float*)d_in[16]);
  lgq_trace<<<dim3(256), dim3(256), 0, stream>>>((const float*)d_in[6],
                                                 (const float*)d_in[3]);
  lgq_fin<<<dim3(1), dim3(1), 0, stream>>>((float*)d_out);
}

// Round 5
// 170.421 us; speedup vs baseline: 16.9489x; 1.0692x over previous
//
#include <hip/hip_runtime.h>
#include <cmath>

#define L2PI 1.8378770664093453f
#define CT16 (16.f * L2PI)

// Per-launch scratch (fully rewritten every call before being read).
__device__ __align__(16) float g_Gstore[255 * 256];
__device__ float g_Pff[256], g_Om0[256], g_Omo[256], g_Omt[256], g_Ginf[256];
__device__ float g_partial, g_acc;
__device__ int g_tb;
__device__ unsigned g_cnt;

__device__ __forceinline__ float dAB(const float* A, const float* B, int i, int j) {
  float s = 0.f;
#pragma unroll
  for (int k = 0; k < 16; ++k) s = fmaf(A[i * 16 + k], B[k * 16 + j], s);
  return s;
}
__device__ __forceinline__ float dATB(const float* A, const float* B, int i, int j) {
  float s = 0.f;
#pragma unroll
  for (int k = 0; k < 16; ++k) s = fmaf(A[k * 16 + i], B[k * 16 + j], s);
  return s;
}
__device__ __forceinline__ float dABT(const float* A, const float* B, int i, int j) {
  float s = 0.f;
#pragma unroll
  for (int k = 0; k < 16; ++k) s = fmaf(A[i * 16 + k], B[j * 16 + k], s);
  return s;
}
__device__ __forceinline__ float mv(const float* M, const float* v, int r) {
  float s = 0.f;
#pragma unroll
  for (int k = 0; k < 16; ++k) s = fmaf(M[r * 16 + k], v[k], s);
  return s;
}
__device__ __forceinline__ float mvT(const float* M, const float* v, int r) {
  float s = 0.f;
#pragma unroll
  for (int k = 0; k < 16; ++k) s = fmaf(M[k * 16 + r], v[k], s);
  return s;
}
__device__ __forceinline__ float wave_sum(float v) {
#pragma unroll
  for (int off = 32; off; off >>= 1) v += __shfl_down(v, off);
  return v;
}
__device__ __forceinline__ float wave_max(float v) {
#pragma unroll
  for (int off = 32; off; off >>= 1) v = fmaxf(v, __shfl_down(v, off));
  return v;
}

// Register-resident Gauss-Jordan inverse of SPD 16x16, one wave, barrier-free.
// Lane l owns column (l&15), rows (l>>4)+4q. Writes inverse to dst, returns det.
__device__ __forceinline__ float reg_gj_core(const float* __restrict__ src,
                                             float aI[4]) {
  const int wl = threadIdx.x & 63;
  const int col = wl & 15, rg = wl >> 4;
  float aA[4];
#pragma unroll
  for (int q = 0; q < 4; ++q) {
    const int r = rg + 4 * q;
    aA[q] = src[r * 16 + col];
    aI[q] = (r == col) ? 1.f : 0.f;
  }
  float det = 1.f;
#pragma unroll
  for (int k = 0; k < 16; ++k) {
    const int kq = k >> 2, kr = k & 3;
    const float piv = __shfl(aA[kq], (kr << 4) | k);
    det *= piv;
    const float rp = 1.f / piv;
    const float pA = __shfl(aA[kq], (kr << 4) | col);
    const float pI = __shfl(aI[kq], (kr << 4) | col);
    float f[4];
    f[0] = __shfl(aA[0], (rg << 4) | k);
    f[1] = __shfl(aA[1], (rg << 4) | k);
    f[2] = __shfl(aA[2], (rg << 4) | k);
    f[3] = __shfl(aA[3], (rg << 4) | k);
#pragma unroll
    for (int q = 0; q < 4; ++q) {
      const float tq = f[q] * rp;
      const float nA = fmaf(-tq, pA, aA[q]);
      const float nI = fmaf(-tq, pI, aI[q]);
      if (q == kq) {
        const bool isp = (rg == kr);
        aA[q] = isp ? pA * rp : nA;
        aI[q] = isp ? pI * rp : nI;
      } else {
        aA[q] = nA;
        aI[q] = nI;
      }
    }
  }
  return det;
}

__device__ __forceinline__ float reg_gj_inv(const float* __restrict__ src,
                                            float* __restrict__ dst) {
  const int wl = threadIdx.x & 63;
  const int col = wl & 15, rg = wl >> 4;
  float aI[4];
  const float det = reg_gj_core(src, aI);
#pragma unroll
  for (int q = 0; q < 4; ++q) dst[(rg + 4 * q) * 16 + col] = aI[q];
  return det;
}

// GJ inverse fused with a product, inverse never touches LDS.
// MODE 0: dst = Bm^T * inv   (dst[i][j] = sum_k Bm[k][i] * inv[k][j])
// MODE 1: dst = Bm * inv     (dst[i][j] = sum_k Bm[i][k] * inv[k][j])
template <int MODE>
__device__ __forceinline__ float gj_inv_mul(const float* __restrict__ src,
                                            const float* __restrict__ Bm,
                                            float* __restrict__ dst) {
  const int wl = threadIdx.x & 63;
  const int col = wl & 15, rg = wl >> 4;
  float aI[4];
  const float det = reg_gj_core(src, aI);
  float part[16];
#pragma unroll
  for (int ii = 0; ii < 16; ++ii) {
    float s = 0.f;
#pragma unroll
    for (int q = 0; q < 4; ++q) {
      const int k = rg + 4 * q;
      s = fmaf(MODE == 0 ? Bm[k * 16 + ii] : Bm[ii * 16 + k], aI[q], s);
    }
    part[ii] = s;
  }
#pragma unroll
  for (int ii = 0; ii < 16; ++ii) {
    part[ii] += __shfl_xor(part[ii], 16);
    part[ii] += __shfl_xor(part[ii], 32);
  }
  if (rg == 0) {
    dst[0 * 16 + col] = part[0];  dst[1 * 16 + col] = part[1];
    dst[2 * 16 + col] = part[2];  dst[3 * 16 + col] = part[3];
  } else if (rg == 1) {
    dst[4 * 16 + col] = part[4];  dst[5 * 16 + col] = part[5];
    dst[6 * 16 + col] = part[6];  dst[7 * 16 + col] = part[7];
  } else if (rg == 2) {
    dst[8 * 16 + col] = part[8];  dst[9 * 16 + col] = part[9];
    dst[10 * 16 + col] = part[10]; dst[11 * 16 + col] = part[11];
  } else {
    dst[12 * 16 + col] = part[12]; dst[13 * 16 + col] = part[13];
    dst[14 * 16 + col] = part[14]; dst[15 * 16 + col] = part[15];
  }
  return det;
}

__global__ void __launch_bounds__(256)
lgq_fwd(const float* __restrict__ obs,
        const float* __restrict__ ppm, const float* __restrict__ ppc,
        const float* __restrict__ ptw, const float* __restrict__ ptb,
        const float* __restrict__ ptc, const float* __restrict__ pew,
        const float* __restrict__ peb, const float* __restrict__ pec,
        const float* __restrict__ qpm, const float* __restrict__ qpc,
        const float* __restrict__ qtw, const float* __restrict__ qtb,
        const float* __restrict__ qtc, const float* __restrict__ qew,
        const float* __restrict__ qeb, const float* __restrict__ qec) {
  const int e = threadIdx.x;
  const int i = e >> 4, j = e & 15;
  const int wid = e >> 6;
  const int lane = e & 63;

  __shared__ float W[256], Qm[256], Hm[256], Rm[256], Em[256], Pwm[256];
  __shared__ float HW[256], QHt[256], HQH[256], TmpB[256];
  __shared__ float Om0[256], Omo[256], Omt[256], Fo[256], Ft[256], Nm[256], EOm[256];
  __shared__ float Sm[256], Pf[256];
  __shared__ float WP[256], U[256], Ppred[256], Smat[256], PHt[256];
  __shared__ float Pi[256], Si[256], Gm[256], Kgm[256], Mm[256], T1m[256], NGm[256];
  __shared__ float sObs[256 * 16];
  __shared__ float detPArr[256], detSArr[256], d3all[256], lp[256], ls[256];
  __shared__ float mf[16], mfN[16], rv[16], pb[16], bqv[16], bemv[16], pbemv[16],
      ptbv[16];
  __shared__ float w2[16], q2[16], mpred[16], av[16], hv[16];
  __shared__ float EOpb[16], resid[16], tv1[16], tv2[16], Opf[16];
  __shared__ float ca[16], mca[16], nca[16], c1[16], cg1[16], qc[16], epbm[16];
  __shared__ float red[4], red2[4], red3[4], dets[6];
  __shared__ float sc_const, sc_c, ctb, sh_cstep;
  __shared__ float ld_pprior, ld_ptr, ld_pem, ld_Q, ld_R, ld_qprior, ld_Pf;
  __shared__ float sh_detS, sh_tstep_inf;
  __shared__ int sh_frozen;

  // I0: load fixed inputs + stage obs into LDS
  W[e] = qtw[e]; Qm[e] = qtc[e]; Hm[e] = qew[e]; Rm[e] = qec[e];
  Em[e] = pew[e]; Pwm[e] = ptw[e];
  {
    const float4* o4 = (const float4*)obs;
    float4* s4 = (float4*)sObs;
#pragma unroll
    for (int q = 0; q < 4; ++q) s4[e + 256 * q] = o4[e + 256 * q];
  }
  if (e < 16) { bqv[e] = qtb[e]; bemv[e] = qeb[e]; pbemv[e] = peb[e]; ptbv[e] = ptb[e]; }
  if (e == 0) { sh_frozen = 0; g_acc = 0.f; g_cnt = 0u; }
  __syncthreads();
  // I1
  HW[e] = dAB(Hm, W, i, j);
  TmpB[e] = dAB(Hm, Qm, i, j);
  __syncthreads();
  // I2
  HQH[e] = dABT(TmpB, Hm, i, j) + Rm[e];
  QHt[e] = TmpB[j * 16 + i];
  __syncthreads();
  // I3: six fixed inversions, two per wave
  if (wid == 0) {
    float d0 = reg_gj_inv(ppc, Pi);
    float d1 = reg_gj_inv(ptc, Si);
    if (e == 0) { dets[0] = d0; dets[1] = d1; }
  } else if (wid == 1) {
    float d2 = reg_gj_inv(pec, Gm);
    float d3 = reg_gj_inv(qtc, Kgm);
    if (e == 64) { dets[2] = d2; dets[3] = d3; }
  } else if (wid == 2) {
    float d4 = reg_gj_inv(qec, T1m);
    float d5 = reg_gj_inv(qpc, NGm);
    if (e == 128) { dets[4] = d4; dets[5] = d5; }
  }
  __syncthreads();
  // I4
  Om0[e] = -0.5f * Pi[e];
  Omt[e] = -0.5f * Si[e];
  Omo[e] = -0.5f * Gm[e];
  if (e == 0) {
    ld_pprior = logf(dets[0]); ld_ptr = logf(dets[1]); ld_pem = logf(dets[2]);
    ld_Q = logf(dets[3]); ld_R = logf(dets[4]); ld_qprior = logf(dets[5]);
  }
  __syncthreads();
  // I5
  g_Om0[e] = Om0[e]; g_Omo[e] = Omo[e]; g_Omt[e] = Omt[e];
  TmpB[e] = dAB(Omo, Em, i, j);
  Nm[e] = dAB(Omt, Pwm, i, j);
  EOm[e] = dATB(Em, Omo, i, j);
  Sm[e] = Om0[e];
  __syncthreads();
  // I6: fixed quadratic mats, vectors, and d3all[t] = pb_t^T Omo pb_t for ALL t
  Fo[e] = dATB(Em, TmpB, i, j);
  Ft[e] = dATB(Pwm, Nm, i, j);
  if (e < 16) w2[e] = mvT(Nm, ptbv, e);
  else if (e < 32) q2[e - 16] = mv(Omt, ptbv, e - 16);
  else if (e < 48) rv[e - 32] = -mv(Om0, ppm, e - 32);
  else if (e < 64) pb[e - 48] = pbemv[e - 48] - sObs[e - 48];
  {
    const int rr = e & 15, tg = e >> 4;
#pragma unroll
    for (int it = 0; it < 16; ++it) {
      const int tt = it * 16 + tg;
      float s = 0.f;
#pragma unroll
      for (int k = 0; k < 16; ++k)
        s = fmaf(Omo[rr * 16 + k], pbemv[k] - sObs[tt * 16 + k], s);
      s *= (pbemv[rr] - sObs[tt * 16 + rr]);
      s += __shfl_xor(s, 1); s += __shfl_xor(s, 2);
      s += __shfl_xor(s, 4); s += __shfl_xor(s, 8);
      if (rr == 0) d3all[tt] = s;
    }
  }
  __syncthreads();
  // I7
  if (e == 0) {
    float s = 0.f, ct = 0.f;
    for (int k = 0; k < 16; ++k) { s = fmaf(ppm[k], rv[k], s); ct = fmaf(ptbv[k], q2[k], ct); }
    sc_c = -s;
    ctb = ct;
    sc_const = -0.5f * (CT16 + ld_pprior) - 0.5f * (CT16 + ld_pem);
    sh_cstep = 8.f - 0.5f * CT16 - 0.5f * (ld_pem + ld_ptr);
  }
  if (e < 16) mpred[e] = qpm[e];
  TmpB[e] = dAB(Hm, qpc, i, j);
  __syncthreads();
  // I8
  Smat[e] = dABT(TmpB, Hm, i, j) + Rm[e];
  if (e < 16) resid[e] = sObs[e] - bemv[e] - mv(Hm, mpred, e);
  __syncthreads();
  // I9
  if (wid == 0) {
    float d = reg_gj_inv(Smat, Si);
    if (e == 0) sh_detS = d;
  }
  __syncthreads();
  // I10
  Kgm[e] = dATB(TmpB, Si, i, j);
  if (e == 0) ld_Pf = ld_qprior + ld_R - logf(sh_detS);  // ld_Pf_0
  __syncthreads();
  // I11
  Pf[e] = qpc[e] - dAB(Kgm, TmpB, i, j);
  if (e < 16) { mf[e] = mpred[e] + mv(Kgm, resid, e); mfN[e] = mf[e]; }
  __syncthreads();

  // ---- forward scan: 4 phases/step, zero serial thread0 work ----
  float d1acc = 0.f, tacc = 0.f, fd2 = 0.f, facc = 0.f;
  int t = 1;
  for (; t < 256; ++t) {
    const float* y = sObs + t * 16;
    // P_A: staging + closure of step t-1
    WP[e] = dAB(W, Pf, i, j);
    U[e] = dAB(HW, Pf, i, j);
    if (t > 1) {
      const float sN = dATB(Gm, T1m, i, j) - NGm[j * 16 + i] - NGm[e] + Omt[e];
      const float sd = fabsf(sN - Sm[e]);
      Sm[e] = sN;
      const float vm = wave_max(sd);
      if (lane == 0) red3[wid] = vm;
      d1acc = fmaf(Mm[e] * av[i], av[j], d1acc);
      if (e < 16) {
        float s = -q2[e];
#pragma unroll
        for (int k = 0; k < 16; ++k) {
          s = fmaf(T1m[k * 16 + e], av[k], s);
          s = fmaf(Gm[k * 16 + e], hv[k], s);
          s = fmaf(-Nm[e * 16 + k], av[k], s);
        }
        rv[e] = s;
      } else if (e < 32) {
        fd2 = fmaf(av[e - 16], hv[e - 16], fd2);
        mf[e - 16] = mfN[e - 16];
      } else if (e < 48) {
        mpred[e - 32] = bqv[e - 32] + mv(W, mfN, e - 32);
      }
    } else {
      if (e < 16) mpred[e] = bqv[e] + mv(W, mf, e);
    }
    __syncthreads();
    // P_B: predicted covariances + freeze decision
    Ppred[e] = dABT(WP, W, i, j) + Qm[e];
    Smat[e] = dABT(U, HW, i, j) + HQH[e];
    PHt[e] = dABT(WP, HW, i, j) + QHt[e];
    if (e < 16) resid[e] = y[e] - bemv[e] - mv(Hm, mpred, e);
    if (e == 0 && t >= 8) {
      const float pfd = fmaxf(fmaxf(red2[0], red2[1]), fmaxf(red2[2], red2[3]));
      const float sdm = fmaxf(fmaxf(red3[0], red3[1]), fmaxf(red3[2], red3[3]));
      if (pfd < 1e-3f && sdm < 1e-2f) sh_frozen = 1;
    }
    __syncthreads();
    if (sh_frozen) break;
    // P_C: inversions fused with gain products (waves 0,1); M/EOpb (wave 2)
    if (wid == 0) {
      const float d = gj_inv_mul<0>(Ppred, WP, Gm);   // G = WP^T * Ppred^-1
      if (e == 0) detPArr[t] = d;
    } else if (wid == 1) {
      const float d = gj_inv_mul<1>(Smat, PHt, Kgm);  // Kg = PHt * Smat^-1
      if (e == 64) detSArr[t] = d;
    } else if (wid == 2) {
      const int wl = e & 63;
#pragma unroll
      for (int q = 0; q < 4; ++q) { const int x = wl + 64 * q; Mm[x] = Sm[x] + Fo[x] + Ft[x]; }
      if (wl < 16) EOpb[wl] = mv(EOm, pb, wl);
    }
    __syncthreads();
    // P_D: trace partial, Pf update, M*G, N*G, vectors, G store
    {
      const float bc = Pf[e] - dAB(Gm, WP, i, j);
      tacc = fmaf(Mm[e], bc, tacc);
      const float pfN = Ppred[e] - dABT(Kgm, PHt, i, j);
      const float df = fabsf(pfN - Pf[e]);
      Pf[e] = pfN;
      const float vm = wave_max(df);
      if (lane == 0) red2[wid] = vm;
    }
    T1m[e] = dAB(Mm, Gm, i, j);
    NGm[e] = dAB(Nm, Gm, i, j);
    g_Gstore[(t - 1) * 256 + e] = Gm[e];
    if (e < 16) av[e] = mf[e] - mv(Gm, mpred, e);
    else if (e < 32) mfN[e - 16] = mpred[e - 16] + mv(Kgm, resid, e - 16);
    else if (e < 48) hv[e - 32] = rv[e - 32] + EOpb[e - 32] + w2[e - 32];
    else if (e < 64) pb[e - 48] = pbemv[e - 48] - y[e - 48];
    __syncthreads();
  }

  const int tb = t;  // steps 1..tb-1 fully processed
  if (sh_frozen) {
    // ---- build fused frozen operators (3 phases) ----
    // B1
    T1m[e] = dAB(Kgm, Hm, i, j);                          // KH
    NGm[e] = ((i == j) ? 1.f : 0.f) - dAB(Gm, W, i, j);   // Av
    Mm[e] = Sm[e] + Fo[e] + Ft[e];
    if (e < 16) ca[e] = -mv(Gm, bqv, e);
    else if (e < 32) epbm[e - 16] = mv(EOm, pbemv, e - 16);
    __syncthreads();
    // B2
    Smat[e] = W[e] - dAB(T1m, W, i, j);                   // A1
    Pi[e] = dAB(Mm, NGm, i, j);                           // MAv
    Si[e] = dAB(Nm, NGm, i, j);                           // NAv
    {
      const float bcf = Pf[e] - dAB(Gm, WP, i, j);        // frozen bcov
      const float v = wave_sum(Mm[e] * bcf);
      if (lane == 0) red[wid] = v;
    }
    if (e < 16) mca[e] = mv(Mm, ca, e);
    else if (e < 32) nca[e - 16] = mv(Nm, ca, e - 16);
    else if (e < 48) {
      const int r = e - 32;
      c1[r] = bqv[r] - mv(T1m, bqv, r) - mv(Kgm, bemv, r);
    }
    __syncthreads();
    // B3
    U[e] = dATB(Gm, Pi, i, j) - Si[e];                    // B1
    Ppred[e] = dATB(Gm, EOm, i, j);                       // GEO
    if (e < 16) {
      float s = 0.f;
#pragma unroll
      for (int k = 0; k < 16; ++k)
        s = fmaf(Gm[k * 16 + e], w2[k] + mca[k] + epbm[k], s);
      cg1[e] = s - nca[e] - q2[e];
    } else if (e < 32) {
      const int r = e - 16;
      qc[r] = mca[r] + 2.f * w2[r] + 2.f * epbm[r];
    }
    if (e == 0) sh_tstep_inf = red[0] + red[1] + red[2] + red[3];
    __syncthreads();
    // ---- frozen loop: wave 0 only, zero barriers, register/shuffle ----
    if (wid == 0) {
      const int g = lane >> 4, r = lane & 15;
      float Trow[32], Brow[16], Crow[16];
#pragma unroll
      for (int k = 0; k < 16; ++k) {
        Trow[k] = (g == 0) ? Smat[r * 16 + k]
                : (g == 1) ? U[r * 16 + k]
                : (g == 2) ? NGm[r * 16 + k] : Pi[r * 16 + k];
        Trow[16 + k] = (g == 1) ? Gm[k * 16 + r]
                     : (g == 3) ? ((k == r) ? 2.f : 0.f) : 0.f;
        Brow[k] = (g == 0) ? Kgm[r * 16 + k] : 0.f;
        Crow[k] = (g == 1) ? -Ppred[r * 16 + k]
                : (g == 3) ? -2.f * EOm[r * 16 + k] : 0.f;
      }
      const float cfold = (g == 0) ? c1[r] : (g == 1) ? cg1[r]
                        : (g == 2) ? ca[r] : qc[r];
      float x = (g == 0) ? mf[r] : (g == 1) ? rv[r] : 0.f;
      float yprev = sObs[(tb - 1) * 16 + r];
      for (int tt = tb; tt < 256; ++tt) {
        const float ycur = sObs[tt * 16 + r];
        float s0 = cfold, s1 = 0.f, s2 = 0.f, s3 = 0.f;
#pragma unroll
        for (int k = 0; k < 32; k += 4) {
          s0 = fmaf(Trow[k], __shfl(x, k), s0);
          s1 = fmaf(Trow[k + 1], __shfl(x, k + 1), s1);
          s2 = fmaf(Trow[k + 2], __shfl(x, k + 2), s2);
          s3 = fmaf(Trow[k + 3], __shfl(x, k + 3), s3);
        }
#pragma unroll
        for (int k = 0; k < 16; k += 2) {
          s0 = fmaf(Brow[k], __shfl(ycur, k), s0);
          s1 = fmaf(Brow[k + 1], __shfl(ycur, k + 1), s1);
          s2 = fmaf(Crow[k], __shfl(yprev, k), s2);
          s3 = fmaf(Crow[k + 1], __shfl(yprev, k + 1), s3);
        }
        const float acc = (s0 + s1) + (s2 + s3);
        const float qv = __shfl_down(acc, 16);  // lanes 32-47 get q from 48-63
        if (g == 2) facc = fmaf(acc, qv, facc);
        if (g < 2) x = acc;
        yprev = ycur;
      }
      if (g == 0) { mf[r] = x; pb[r] = pbemv[r] - sObs[255 * 16 + r]; }
      else if (g == 1) rv[r] = x;
    }
    __syncthreads();
  } else {
    // never froze (fallback): closure of step 255
    const float sN = dATB(Gm, T1m, i, j) - NGm[j * 16 + i] - NGm[e] + Omt[e];
    Sm[e] = sN;
    d1acc = fmaf(Mm[e] * av[i], av[j], d1acc);
    if (e < 16) {
      float s = -q2[e];
#pragma unroll
      for (int k = 0; k < 16; ++k) {
        s = fmaf(T1m[k * 16 + e], av[k], s);
        s = fmaf(Gm[k * 16 + e], hv[k], s);
        s = fmaf(-Nm[e * 16 + k], av[k], s);
      }
      rv[e] = s;
    } else if (e < 32) {
      fd2 = fmaf(av[e - 16], hv[e - 16], fd2);
      mf[e - 16] = mfN[e - 16];
    }
    __syncthreads();
  }

  // ---- E1: parallel logs + the three deferred reductions ----
  const int n = tb - 1;
  if (e >= 1 && e <= n) { lp[e] = logf(detPArr[e]); ls[e] = logf(detSArr[e]); }
  {
    const float vA = d1acc + 2.f * fd2 + facc;
    const float vB = tacc;
    const float vC = (e < 255) ? d3all[e] : 0.f;
    const float sA = wave_sum(vA);
    const float sB = wave_sum(vB);
    const float sC = wave_sum(vC);
    if (lane == 0) { red[wid] = sA; red2[wid] = sB; red3[wid] = sC; }
  }
  __syncthreads();
  // ---- E2: serial epilogue (tiny) ----
  if (e == 0) {
    const float dsum = red[0] + red[1] + red[2] + red[3];
    const float tsum = red2[0] + red2[1] + red2[2] + red2[3];
    const float d3tot = red3[0] + red3[1] + red3[2] + red3[3];
    float lpf = ld_Pf;
    float sum_ldb = 0.f, ldbl = 0.f;
    for (int s2 = 1; s2 <= n; ++s2) {
      ldbl = lpf + ld_Q - lp[s2];
      sum_ldb += ldbl;
      lpf = lp[s2] + ld_R - ls[s2];
    }
    float sc = sc_const + tsum + (float)n * sh_cstep + 0.5f * sum_ldb;
    if (tb < 256) sc += (float)(256 - tb) * (sh_tstep_inf + sh_cstep + 0.5f * ldbl);
    sc_const = sc;
    ld_Pf = lpf;
    sc_c += dsum + d3tot + 255.f * ctb;
  }
  __syncthreads();

  // ---- final terms ----
  g_Pff[e] = Pf[e];
  g_Ginf[e] = Gm[e];
  if (e == 0) g_tb = tb;
  WP[e] = dAB(Pf, Em, i, j);  // PE = Pf * E
  if (e < 16) tv1[e] = mv(Sm, mf, e);
  else if (e < 32) tv2[e - 16] = pb[e - 16] + mv(Em, mf, e - 16);
  __syncthreads();
  {
    const float v = wave_sum(EOm[e] * WP[e]);
    if (lane == 0) red[wid] = v;
  }
  if (e < 16) Opf[e] = mv(Omo, tv2, e);
  __syncthreads();
  if (e == 0) {
    const float tr_p = red[0] + red[1] + red[2] + red[3];
    float ev1 = 0.f, ev2 = 0.f, evp = 0.f;
    for (int k = 0; k < 16; ++k) {
      ev1 = fmaf(mf[k], tv1[k], ev1);
      ev2 = fmaf(rv[k], mf[k], ev2);
      evp = fmaf(tv2[k], Opf[k], evp);
    }
    g_partial = sc_const + 0.5f * (CT16 + ld_Pf) + (ev1 + 2.f * ev2 + sc_c)
                + tr_p + evp + 8.f;
  }
}

// One block per t. Each block builds its OWN suffix product (binary powering
// of Ginf + short chain over stored G's), computes its trace terms, and the
// last finishing block writes the final output.
__global__ void __launch_bounds__(256)
lgq_trace(const float* __restrict__ pew, const float* __restrict__ ptw,
          float* __restrict__ out) {
  const int e = threadIdx.x, i = e >> 4, j = e & 15, b = blockIdx.x;
  const int lane = e & 63, wid = e >> 6;
  __shared__ float Pfs[256], OmA[256], OmtS[256], EmS[256], PwS[256], GinfS[256];
  __shared__ float Xb[2][256], Bb[2][256];
  __shared__ float Sm1[256], Sf[256], A1[256], A2[256];
  __shared__ float T1v[256], NGv[256], Kxv[256], S2v[256];
  __shared__ float redt[4];
  const int tb = g_tb;
  Pfs[e] = g_Pff[e];
  OmtS[e] = g_Omt[e];
  EmS[e] = pew[e];
  PwS[e] = ptw[e];
  GinfS[e] = g_Ginf[e];
  OmA[e] = (b == 0) ? g_Om0[e] : g_Omo[e];
  Xb[0][e] = (i == j) ? 1.f : 0.f;
  Bb[0][e] = g_Ginf[e];
  __syncthreads();
  // binary powering: X = Ginf^E0
  int E = (b >= tb) ? (255 - b) : (256 - tb);
  int xc = 0, bc2 = 0;
  while (E) {
    Xb[xc ^ 1][e] = (E & 1) ? dAB(Xb[xc], Bb[bc2], i, j) : Xb[xc][e];
    if (E > 1) Bb[bc2 ^ 1][e] = dAB(Bb[bc2], Bb[bc2], i, j);
    __syncthreads();
    xc ^= 1; bc2 ^= 1;
    E >>= 1;
  }
  if (b >= tb) {
    Sf[e] = Xb[xc][e];                       // Suf_b = Ginf^(255-b)
    Sm1[e] = dAB(GinfS, Xb[xc], i, j);       // Suf_{b-1}
    __syncthreads();
  } else {
    // chain: Suf_b = G_{b+1} ... G_{tb-1} * Ginf^(256-tb)
    int cur = xc;
    for (int s2 = tb - 1; s2 >= b + 1; --s2) {
      const float4* gr = (const float4*)(g_Gstore + (s2 - 1) * 256 + i * 16);
      const float4 a0 = gr[0], a1 = gr[1], a2 = gr[2], a3 = gr[3];
      const float* Xc = Xb[cur];
      float s = 0.f;
      s = fmaf(a0.x, Xc[0 * 16 + j], s);  s = fmaf(a0.y, Xc[1 * 16 + j], s);
      s = fmaf(a0.z, Xc[2 * 16 + j], s);  s = fmaf(a0.w, Xc[3 * 16 + j], s);
      s = fmaf(a1.x, Xc[4 * 16 + j], s);  s = fmaf(a1.y, Xc[5 * 16 + j], s);
      s = fmaf(a1.z, Xc[6 * 16 + j], s);  s = fmaf(a1.w, Xc[7 * 16 + j], s);
      s = fmaf(a2.x, Xc[8 * 16 + j], s);  s = fmaf(a2.y, Xc[9 * 16 + j], s);
      s = fmaf(a2.z, Xc[10 * 16 + j], s); s = fmaf(a2.w, Xc[11 * 16 + j], s);
      s = fmaf(a3.x, Xc[12 * 16 + j], s); s = fmaf(a3.y, Xc[13 * 16 + j], s);
      s = fmaf(a3.z, Xc[14 * 16 + j], s); s = fmaf(a3.w, Xc[15 * 16 + j], s);
      Xb[cur ^ 1][e] = s;
      __syncthreads();
      cur ^= 1;
    }
    Sf[e] = Xb[cur][e];  // Suf_b
    if (b >= 1) {
      const float4* gr = (const float4*)(g_Gstore + (b - 1) * 256 + i * 16);
      const float4 a0 = gr[0], a1 = gr[1], a2 = gr[2], a3 = gr[3];
      const float* Xc = Xb[cur];
      float s = 0.f;
      s = fmaf(a0.x, Xc[0 * 16 + j], s);  s = fmaf(a0.y, Xc[1 * 16 + j], s);
      s = fmaf(a0.z, Xc[2 * 16 + j], s);  s = fmaf(a0.w, Xc[3 * 16 + j], s);
      s = fmaf(a1.x, Xc[4 * 16 + j], s);  s = fmaf(a1.y, Xc[5 * 16 + j], s);
      s = fmaf(a1.z, Xc[6 * 16 + j], s);  s = fmaf(a1.w, Xc[7 * 16 + j], s);
      s = fmaf(a2.x, Xc[8 * 16 + j], s);  s = fmaf(a2.y, Xc[9 * 16 + j], s);
      s = fmaf(a2.z, Xc[10 * 16 + j], s); s = fmaf(a2.w, Xc[11 * 16 + j], s);
      s = fmaf(a3.x, Xc[12 * 16 + j], s); s = fmaf(a3.y, Xc[13 * 16 + j], s);
      s = fmaf(a3.z, Xc[14 * 16 + j], s); s = fmaf(a3.w, Xc[15 * 16 + j], s);
      Sm1[e] = s;          // Suf_{b-1} = G_b * Suf_b
    } else {
      Sm1[e] = Xb[cur][e]; // Suf_0
    }
    __syncthreads();
  }
  if (b == 0) {
    A1[e] = Sm1[e];
    A2[e] = 0.f;
  } else {
    A1[e] = dAB(EmS, Sm1, i, j);
    A2[e] = dAB(PwS, Sm1, i, j) - Sf[e];
  }
  __syncthreads();
  T1v[e] = dAB(OmA, A1, i, j);
  NGv[e] = dAB(Pfs, A1, i, j);
  Kxv[e] = dAB(OmtS, A2, i, j);
  S2v[e] = dAB(Pfs, A2, i, j);
  __syncthreads();
  float val = T1v[e] * NGv[j * 16 + i] + Kxv[e] * S2v[j * 16 + i];
  val = wave_sum(val);
  if (lane == 0) redt[wid] = val;
  __syncthreads();
  if (e == 0) {
    atomicAdd(&g_acc, redt[0] + redt[1] + redt[2] + redt[3]);
    __threadfence();
    const unsigned o = atomicAdd(&g_cnt, 1u);
    if (o == 255u) {
      const float acc = atomicAdd(&g_acc, 0.f);  // final value (all adds done)
      out[0] = g_partial + acc;
    }
  }
}

extern "C" void kernel_launch(void* const* d_in, const int* in_sizes, int n_in,
                              void* d_out, int out_size, void* d_ws, size_t ws_size,
                              hipStream_t stream) {
  (void)in_sizes; (void)n_in; (void)out_size; (void)d_ws; (void)ws_size;
  lgq_fwd<<<dim3(1), dim3(256), 0, stream>>>(
      (const float*)d_in[0], (const float*)d_in[1], (const float*)d_in[2],
      (const float*)d_in[3], (const float*)d_in[4], (const float*)d_in[5],
      (const float*)d_in[6], (const float*)d_in[7], (const float*)d_in[8],
      (const float*)d_in[9], (const float*)d_in[10], (const float*)d_in[11],
      (const float*)d_in[12], (const float*)d_in[13], (const float*)d_in[14],
      (const float*)d_in[15], (const float*)d_in[16]);
  lgq_trace<<<dim3(256), dim3(256), 0, stream>>>((const float*)d_in[6],
                                                 (const float*)d_in[3],
                                                 (float*)d_out);
}

// Round 6
// 138.245 us; speedup vs baseline: 20.8937x; 1.2327x over previous
//
#include <hip/hip_runtime.h>
#include <cmath>

#define L2PI 1.8378770664093453f
#define CT16 (16.f * L2PI)

// Per-launch scratch (fully rewritten every call before being read).
__device__ __align__(16) float g_Gstore[255 * 256];
__device__ float g_Pff[256], g_Om0[256], g_Omo[256], g_Omt[256], g_Ginf[256];
__device__ float g_partial, g_acc;
__device__ int g_tb;
__device__ unsigned g_cnt;

__device__ __forceinline__ float dAB(const float* A, const float* B, int i, int j) {
  float s = 0.f;
#pragma unroll
  for (int k = 0; k < 16; ++k) s = fmaf(A[i * 16 + k], B[k * 16 + j], s);
  return s;
}
__device__ __forceinline__ float dATB(const float* A, const float* B, int i, int j) {
  float s = 0.f;
#pragma unroll
  for (int k = 0; k < 16; ++k) s = fmaf(A[k * 16 + i], B[k * 16 + j], s);
  return s;
}
__device__ __forceinline__ float dABT(const float* A, const float* B, int i, int j) {
  float s = 0.f;
#pragma unroll
  for (int k = 0; k < 16; ++k) s = fmaf(A[i * 16 + k], B[j * 16 + k], s);
  return s;
}
__device__ __forceinline__ float mv(const float* M, const float* v, int r) {
  float s = 0.f;
#pragma unroll
  for (int k = 0; k < 16; ++k) s = fmaf(M[r * 16 + k], v[k], s);
  return s;
}
__device__ __forceinline__ float mvT(const float* M, const float* v, int r) {
  float s = 0.f;
#pragma unroll
  for (int k = 0; k < 16; ++k) s = fmaf(M[k * 16 + r], v[k], s);
  return s;
}
__device__ __forceinline__ float wave_sum(float v) {
#pragma unroll
  for (int off = 32; off; off >>= 1) v += __shfl_down(v, off);
  return v;
}
__device__ __forceinline__ float wave_max(float v) {
#pragma unroll
  for (int off = 32; off; off >>= 1) v = fmaxf(v, __shfl_down(v, off));
  return v;
}
// Broadcast from a compile-time-uniform lane: SALU-latency, no LDS round-trip.
__device__ __forceinline__ float rl(float v, int l) {
  return __int_as_float(__builtin_amdgcn_readlane(__float_as_int(v), l));
}

// Register-resident Gauss-Jordan inverse of SPD 16x16, one wave, barrier-free.
// Lane l owns column (l&15), rows (l>>4)+4q. Returns det.
__device__ __forceinline__ float reg_gj_core(const float* __restrict__ src,
                                             float aI[4]) {
  const int wl = threadIdx.x & 63;
  const int col = wl & 15, rg = wl >> 4;
  float aA[4];
#pragma unroll
  for (int q = 0; q < 4; ++q) {
    const int r = rg + 4 * q;
    aA[q] = src[r * 16 + col];
    aI[q] = (r == col) ? 1.f : 0.f;
  }
  float det = 1.f;
#pragma unroll
  for (int k = 0; k < 16; ++k) {
    const int kq = k >> 2, kr = k & 3;
    const float piv = rl(aA[kq], (kr << 4) | k);
    det *= piv;
    const float rp = 1.f / piv;
    const float pA = __shfl(aA[kq], (kr << 4) | col);
    const float pI = __shfl(aI[kq], (kr << 4) | col);
    float f[4];
    f[0] = __shfl(aA[0], (rg << 4) | k);
    f[1] = __shfl(aA[1], (rg << 4) | k);
    f[2] = __shfl(aA[2], (rg << 4) | k);
    f[3] = __shfl(aA[3], (rg << 4) | k);
#pragma unroll
    for (int q = 0; q < 4; ++q) {
      const float tq = f[q] * rp;
      const float nA = fmaf(-tq, pA, aA[q]);
      const float nI = fmaf(-tq, pI, aI[q]);
      if (q == kq) {
        const bool isp = (rg == kr);
        aA[q] = isp ? pA * rp : nA;
        aI[q] = isp ? pI * rp : nI;
      } else {
        aA[q] = nA;
        aI[q] = nI;
      }
    }
  }
  return det;
}

__device__ __forceinline__ float reg_gj_inv(const float* __restrict__ src,
                                            float* __restrict__ dst) {
  const int wl = threadIdx.x & 63;
  const int col = wl & 15, rg = wl >> 4;
  float aI[4];
  const float det = reg_gj_core(src, aI);
#pragma unroll
  for (int q = 0; q < 4; ++q) dst[(rg + 4 * q) * 16 + col] = aI[q];
  return det;
}

// GJ inverse fused with a product, inverse never touches LDS.
// MODE 0: dst = Bm^T * inv ; MODE 1: dst = Bm * inv
template <int MODE>
__device__ __forceinline__ float gj_inv_mul(const float* __restrict__ src,
                                            const float* __restrict__ Bm,
                                            float* __restrict__ dst) {
  const int wl = threadIdx.x & 63;
  const int col = wl & 15, rg = wl >> 4;
  float aI[4];
  const float det = reg_gj_core(src, aI);
  float part[16];
#pragma unroll
  for (int ii = 0; ii < 16; ++ii) {
    float s = 0.f;
#pragma unroll
    for (int q = 0; q < 4; ++q) {
      const int k = rg + 4 * q;
      s = fmaf(MODE == 0 ? Bm[k * 16 + ii] : Bm[ii * 16 + k], aI[q], s);
    }
    part[ii] = s;
  }
#pragma unroll
  for (int ii = 0; ii < 16; ++ii) {
    part[ii] += __shfl_xor(part[ii], 16);
    part[ii] += __shfl_xor(part[ii], 32);
  }
  if (rg == 0) {
    dst[0 * 16 + col] = part[0];  dst[1 * 16 + col] = part[1];
    dst[2 * 16 + col] = part[2];  dst[3 * 16 + col] = part[3];
  } else if (rg == 1) {
    dst[4 * 16 + col] = part[4];  dst[5 * 16 + col] = part[5];
    dst[6 * 16 + col] = part[6];  dst[7 * 16 + col] = part[7];
  } else if (rg == 2) {
    dst[8 * 16 + col] = part[8];  dst[9 * 16 + col] = part[9];
    dst[10 * 16 + col] = part[10]; dst[11 * 16 + col] = part[11];
  } else {
    dst[12 * 16 + col] = part[12]; dst[13 * 16 + col] = part[13];
    dst[14 * 16 + col] = part[14]; dst[15 * 16 + col] = part[15];
  }
  return det;
}

__global__ void __launch_bounds__(256)
lgq_fwd(const float* __restrict__ obs,
        const float* __restrict__ ppm, const float* __restrict__ ppc,
        const float* __restrict__ ptw, const float* __restrict__ ptb,
        const float* __restrict__ ptc, const float* __restrict__ pew,
        const float* __restrict__ peb, const float* __restrict__ pec,
        const float* __restrict__ qpm, const float* __restrict__ qpc,
        const float* __restrict__ qtw, const float* __restrict__ qtb,
        const float* __restrict__ qtc, const float* __restrict__ qew,
        const float* __restrict__ qeb, const float* __restrict__ qec) {
  const int e = threadIdx.x;
  const int i = e >> 4, j = e & 15;
  const int wid = e >> 6;
  const int lane = e & 63;

  __shared__ float W[256], Qm[256], Hm[256], Rm[256], Em[256], Pwm[256];
  __shared__ float HW[256], QHt[256], HQH[256], TmpB[256];
  __shared__ float Om0[256], Omo[256], Omt[256], Fo[256], Ft[256], Nm[256], EOm[256];
  __shared__ float Sm[256], Pf[256];
  __shared__ float WP[256], U[256], Ppred[256], Smat[256], PHt[256];
  __shared__ float Pi[256], Si[256], Gm[256], Kgm[256], Mm[256], T1m[256], NGm[256];
  __shared__ float sObs[256 * 16];
  __shared__ float detPArr[256], detSArr[256], d3all[256];
  __shared__ float u_all[250 * 48];  // per-step inhomogeneous terms (frozen loop)
  __shared__ float mf[16], mfN[16], rv[16], pb[16], bqv[16], bemv[16], pbemv[16],
      ptbv[16];
  __shared__ float w2[16], q2[16], mpred[16], av[16], hv[16];
  __shared__ float EOpb[16], resid[16], tv1[16], tv2[16], Opf[16];
  __shared__ float ca[16], mca[16], nca[16], c1[16], cg1[16], qc[16], epbm[16];
  __shared__ float red[4], red2[4], red3[4], dets[6];
  __shared__ float sc_const, sc_c, ctb, sh_cstep;
  __shared__ float ld_pprior, ld_ptr, ld_pem, ld_Q, ld_R, ld_qprior, ld_Pf;
  __shared__ float sh_detS, sh_tstep_inf;
  __shared__ int sh_frozen;

  // I0: load fixed inputs + stage obs into LDS
  W[e] = qtw[e]; Qm[e] = qtc[e]; Hm[e] = qew[e]; Rm[e] = qec[e];
  Em[e] = pew[e]; Pwm[e] = ptw[e];
  {
    const float4* o4 = (const float4*)obs;
    float4* s4 = (float4*)sObs;
#pragma unroll
    for (int q = 0; q < 4; ++q) s4[e + 256 * q] = o4[e + 256 * q];
  }
  if (e < 16) { bqv[e] = qtb[e]; bemv[e] = qeb[e]; pbemv[e] = peb[e]; ptbv[e] = ptb[e]; }
  if (e == 0) { sh_frozen = 0; g_acc = 0.f; g_cnt = 0u; }
  __syncthreads();
  // I1
  HW[e] = dAB(Hm, W, i, j);
  TmpB[e] = dAB(Hm, Qm, i, j);
  __syncthreads();
  // I2
  HQH[e] = dABT(TmpB, Hm, i, j) + Rm[e];
  QHt[e] = TmpB[j * 16 + i];
  __syncthreads();
  // I3: six fixed inversions, two per wave
  if (wid == 0) {
    float d0 = reg_gj_inv(ppc, Pi);
    float d1 = reg_gj_inv(ptc, Si);
    if (e == 0) { dets[0] = d0; dets[1] = d1; }
  } else if (wid == 1) {
    float d2 = reg_gj_inv(pec, Gm);
    float d3 = reg_gj_inv(qtc, Kgm);
    if (e == 64) { dets[2] = d2; dets[3] = d3; }
  } else if (wid == 2) {
    float d4 = reg_gj_inv(qec, T1m);
    float d5 = reg_gj_inv(qpc, NGm);
    if (e == 128) { dets[4] = d4; dets[5] = d5; }
  }
  __syncthreads();
  // I4
  Om0[e] = -0.5f * Pi[e];
  Omt[e] = -0.5f * Si[e];
  Omo[e] = -0.5f * Gm[e];
  if (e == 0) {
    ld_pprior = logf(dets[0]); ld_ptr = logf(dets[1]); ld_pem = logf(dets[2]);
    ld_Q = logf(dets[3]); ld_R = logf(dets[4]); ld_qprior = logf(dets[5]);
  }
  __syncthreads();
  // I5
  g_Om0[e] = Om0[e]; g_Omo[e] = Omo[e]; g_Omt[e] = Omt[e];
  TmpB[e] = dAB(Omo, Em, i, j);
  Nm[e] = dAB(Omt, Pwm, i, j);
  EOm[e] = dATB(Em, Omo, i, j);
  Sm[e] = Om0[e];
  __syncthreads();
  // I6: fixed quadratic mats, vectors, and d3all[t] = pb_t^T Omo pb_t for ALL t
  Fo[e] = dATB(Em, TmpB, i, j);
  Ft[e] = dATB(Pwm, Nm, i, j);
  if (e < 16) w2[e] = mvT(Nm, ptbv, e);
  else if (e < 32) q2[e - 16] = mv(Omt, ptbv, e - 16);
  else if (e < 48) rv[e - 32] = -mv(Om0, ppm, e - 32);
  else if (e < 64) pb[e - 48] = pbemv[e - 48] - sObs[e - 48];
  {
    const int rr = e & 15, tg = e >> 4;
#pragma unroll
    for (int it = 0; it < 16; ++it) {
      const int tt = it * 16 + tg;
      float s = 0.f;
#pragma unroll
      for (int k = 0; k < 16; ++k)
        s = fmaf(Omo[rr * 16 + k], pbemv[k] - sObs[tt * 16 + k], s);
      s *= (pbemv[rr] - sObs[tt * 16 + rr]);
      s += __shfl_xor(s, 1); s += __shfl_xor(s, 2);
      s += __shfl_xor(s, 4); s += __shfl_xor(s, 8);
      if (rr == 0) d3all[tt] = s;
    }
  }
  __syncthreads();
  // I7
  if (e == 0) {
    float s = 0.f, ct = 0.f;
    for (int k = 0; k < 16; ++k) { s = fmaf(ppm[k], rv[k], s); ct = fmaf(ptbv[k], q2[k], ct); }
    sc_c = -s;
    ctb = ct;
    sc_const = -0.5f * (CT16 + ld_pprior) - 0.5f * (CT16 + ld_pem);
    sh_cstep = 8.f - 0.5f * CT16 - 0.5f * (ld_pem + ld_ptr);
  }
  if (e < 16) mpred[e] = qpm[e];
  TmpB[e] = dAB(Hm, qpc, i, j);
  __syncthreads();
  // I8
  Smat[e] = dABT(TmpB, Hm, i, j) + Rm[e];
  if (e < 16) resid[e] = sObs[e] - bemv[e] - mv(Hm, mpred, e);
  __syncthreads();
  // I9
  if (wid == 0) {
    float d = reg_gj_inv(Smat, Si);
    if (e == 0) sh_detS = d;
  }
  __syncthreads();
  // I10
  Kgm[e] = dATB(TmpB, Si, i, j);
  if (e == 0) ld_Pf = ld_qprior + ld_R - logf(sh_detS);  // ld_Pf_0
  __syncthreads();
  // I11
  Pf[e] = qpc[e] - dAB(Kgm, TmpB, i, j);
  if (e < 16) { mf[e] = mpred[e] + mv(Kgm, resid, e); mfN[e] = mf[e]; }
  __syncthreads();

  // ---- forward scan: 4 phases/step, zero serial thread0 work ----
  float d1acc = 0.f, tacc = 0.f, fd2 = 0.f, facc = 0.f;
  int t = 1;
  for (; t < 256; ++t) {
    const float* y = sObs + t * 16;
    // P_A: staging + closure of step t-1
    WP[e] = dAB(W, Pf, i, j);
    U[e] = dAB(HW, Pf, i, j);
    if (t > 1) {
      const float sN = dATB(Gm, T1m, i, j) - NGm[j * 16 + i] - NGm[e] + Omt[e];
      const float sd = fabsf(sN - Sm[e]);
      Sm[e] = sN;
      const float vm = wave_max(sd);
      if (lane == 0) red3[wid] = vm;
      d1acc = fmaf(Mm[e] * av[i], av[j], d1acc);
      if (e < 16) {
        float s = -q2[e];
#pragma unroll
        for (int k = 0; k < 16; ++k) {
          s = fmaf(T1m[k * 16 + e], av[k], s);
          s = fmaf(Gm[k * 16 + e], hv[k], s);
          s = fmaf(-Nm[e * 16 + k], av[k], s);
        }
        rv[e] = s;
      } else if (e < 32) {
        fd2 = fmaf(av[e - 16], hv[e - 16], fd2);
        mf[e - 16] = mfN[e - 16];
      } else if (e < 48) {
        mpred[e - 32] = bqv[e - 32] + mv(W, mfN, e - 32);
      }
    } else {
      if (e < 16) mpred[e] = bqv[e] + mv(W, mf, e);
    }
    __syncthreads();
    // P_B: predicted covariances + freeze decision
    Ppred[e] = dABT(WP, W, i, j) + Qm[e];
    Smat[e] = dABT(U, HW, i, j) + HQH[e];
    PHt[e] = dABT(WP, HW, i, j) + QHt[e];
    if (e < 16) resid[e] = y[e] - bemv[e] - mv(Hm, mpred, e);
    if (e == 0 && t >= 7) {
      const float pfd = fmaxf(fmaxf(red2[0], red2[1]), fmaxf(red2[2], red2[3]));
      const float sdm = fmaxf(fmaxf(red3[0], red3[1]), fmaxf(red3[2], red3[3]));
      if (pfd < 3e-3f && sdm < 3e-2f) sh_frozen = 1;
    }
    __syncthreads();
    if (sh_frozen) break;
    // P_C: inversions fused with gain products (waves 0,1); M/EOpb (wave 2)
    if (wid == 0) {
      const float d = gj_inv_mul<0>(Ppred, WP, Gm);   // G = WP^T * Ppred^-1
      if (e == 0) detPArr[t] = d;
    } else if (wid == 1) {
      const float d = gj_inv_mul<1>(Smat, PHt, Kgm);  // Kg = PHt * Smat^-1
      if (e == 64) detSArr[t] = d;
    } else if (wid == 2) {
      const int wl = e & 63;
#pragma unroll
      for (int q = 0; q < 4; ++q) { const int x = wl + 64 * q; Mm[x] = Sm[x] + Fo[x] + Ft[x]; }
      if (wl < 16) EOpb[wl] = mv(EOm, pb, wl);
    }
    __syncthreads();
    // P_D: trace partial, Pf update, M*G, N*G, vectors, G store
    {
      const float bc = Pf[e] - dAB(Gm, WP, i, j);
      tacc = fmaf(Mm[e], bc, tacc);
      const float pfN = Ppred[e] - dABT(Kgm, PHt, i, j);
      const float df = fabsf(pfN - Pf[e]);
      Pf[e] = pfN;
      const float vm = wave_max(df);
      if (lane == 0) red2[wid] = vm;
    }
    T1m[e] = dAB(Mm, Gm, i, j);
    NGm[e] = dAB(Nm, Gm, i, j);
    g_Gstore[(t - 1) * 256 + e] = Gm[e];
    if (e < 16) av[e] = mf[e] - mv(Gm, mpred, e);
    else if (e < 32) mfN[e - 16] = mpred[e - 16] + mv(Kgm, resid, e - 16);
    else if (e < 48) hv[e - 32] = rv[e - 32] + EOpb[e - 32] + w2[e - 32];
    else if (e < 64) pb[e - 48] = pbemv[e - 48] - y[e - 48];
    __syncthreads();
  }

  const int tb = t;  // steps 1..tb-1 fully processed
  if (sh_frozen) {
    // ---- build fused frozen operators (3 phases) ----
    // B1
    T1m[e] = dAB(Kgm, Hm, i, j);                          // KH
    NGm[e] = ((i == j) ? 1.f : 0.f) - dAB(Gm, W, i, j);   // Av
    Mm[e] = Sm[e] + Fo[e] + Ft[e];
    if (e < 16) ca[e] = -mv(Gm, bqv, e);
    else if (e < 32) epbm[e - 16] = mv(EOm, pbemv, e - 16);
    __syncthreads();
    // B2
    Smat[e] = W[e] - dAB(T1m, W, i, j);                   // A1
    Pi[e] = dAB(Mm, NGm, i, j);                           // MAv
    Si[e] = dAB(Nm, NGm, i, j);                           // NAv
    {
      const float bcf = Pf[e] - dAB(Gm, WP, i, j);        // frozen bcov
      const float v = wave_sum(Mm[e] * bcf);
      if (lane == 0) red[wid] = v;
    }
    if (e < 16) mca[e] = mv(Mm, ca, e);
    else if (e < 32) nca[e - 16] = mv(Nm, ca, e - 16);
    else if (e < 48) {
      const int r = e - 32;
      c1[r] = bqv[r] - mv(T1m, bqv, r) - mv(Kgm, bemv, r);
    }
    __syncthreads();
    // B3
    U[e] = dATB(Gm, Pi, i, j) - Si[e];                    // B1
    Ppred[e] = dATB(Gm, EOm, i, j);                       // GEO
    if (e < 16) {
      float s = 0.f;
#pragma unroll
      for (int k = 0; k < 16; ++k)
        s = fmaf(Gm[k * 16 + e], w2[k] + mca[k] + epbm[k], s);
      cg1[e] = s - nca[e] - q2[e];
    } else if (e < 32) {
      const int r = e - 16;
      qc[r] = mca[r] + 2.f * w2[r] + 2.f * epbm[r];
    }
    if (e == 0) sh_tstep_inf = red[0] + red[1] + red[2] + red[3];
    __syncthreads();
    // PU: precompute per-step inhomogeneous terms (all 256 threads, parallel)
    // slot 0-15 : c1 + Kg y_t          (mf drive)
    // slot 16-31: cg1 - GEO y_{t-1}    (rv drive)
    // slot 32-47: qc0 - 2 EOm y_{t-1}  (q drive)
    {
      const int c = e & 63, qq = e >> 6;
      const int g2 = c >> 4, r2 = c & 15;
      for (int tt = tb + qq; tt < 256; tt += 4) {
        const float* yc = sObs + tt * 16;
        const float* yp = yc - 16;
        const int base = (tt - tb) * 48;
        if (g2 == 0) u_all[base + r2] = c1[r2] + mv(Kgm, yc, r2);
        else if (g2 == 1) u_all[base + 16 + r2] = cg1[r2] - mv(Ppred, yp, r2);
        else if (g2 == 2) u_all[base + 32 + r2] = qc[r2] - 2.f * mv(EOm, yp, r2);
      }
    }
    __syncthreads();
    // ---- frozen loop: wave 0 only, zero barriers, readlane broadcast ----
    if (wid == 0) {
      const int g = lane >> 4, r = lane & 15;
      float Trow[32];
#pragma unroll
      for (int k = 0; k < 16; ++k) {
        Trow[k] = (g == 0) ? Smat[r * 16 + k]
                : (g == 1) ? U[r * 16 + k]
                : (g == 2) ? NGm[r * 16 + k] : Pi[r * 16 + k];
        Trow[16 + k] = (g == 1) ? Gm[k * 16 + r]
                     : (g == 3) ? ((k == r) ? 2.f : 0.f) : 0.f;
      }
      const float uconst = ca[r];  // g==2 drive (constant)
      const int uoff = (g == 0) ? r : (g == 1) ? 16 + r : 32 + r;  // g==3 -> 32+r
      float x = (g == 0) ? mf[r] : (g == 1) ? rv[r] : 0.f;
      for (int tt = tb; tt < 256; ++tt) {
        const float u = (g == 2) ? uconst : u_all[(tt - tb) * 48 + uoff];
        float s0 = u, s1 = 0.f, s2 = 0.f, s3 = 0.f;
#pragma unroll
        for (int k = 0; k < 32; k += 4) {
          s0 = fmaf(Trow[k],     rl(x, k),     s0);
          s1 = fmaf(Trow[k + 1], rl(x, k + 1), s1);
          s2 = fmaf(Trow[k + 2], rl(x, k + 2), s2);
          s3 = fmaf(Trow[k + 3], rl(x, k + 3), s3);
        }
        const float acc = (s0 + s1) + (s2 + s3);
        const float qv = __shfl_down(acc, 16);  // lanes 32-47 get q from 48-63
        if (g == 2) facc = fmaf(acc, qv, facc);
        if (g < 2) x = acc;
      }
      if (g == 0) { mf[r] = x; pb[r] = pbemv[r] - sObs[255 * 16 + r]; }
      else if (g == 1) rv[r] = x;
    }
    __syncthreads();
  } else {
    // never froze (fallback): closure of step 255
    const float sN = dATB(Gm, T1m, i, j) - NGm[j * 16 + i] - NGm[e] + Omt[e];
    Sm[e] = sN;
    d1acc = fmaf(Mm[e] * av[i], av[j], d1acc);
    if (e < 16) {
      float s = -q2[e];
#pragma unroll
      for (int k = 0; k < 16; ++k) {
        s = fmaf(T1m[k * 16 + e], av[k], s);
        s = fmaf(Gm[k * 16 + e], hv[k], s);
        s = fmaf(-Nm[e * 16 + k], av[k], s);
      }
      rv[e] = s;
    } else if (e < 32) {
      fd2 = fmaf(av[e - 16], hv[e - 16], fd2);
      mf[e - 16] = mfN[e - 16];
    }
    __syncthreads();
  }

  // ---- E1: parallel logs (in-place) + the three deferred reductions ----
  const int n = tb - 1;
  if (e >= 1 && e <= n) {
    detPArr[e] = logf(detPArr[e]);
    detSArr[e] = logf(detSArr[e]);
  }
  {
    const float vA = d1acc + 2.f * fd2 + facc;
    const float vB = tacc;
    const float vC = (e < 255) ? d3all[e] : 0.f;
    const float sA = wave_sum(vA);
    const float sB = wave_sum(vB);
    const float sC = wave_sum(vC);
    if (lane == 0) { red[wid] = sA; red2[wid] = sB; red3[wid] = sC; }
  }
  __syncthreads();
  // ---- E2: serial epilogue (tiny) ----
  if (e == 0) {
    const float dsum = red[0] + red[1] + red[2] + red[3];
    const float tsum = red2[0] + red2[1] + red2[2] + red2[3];
    const float d3tot = red3[0] + red3[1] + red3[2] + red3[3];
    float lpf = ld_Pf;
    float sum_ldb = 0.f, ldbl = 0.f;
    for (int s2 = 1; s2 <= n; ++s2) {
      ldbl = lpf + ld_Q - detPArr[s2];
      sum_ldb += ldbl;
      lpf = detPArr[s2] + ld_R - detSArr[s2];
    }
    float sc = sc_const + tsum + (float)n * sh_cstep + 0.5f * sum_ldb;
    if (tb < 256) sc += (float)(256 - tb) * (sh_tstep_inf + sh_cstep + 0.5f * ldbl);
    sc_const = sc;
    ld_Pf = lpf;
    sc_c += dsum + d3tot + 255.f * ctb;
  }
  __syncthreads();

  // ---- final terms ----
  g_Pff[e] = Pf[e];
  g_Ginf[e] = Gm[e];
  if (e == 0) g_tb = tb;
  WP[e] = dAB(Pf, Em, i, j);  // PE = Pf * E
  if (e < 16) tv1[e] = mv(Sm, mf, e);
  else if (e < 32) tv2[e - 16] = pb[e - 16] + mv(Em, mf, e - 16);
  __syncthreads();
  {
    const float v = wave_sum(EOm[e] * WP[e]);
    if (lane == 0) red[wid] = v;
  }
  if (e < 16) Opf[e] = mv(Omo, tv2, e);
  __syncthreads();
  if (e == 0) {
    const float tr_p = red[0] + red[1] + red[2] + red[3];
    float ev1 = 0.f, ev2 = 0.f, evp = 0.f;
    for (int k = 0; k < 16; ++k) {
      ev1 = fmaf(mf[k], tv1[k], ev1);
      ev2 = fmaf(rv[k], mf[k], ev2);
      evp = fmaf(tv2[k], Opf[k], evp);
    }
    g_partial = sc_const + 0.5f * (CT16 + ld_Pf) + (ev1 + 2.f * ev2 + sc_c)
                + tr_p + evp + 8.f;
  }
}

// One block per t. Each block builds its OWN suffix product (binary powering
// of Ginf + short chain over stored G's), computes its trace terms, and the
// last finishing block writes the final output.
__global__ void __launch_bounds__(256)
lgq_trace(const float* __restrict__ pew, const float* __restrict__ ptw,
          float* __restrict__ out) {
  const int e = threadIdx.x, i = e >> 4, j = e & 15, b = blockIdx.x;
  const int lane = e & 63, wid = e >> 6;
  __shared__ float Pfs[256], OmA[256], OmtS[256], EmS[256], PwS[256], GinfS[256];
  __shared__ float Xb[2][256], Bb[2][256];
  __shared__ float Sm1[256], Sf[256], A1[256], A2[256];
  __shared__ float T1v[256], NGv[256], Kxv[256], S2v[256];
  __shared__ float redt[4];
  int tb = g_tb;
  tb = (tb < 1) ? 1 : (tb > 256 ? 256 : tb);  // robustness (rocprof replay)
  Pfs[e] = g_Pff[e];
  OmtS[e] = g_Omt[e];
  EmS[e] = pew[e];
  PwS[e] = ptw[e];
  GinfS[e] = g_Ginf[e];
  OmA[e] = (b == 0) ? g_Om0[e] : g_Omo[e];
  Xb[0][e] = (i == j) ? 1.f : 0.f;
  Bb[0][e] = g_Ginf[e];
  __syncthreads();
  // binary powering: X = Ginf^E0
  int E = (b >= tb) ? (255 - b) : (256 - tb);
  int xc = 0, bc2 = 0;
  while (E) {
    Xb[xc ^ 1][e] = (E & 1) ? dAB(Xb[xc], Bb[bc2], i, j) : Xb[xc][e];
    if (E > 1) Bb[bc2 ^ 1][e] = dAB(Bb[bc2], Bb[bc2], i, j);
    __syncthreads();
    xc ^= 1; bc2 ^= 1;
    E >>= 1;
  }
  if (b >= tb) {
    Sf[e] = Xb[xc][e];                       // Suf_b = Ginf^(255-b)
    Sm1[e] = dAB(GinfS, Xb[xc], i, j);       // Suf_{b-1}
    __syncthreads();
  } else {
    // chain: Suf_b = G_{b+1} ... G_{tb-1} * Ginf^(256-tb)
    int cur = xc;
    for (int s2 = tb - 1; s2 >= b + 1; --s2) {
      const float4* gr = (const float4*)(g_Gstore + (s2 - 1) * 256 + i * 16);
      const float4 a0 = gr[0], a1 = gr[1], a2 = gr[2], a3 = gr[3];
      const float* Xc = Xb[cur];
      float s = 0.f;
      s = fmaf(a0.x, Xc[0 * 16 + j], s);  s = fmaf(a0.y, Xc[1 * 16 + j], s);
      s = fmaf(a0.z, Xc[2 * 16 + j], s);  s = fmaf(a0.w, Xc[3 * 16 + j], s);
      s = fmaf(a1.x, Xc[4 * 16 + j], s);  s = fmaf(a1.y, Xc[5 * 16 + j], s);
      s = fmaf(a1.z, Xc[6 * 16 + j], s);  s = fmaf(a1.w, Xc[7 * 16 + j], s);
      s = fmaf(a2.x, Xc[8 * 16 + j], s);  s = fmaf(a2.y, Xc[9 * 16 + j], s);
      s = fmaf(a2.z, Xc[10 * 16 + j], s); s = fmaf(a2.w, Xc[11 * 16 + j], s);
      s = fmaf(a3.x, Xc[12 * 16 + j], s); s = fmaf(a3.y, Xc[13 * 16 + j], s);
      s = fmaf(a3.z, Xc[14 * 16 + j], s); s = fmaf(a3.w, Xc[15 * 16 + j], s);
      Xb[cur ^ 1][e] = s;
      __syncthreads();
      cur ^= 1;
    }
    Sf[e] = Xb[cur][e];  // Suf_b
    if (b >= 1) {
      const float4* gr = (const float4*)(g_Gstore + (b - 1) * 256 + i * 16);
      const float4 a0 = gr[0], a1 = gr[1], a2 = gr[2], a3 = gr[3];
      const float* Xc = Xb[cur];
      float s = 0.f;
      s = fmaf(a0.x, Xc[0 * 16 + j], s);  s = fmaf(a0.y, Xc[1 * 16 + j], s);
      s = fmaf(a0.z, Xc[2 * 16 + j], s);  s = fmaf(a0.w, Xc[3 * 16 + j], s);
      s = fmaf(a1.x, Xc[4 * 16 + j], s);  s = fmaf(a1.y, Xc[5 * 16 + j], s);
      s = fmaf(a1.z, Xc[6 * 16 + j], s);  s = fmaf(a1.w, Xc[7 * 16 + j], s);
      s = fmaf(a2.x, Xc[8 * 16 + j], s);  s = fmaf(a2.y, Xc[9 * 16 + j], s);
      s = fmaf(a2.z, Xc[10 * 16 + j], s); s = fmaf(a2.w, Xc[11 * 16 + j], s);
      s = fmaf(a3.x, Xc[12 * 16 + j], s); s = fmaf(a3.y, Xc[13 * 16 + j], s);
      s = fmaf(a3.z, Xc[14 * 16 + j], s); s = fmaf(a3.w, Xc[15 * 16 + j], s);
      Sm1[e] = s;          // Suf_{b-1} = G_b * Suf_b
    } else {
      Sm1[e] = Xb[cur][e]; // Suf_0
    }
    __syncthreads();
  }
  if (b == 0) {
    A1[e] = Sm1[e];
    A2[e] = 0.f;
  } else {
    A1[e] = dAB(EmS, Sm1, i, j);
    A2[e] = dAB(PwS, Sm1, i, j) - Sf[e];
  }
  __syncthreads();
  T1v[e] = dAB(OmA, A1, i, j);
  NGv[e] = dAB(Pfs, A1, i, j);
  Kxv[e] = dAB(OmtS, A2, i, j);
  S2v[e] = dAB(Pfs, A2, i, j);
  __syncthreads();
  float val = T1v[e] * NGv[j * 16 + i] + Kxv[e] * S2v[j * 16 + i];
  val = wave_sum(val);
  if (lane == 0) redt[wid] = val;
  __syncthreads();
  if (e == 0) {
    atomicAdd(&g_acc, redt[0] + redt[1] + redt[2] + redt[3]);
    __threadfence();
    const unsigned o = atomicAdd(&g_cnt, 1u);
    if (o == 255u) {
      const float acc = atomicAdd(&g_acc, 0.f);  // final value (all adds done)
      out[0] = g_partial + acc;
    }
  }
}

extern "C" void kernel_launch(void* const* d_in, const int* in_sizes, int n_in,
                              void* d_out, int out_size, void* d_ws, size_t ws_size,
                              hipStream_t stream) {
  (void)in_sizes; (void)n_in; (void)out_size; (void)d_ws; (void)ws_size;
  lgq_fwd<<<dim3(1), dim3(256), 0, stream>>>(
      (const float*)d_in[0], (const float*)d_in[1], (const float*)d_in[2],
      (const float*)d_in[3], (const float*)d_in[4], (const float*)d_in[5],
      (const float*)d_in[6], (const float*)d_in[7], (const float*)d_in[8],
      (const float*)d_in[9], (const float*)d_in[10], (const float*)d_in[11],
      (const float*)d_in[12], (const float*)d_in[13], (const float*)d_in[14],
      (const float*)d_in[15], (const float*)d_in[16]);
  lgq_trace<<<dim3(256), dim3(256), 0, stream>>>((const float*)d_in[6],
                                                 (const float*)d_in[3],
                                                 (float*)d_out);
}

// Round 7
// 96.324 us; speedup vs baseline: 29.9867x; 1.4352x over previous
//
#include <hip/hip_runtime.h>
#include <cmath>

#define L2PI 1.8378770664093453f
#define CT16 (16.f * L2PI)

// Per-launch scratch (fully rewritten every call before being read).
__device__ __align__(16) float g_Gstore[255 * 256];
__device__ float g_Pff[256], g_Om0[256], g_Omo[256], g_Omt[256], g_Ginf[256];
__device__ float g_partial, g_acc;
__device__ int g_tb;
__device__ unsigned g_cnt;

__device__ __forceinline__ float dAB(const float* A, const float* B, int i, int j) {
  float s = 0.f;
#pragma unroll
  for (int k = 0; k < 16; ++k) s = fmaf(A[i * 16 + k], B[k * 16 + j], s);
  return s;
}
__device__ __forceinline__ float dATB(const float* A, const float* B, int i, int j) {
  float s = 0.f;
#pragma unroll
  for (int k = 0; k < 16; ++k) s = fmaf(A[k * 16 + i], B[k * 16 + j], s);
  return s;
}
__device__ __forceinline__ float dABT(const float* A, const float* B, int i, int j) {
  float s = 0.f;
#pragma unroll
  for (int k = 0; k < 16; ++k) s = fmaf(A[i * 16 + k], B[j * 16 + k], s);
  return s;
}
__device__ __forceinline__ float mv(const float* M, const float* v, int r) {
  float s = 0.f;
#pragma unroll
  for (int k = 0; k < 16; ++k) s = fmaf(M[r * 16 + k], v[k], s);
  return s;
}
__device__ __forceinline__ float mvT(const float* M, const float* v, int r) {
  float s = 0.f;
#pragma unroll
  for (int k = 0; k < 16; ++k) s = fmaf(M[k * 16 + r], v[k], s);
  return s;
}
__device__ __forceinline__ float wave_sum(float v) {
#pragma unroll
  for (int off = 32; off; off >>= 1) v += __shfl_down(v, off);
  return v;
}
__device__ __forceinline__ float wave_max(float v) {
#pragma unroll
  for (int off = 32; off; off >>= 1) v = fmaxf(v, __shfl_down(v, off));
  return v;
}
// Broadcast from a compile-time-uniform lane: no LDS round-trip.
__device__ __forceinline__ float rl(float v, int l) {
  return __int_as_float(__builtin_amdgcn_readlane(__float_as_int(v), l));
}

// Register-resident Gauss-Jordan inverse of SPD 16x16, one wave, barrier-free.
__device__ __forceinline__ float reg_gj_core(const float* __restrict__ src,
                                             float aI[4]) {
  const int wl = threadIdx.x & 63;
  const int col = wl & 15, rg = wl >> 4;
  float aA[4];
#pragma unroll
  for (int q = 0; q < 4; ++q) {
    const int r = rg + 4 * q;
    aA[q] = src[r * 16 + col];
    aI[q] = (r == col) ? 1.f : 0.f;
  }
  float det = 1.f;
#pragma unroll
  for (int k = 0; k < 16; ++k) {
    const int kq = k >> 2, kr = k & 3;
    const float piv = rl(aA[kq], (kr << 4) | k);
    det *= piv;
    const float rp = 1.f / piv;
    const float pA = __shfl(aA[kq], (kr << 4) | col);
    const float pI = __shfl(aI[kq], (kr << 4) | col);
    float f[4];
    f[0] = __shfl(aA[0], (rg << 4) | k);
    f[1] = __shfl(aA[1], (rg << 4) | k);
    f[2] = __shfl(aA[2], (rg << 4) | k);
    f[3] = __shfl(aA[3], (rg << 4) | k);
#pragma unroll
    for (int q = 0; q < 4; ++q) {
      const float tq = f[q] * rp;
      const float nA = fmaf(-tq, pA, aA[q]);
      const float nI = fmaf(-tq, pI, aI[q]);
      if (q == kq) {
        const bool isp = (rg == kr);
        aA[q] = isp ? pA * rp : nA;
        aI[q] = isp ? pI * rp : nI;
      } else {
        aA[q] = nA;
        aI[q] = nI;
      }
    }
  }
  return det;
}

__device__ __forceinline__ float reg_gj_inv(const float* __restrict__ src,
                                            float* __restrict__ dst) {
  const int wl = threadIdx.x & 63;
  const int col = wl & 15, rg = wl >> 4;
  float aI[4];
  const float det = reg_gj_core(src, aI);
#pragma unroll
  for (int q = 0; q < 4; ++q) dst[(rg + 4 * q) * 16 + col] = aI[q];
  return det;
}

// GJ inverse fused with a product; inverse never touches LDS.
// MODE 0: dst = Bm^T * inv ; MODE 1: dst = Bm * inv
template <int MODE>
__device__ __forceinline__ float gj_inv_mul(const float* __restrict__ src,
                                            const float* __restrict__ Bm,
                                            float* __restrict__ dst) {
  const int wl = threadIdx.x & 63;
  const int col = wl & 15, rg = wl >> 4;
  float aI[4];
  const float det = reg_gj_core(src, aI);
  float part[16];
#pragma unroll
  for (int ii = 0; ii < 16; ++ii) {
    float s = 0.f;
#pragma unroll
    for (int q = 0; q < 4; ++q) {
      const int k = rg + 4 * q;
      s = fmaf(MODE == 0 ? Bm[k * 16 + ii] : Bm[ii * 16 + k], aI[q], s);
    }
    part[ii] = s;
  }
#pragma unroll
  for (int ii = 0; ii < 16; ++ii) {
    part[ii] += __shfl_xor(part[ii], 16);
    part[ii] += __shfl_xor(part[ii], 32);
  }
  if (rg == 0) {
    dst[0 * 16 + col] = part[0];  dst[1 * 16 + col] = part[1];
    dst[2 * 16 + col] = part[2];  dst[3 * 16 + col] = part[3];
  } else if (rg == 1) {
    dst[4 * 16 + col] = part[4];  dst[5 * 16 + col] = part[5];
    dst[6 * 16 + col] = part[6];  dst[7 * 16 + col] = part[7];
  } else if (rg == 2) {
    dst[8 * 16 + col] = part[8];  dst[9 * 16 + col] = part[9];
    dst[10 * 16 + col] = part[10]; dst[11 * 16 + col] = part[11];
  } else {
    dst[12 * 16 + col] = part[12]; dst[13 * 16 + col] = part[13];
    dst[14 * 16 + col] = part[14]; dst[15 * 16 + col] = part[15];
  }
  return det;
}

__global__ void __launch_bounds__(256)
lgq_fwd(const float* __restrict__ obs,
        const float* __restrict__ ppm, const float* __restrict__ ppc,
        const float* __restrict__ ptw, const float* __restrict__ ptb,
        const float* __restrict__ ptc, const float* __restrict__ pew,
        const float* __restrict__ peb, const float* __restrict__ pec,
        const float* __restrict__ qpm, const float* __restrict__ qpc,
        const float* __restrict__ qtw, const float* __restrict__ qtb,
        const float* __restrict__ qtc, const float* __restrict__ qew,
        const float* __restrict__ qeb, const float* __restrict__ qec) {
  const int e = threadIdx.x;
  const int i = e >> 4, j = e & 15;
  const int wid = e >> 6;
  const int lane = e & 63;

  __shared__ float W[256], Qm[256], Hm[256], Rm[256], Em[256], Pwm[256];
  __shared__ float HW[256], QHt[256], HQH[256], TmpB[256];
  __shared__ float Om0[256], Omo[256], Omt[256], Fo[256], Ft[256], Nm[256], EOm[256];
  __shared__ float Sm[256], Pf[256];
  __shared__ float WP[256], U[256], Ppred[256], Smat[256], PHt[256];
  __shared__ float Pi[256], Si[256], Gm[256], Kgm[256], Mm[256], T1m[256], NGm[256];
  __shared__ float sObs[256 * 16];
  __shared__ float detPArr[256], detSArr[256], d3all[256];
  // frozen-region doubling tables (reused across stages)
  __shared__ float uB1[252 * 16], pB1[252 * 16], pC1[252 * 16];
  __shared__ float mfs1[252 * 16], rvs1[252 * 16];
  __shared__ float mf[16], mfN[16], rv[16], pb[16], bqv[16], bemv[16], pbemv[16],
      ptbv[16];
  __shared__ float w2[16], q2[16], mpred[16], av[16], hv[16];
  __shared__ float EOpb[16], resid[16], tv1[16], tv2[16], Opf[16];
  __shared__ float ca[16], mca[16], nca[16], c1[16], cg1[16], qc[16], epbm[16];
  __shared__ float red[4], red2[4], red3[4], dets[6];
  __shared__ float sc_const, sc_c, ctb, sh_cstep;
  __shared__ float ld_pprior, ld_ptr, ld_pem, ld_Q, ld_R, ld_qprior, ld_Pf;
  __shared__ float sh_detS, sh_tstep_inf;
  __shared__ int sh_frozen;

  // I0: load fixed inputs + stage obs into LDS
  W[e] = qtw[e]; Qm[e] = qtc[e]; Hm[e] = qew[e]; Rm[e] = qec[e];
  Em[e] = pew[e]; Pwm[e] = ptw[e];
  {
    const float4* o4 = (const float4*)obs;
    float4* s4 = (float4*)sObs;
#pragma unroll
    for (int q = 0; q < 4; ++q) s4[e + 256 * q] = o4[e + 256 * q];
  }
  if (e < 16) { bqv[e] = qtb[e]; bemv[e] = qeb[e]; pbemv[e] = peb[e]; ptbv[e] = ptb[e]; }
  if (e == 0) { sh_frozen = 0; g_acc = 0.f; g_cnt = 0u; }
  __syncthreads();
  // I1
  HW[e] = dAB(Hm, W, i, j);
  TmpB[e] = dAB(Hm, Qm, i, j);
  __syncthreads();
  // I2
  HQH[e] = dABT(TmpB, Hm, i, j) + Rm[e];
  QHt[e] = TmpB[j * 16 + i];
  __syncthreads();
  // I3: six fixed inversions, two per wave
  if (wid == 0) {
    float d0 = reg_gj_inv(ppc, Pi);
    float d1 = reg_gj_inv(ptc, Si);
    if (e == 0) { dets[0] = d0; dets[1] = d1; }
  } else if (wid == 1) {
    float d2 = reg_gj_inv(pec, Gm);
    float d3 = reg_gj_inv(qtc, Kgm);
    if (e == 64) { dets[2] = d2; dets[3] = d3; }
  } else if (wid == 2) {
    float d4 = reg_gj_inv(qec, T1m);
    float d5 = reg_gj_inv(qpc, NGm);
    if (e == 128) { dets[4] = d4; dets[5] = d5; }
  }
  __syncthreads();
  // I45 (merged): Omega scaling folded into consumers; one barrier saved
  Om0[e] = -0.5f * Pi[e];
  Omt[e] = -0.5f * Si[e];
  Omo[e] = -0.5f * Gm[e];
  g_Om0[e] = Om0[e]; g_Omo[e] = Omo[e]; g_Omt[e] = Omt[e];
  Sm[e] = Om0[e];
  TmpB[e] = -0.5f * dAB(Gm, Em, i, j);   // Omo*E
  Nm[e] = -0.5f * dAB(Si, Pwm, i, j);    // Omt*Pw
  EOm[e] = -0.5f * dATB(Em, Gm, i, j);   // E^T*Omo
  if (e == 0) {
    ld_pprior = logf(dets[0]); ld_ptr = logf(dets[1]); ld_pem = logf(dets[2]);
    ld_Q = logf(dets[3]); ld_R = logf(dets[4]); ld_qprior = logf(dets[5]);
  }
  __syncthreads();
  // I6: fixed quadratic mats, vectors, and d3all[t] = pb_t^T Omo pb_t for ALL t
  Fo[e] = dATB(Em, TmpB, i, j);
  Ft[e] = dATB(Pwm, Nm, i, j);
  if (e < 16) w2[e] = mvT(Nm, ptbv, e);
  else if (e < 32) q2[e - 16] = mv(Omt, ptbv, e - 16);
  else if (e < 48) rv[e - 32] = -mv(Om0, ppm, e - 32);
  else if (e < 64) pb[e - 48] = pbemv[e - 48] - sObs[e - 48];
  {
    const int rr = e & 15, tg = e >> 4;
#pragma unroll
    for (int it = 0; it < 16; ++it) {
      const int tt = it * 16 + tg;
      float s = 0.f;
#pragma unroll
      for (int k = 0; k < 16; ++k)
        s = fmaf(Omo[rr * 16 + k], pbemv[k] - sObs[tt * 16 + k], s);
      s *= (pbemv[rr] - sObs[tt * 16 + rr]);
      s += __shfl_xor(s, 1); s += __shfl_xor(s, 2);
      s += __shfl_xor(s, 4); s += __shfl_xor(s, 8);
      if (rr == 0) d3all[tt] = s;
    }
  }
  __syncthreads();
  // I7
  if (e == 0) {
    float s = 0.f, ct = 0.f;
    for (int k = 0; k < 16; ++k) { s = fmaf(ppm[k], rv[k], s); ct = fmaf(ptbv[k], q2[k], ct); }
    sc_c = -s;
    ctb = ct;
    sc_const = -0.5f * (CT16 + ld_pprior) - 0.5f * (CT16 + ld_pem);
    sh_cstep = 8.f - 0.5f * CT16 - 0.5f * (ld_pem + ld_ptr);
  }
  if (e < 16) mpred[e] = qpm[e];
  TmpB[e] = dAB(Hm, qpc, i, j);
  __syncthreads();
  // I8
  Smat[e] = dABT(TmpB, Hm, i, j) + Rm[e];
  if (e < 16) resid[e] = sObs[e] - bemv[e] - mv(Hm, mpred, e);
  __syncthreads();
  // I9
  if (wid == 0) {
    float d = reg_gj_inv(Smat, Si);
    if (e == 0) sh_detS = d;
  }
  __syncthreads();
  // I10
  Kgm[e] = dATB(TmpB, Si, i, j);
  if (e == 0) ld_Pf = ld_qprior + ld_R - logf(sh_detS);  // ld_Pf_0
  __syncthreads();
  // I11
  Pf[e] = qpc[e] - dAB(Kgm, TmpB, i, j);
  if (e < 16) { mf[e] = mpred[e] + mv(Kgm, resid, e); mfN[e] = mf[e]; }
  __syncthreads();

  // ---- forward scan: 4 phases/step ----
  float d1acc = 0.f, tacc = 0.f, fd2 = 0.f, facc = 0.f;
  int t = 1;
  for (; t < 256; ++t) {
    const float* y = sObs + t * 16;
    // P_A: staging + closure of step t-1
    WP[e] = dAB(W, Pf, i, j);
    U[e] = dAB(HW, Pf, i, j);
    if (t > 1) {
      const float sN = dATB(Gm, T1m, i, j) - NGm[j * 16 + i] - NGm[e] + Omt[e];
      const float sd = fabsf(sN - Sm[e]);
      Sm[e] = sN;
      const float vm = wave_max(sd);
      if (lane == 0) red3[wid] = vm;
      d1acc = fmaf(Mm[e] * av[i], av[j], d1acc);
      if (e < 16) {
        float s = -q2[e];
#pragma unroll
        for (int k = 0; k < 16; ++k) {
          s = fmaf(T1m[k * 16 + e], av[k], s);
          s = fmaf(Gm[k * 16 + e], hv[k], s);
          s = fmaf(-Nm[e * 16 + k], av[k], s);
        }
        rv[e] = s;
      } else if (e < 32) {
        fd2 = fmaf(av[e - 16], hv[e - 16], fd2);
        mf[e - 16] = mfN[e - 16];
      } else if (e < 48) {
        mpred[e - 32] = bqv[e - 32] + mv(W, mfN, e - 32);
      }
    } else {
      if (e < 16) mpred[e] = bqv[e] + mv(W, mf, e);
    }
    __syncthreads();
    // P_B: predicted covariances + freeze decision
    Ppred[e] = dABT(WP, W, i, j) + Qm[e];
    Smat[e] = dABT(U, HW, i, j) + HQH[e];
    PHt[e] = dABT(WP, HW, i, j) + QHt[e];
    if (e < 16) resid[e] = y[e] - bemv[e] - mv(Hm, mpred, e);
    if (e == 0 && t >= 5) {
      const float pfd = fmaxf(fmaxf(red2[0], red2[1]), fmaxf(red2[2], red2[3]));
      const float sdm = fmaxf(fmaxf(red3[0], red3[1]), fmaxf(red3[2], red3[3]));
      if (pfd < 3e-3f && sdm < 3e-2f) sh_frozen = 1;
    }
    __syncthreads();
    if (sh_frozen) break;
    // P_C: inversions fused with gain products (waves 0,1); M/EOpb (wave 2)
    if (wid == 0) {
      const float d = gj_inv_mul<0>(Ppred, WP, Gm);   // G = WP^T * Ppred^-1
      if (e == 0) detPArr[t] = d;
    } else if (wid == 1) {
      const float d = gj_inv_mul<1>(Smat, PHt, Kgm);  // Kg = PHt * Smat^-1
      if (e == 64) detSArr[t] = d;
    } else if (wid == 2) {
      const int wl = e & 63;
#pragma unroll
      for (int q = 0; q < 4; ++q) { const int x = wl + 64 * q; Mm[x] = Sm[x] + Fo[x] + Ft[x]; }
      if (wl < 16) EOpb[wl] = mv(EOm, pb, wl);
    }
    __syncthreads();
    // P_D: trace partial, Pf update, M*G, N*G, vectors, G store
    {
      const float bc = Pf[e] - dAB(Gm, WP, i, j);
      tacc = fmaf(Mm[e], bc, tacc);
      const float pfN = Ppred[e] - dABT(Kgm, PHt, i, j);
      const float df = fabsf(pfN - Pf[e]);
      Pf[e] = pfN;
      const float vm = wave_max(df);
      if (lane == 0) red2[wid] = vm;
    }
    T1m[e] = dAB(Mm, Gm, i, j);
    NGm[e] = dAB(Nm, Gm, i, j);
    g_Gstore[(t - 1) * 256 + e] = Gm[e];
    if (e < 16) av[e] = mf[e] - mv(Gm, mpred, e);
    else if (e < 32) mfN[e - 16] = mpred[e - 16] + mv(Kgm, resid, e - 16);
    else if (e < 48) hv[e - 32] = rv[e - 32] + EOpb[e - 32] + w2[e - 32];
    else if (e < 64) pb[e - 48] = pbemv[e - 48] - y[e - 48];
    __syncthreads();
  }

  const int tb = t;  // steps 1..tb-1 fully processed
  if (sh_frozen) {
    const int NT = 256 - tb;  // frozen steps t = tb..255; k = t-(tb-1) in [1,NT]
    const int AA = NT & ~3;   // last 4-step anchor
    const int r16 = e & 15, kslot = e >> 4;
    // ---- B1 ----
    T1m[e] = dAB(Kgm, Hm, i, j);                          // KH
    NGm[e] = ((i == j) ? 1.f : 0.f) - dAB(Gm, W, i, j);   // Av
    Mm[e] = Sm[e] + Fo[e] + Ft[e];
    if (e < 16) ca[e] = -mv(Gm, bqv, e);
    else if (e < 32) epbm[e - 16] = mv(EOm, pbemv, e - 16);
    __syncthreads();
    // ---- B2 ----
    Smat[e] = W[e] - dAB(T1m, W, i, j);                   // A1
    Pi[e] = dAB(Mm, NGm, i, j);                           // MAv
    Si[e] = dAB(Nm, NGm, i, j);                           // NAv
    {
      const float bcf = Pf[e] - dAB(Gm, WP, i, j);        // frozen bcov
      const float v = wave_sum(Mm[e] * bcf);
      if (lane == 0) red[wid] = v;
    }
    if (e < 16) mca[e] = mv(Mm, ca, e);
    else if (e < 32) nca[e - 16] = mv(Nm, ca, e - 16);
    else if (e < 48) {
      const int r = e - 32;
      c1[r] = bqv[r] - mv(T1m, bqv, r) - mv(Kgm, bemv, r);
    }
    __syncthreads();
    // ---- B3: B1m, GEO, cg1, qc + uA drives + A2, G2 + state init ----
    U[e] = dATB(Gm, Pi, i, j) - Si[e];                    // B1m
    Ppred[e] = dATB(Gm, EOm, i, j);                       // GEO
    Fo[e] = dAB(Smat, Smat, i, j);                        // A2  (Fo dead -> reuse)
    HW[e] = dAB(Gm, Gm, i, j);                            // G2  (HW dead -> reuse)
    if (e < 16) {
      float s = 0.f;
#pragma unroll
      for (int k = 0; k < 16; ++k)
        s = fmaf(Gm[k * 16 + e], w2[k] + mca[k] + epbm[k], s);
      cg1[e] = s - nca[e] - q2[e];
    } else if (e < 32) {
      const int r = e - 16;
      qc[r] = mca[r] + 2.f * w2[r] + 2.f * epbm[r];
    } else if (e < 48) {
      mfs1[e - 32] = mf[e - 32];
    } else if (e < 64) {
      rvs1[e - 48] = rv[e - 48];
    }
    if (e == 0) sh_tstep_inf = red[0] + red[1] + red[2] + red[3];
    {
      float kgrow[16];
#pragma unroll
      for (int k2 = 0; k2 < 16; ++k2) kgrow[k2] = Kgm[r16 * 16 + k2];
      const float c1r = c1[r16];  // c1 written in B2, barriered
      for (int k = 1 + kslot; k <= NT; k += 16) {
        const float* yc = sObs + (tb - 1 + k) * 16;
        float s = c1r;
#pragma unroll
        for (int k2 = 0; k2 < 16; ++k2) s = fmaf(kgrow[k2], yc[k2], s);
        uB1[k * 16 + r16] = s;  // uA
      }
    }
    __syncthreads();
    // ---- F2: p2 drives, A4, G4 ----
    Ft[e] = dAB(Fo, Fo, i, j);                            // A4 (Ft dead -> reuse)
    QHt[e] = dAB(HW, HW, i, j);                           // G4 (QHt dead -> reuse)
    {
      float a1row[16];
#pragma unroll
      for (int k2 = 0; k2 < 16; ++k2) a1row[k2] = Smat[r16 * 16 + k2];
      for (int k = 2 + kslot; k <= NT; k += 16) {
        const float* up = uB1 + (k - 1) * 16;
        float s = uB1[k * 16 + r16];
#pragma unroll
        for (int k2 = 0; k2 < 16; ++k2) s = fmaf(a1row[k2], up[k2], s);
        pB1[k * 16 + r16] = s;  // p2
      }
    }
    __syncthreads();
    // ---- F3: p4 drives ----
    {
      float a2row[16];
#pragma unroll
      for (int k2 = 0; k2 < 16; ++k2) a2row[k2] = Fo[r16 * 16 + k2];
      for (int k = 4 + kslot; k <= NT; k += 16) {
        const float* pp = pB1 + (k - 2) * 16;
        float s = pB1[k * 16 + r16];
#pragma unroll
        for (int k2 = 0; k2 < 16; ++k2) s = fmaf(a2row[k2], pp[k2], s);
        pC1[k * 16 + r16] = s;  // p4
      }
    }
    __syncthreads();
    // ---- S_mf: serial anchor chain mf_{k} = A4 mf_{k-4} + p4_k ----
    if (wid == 0 && AA >= 4) {
      const int r = lane & 15;
      float a4row[16];
#pragma unroll
      for (int k2 = 0; k2 < 16; ++k2) a4row[k2] = Ft[r * 16 + k2];
      float x = mf[r];
      float d0 = pC1[4 * 16 + r];
      float d1 = (AA >= 8) ? pC1[8 * 16 + r] : 0.f;
      for (int k = 4; k <= AA; k += 4) {
        const float d2 = (k + 8 <= AA) ? pC1[(k + 8) * 16 + r] : 0.f;
        float s0 = d0, s1 = 0.f, s2 = 0.f, s3 = 0.f;
#pragma unroll
        for (int k2 = 0; k2 < 16; k2 += 4) {
          s0 = fmaf(a4row[k2],     rl(x, k2),     s0);
          s1 = fmaf(a4row[k2 + 1], rl(x, k2 + 1), s1);
          s2 = fmaf(a4row[k2 + 2], rl(x, k2 + 2), s2);
          s3 = fmaf(a4row[k2 + 3], rl(x, k2 + 3), s3);
        }
        x = (s0 + s1) + (s2 + s3);
        if (lane < 16) mfs1[k * 16 + r] = x;
        d0 = d1; d1 = d2;
      }
    }
    __syncthreads();
    // ---- R1: mfs[a+1], mfs[a+2] from anchors ----
    {
      float a1row[16], a2row[16];
#pragma unroll
      for (int k2 = 0; k2 < 16; ++k2) {
        a1row[k2] = Smat[r16 * 16 + k2];
        a2row[k2] = Fo[r16 * 16 + k2];
      }
      for (int a = 4 * kslot; a <= NT; a += 64) {
        const float* mfp = mfs1 + a * 16;
        if (a + 1 <= NT) {
          float s = uB1[(a + 1) * 16 + r16];
#pragma unroll
          for (int k2 = 0; k2 < 16; ++k2) s = fmaf(a1row[k2], mfp[k2], s);
          mfs1[(a + 1) * 16 + r16] = s;
        }
        if (a + 2 <= NT) {
          float s = pB1[(a + 2) * 16 + r16];
#pragma unroll
          for (int k2 = 0; k2 < 16; ++k2) s = fmaf(a2row[k2], mfp[k2], s);
          mfs1[(a + 2) * 16 + r16] = s;
        }
      }
    }
    __syncthreads();
    // ---- R2: mfs[a+3] ----
    {
      float a2row[16];
#pragma unroll
      for (int k2 = 0; k2 < 16; ++k2) a2row[k2] = Fo[r16 * 16 + k2];
      for (int a = 4 * kslot; a <= NT; a += 64) {
        if (a + 3 <= NT) {
          const float* mfp = mfs1 + (a + 1) * 16;
          float s = pB1[(a + 3) * 16 + r16];
#pragma unroll
          for (int k2 = 0; k2 < 16; ++k2) s = fmaf(a2row[k2], mfp[k2], s);
          mfs1[(a + 3) * 16 + r16] = s;
        }
      }
    }
    __syncthreads();
    // ---- W1: w_k = B1m*mfs[k-1] + cg1 - GEO*y_{k-1}; finalize mf, pb ----
    {
      float b1row[16], georow[16];
#pragma unroll
      for (int k2 = 0; k2 < 16; ++k2) {
        b1row[k2] = U[r16 * 16 + k2];
        georow[k2] = Ppred[r16 * 16 + k2];
      }
      const float cg1r = cg1[r16];
      for (int k = 1 + kslot; k <= NT; k += 16) {
        const float* mfp = mfs1 + (k - 1) * 16;
        const float* yp = sObs + (tb - 2 + k) * 16;
        float s = cg1r;
#pragma unroll
        for (int k2 = 0; k2 < 16; ++k2) {
          s = fmaf(b1row[k2], mfp[k2], s);
          s = fmaf(-georow[k2], yp[k2], s);
        }
        uB1[k * 16 + r16] = s;  // wA (overwrites uA)
      }
    }
    if (e < 16) { mf[e] = mfs1[NT * 16 + e]; pb[e] = pbemv[e] - sObs[255 * 16 + e]; }
    __syncthreads();
    // ---- W2: w2_k = G^T wA_{k-1} + wA_k ----
    {
      float gtrow[16];
#pragma unroll
      for (int k2 = 0; k2 < 16; ++k2) gtrow[k2] = Gm[k2 * 16 + r16];
      for (int k = 2 + kslot; k <= NT; k += 16) {
        const float* wp = uB1 + (k - 1) * 16;
        float s = uB1[k * 16 + r16];
#pragma unroll
        for (int k2 = 0; k2 < 16; ++k2) s = fmaf(gtrow[k2], wp[k2], s);
        pB1[k * 16 + r16] = s;
      }
    }
    __syncthreads();
    // ---- W3: w4_k = (G^2)^T w2_{k-2} + w2_k ----
    {
      float gt2row[16];
#pragma unroll
      for (int k2 = 0; k2 < 16; ++k2) gt2row[k2] = HW[k2 * 16 + r16];
      for (int k = 4 + kslot; k <= NT; k += 16) {
        const float* wp = pB1 + (k - 2) * 16;
        float s = pB1[k * 16 + r16];
#pragma unroll
        for (int k2 = 0; k2 < 16; ++k2) s = fmaf(gt2row[k2], wp[k2], s);
        pC1[k * 16 + r16] = s;
      }
    }
    __syncthreads();
    // ---- S_rv: serial anchor chain rv_k = (G^4)^T rv_{k-4} + w4_k ----
    if (wid == 0 && AA >= 4) {
      const int r = lane & 15;
      float g4row[16];
#pragma unroll
      for (int k2 = 0; k2 < 16; ++k2) g4row[k2] = QHt[k2 * 16 + r];
      float x = rv[r];
      float d0 = pC1[4 * 16 + r];
      float d1 = (AA >= 8) ? pC1[8 * 16 + r] : 0.f;
      for (int k = 4; k <= AA; k += 4) {
        const float d2 = (k + 8 <= AA) ? pC1[(k + 8) * 16 + r] : 0.f;
        float s0 = d0, s1 = 0.f, s2 = 0.f, s3 = 0.f;
#pragma unroll
        for (int k2 = 0; k2 < 16; k2 += 4) {
          s0 = fmaf(g4row[k2],     rl(x, k2),     s0);
          s1 = fmaf(g4row[k2 + 1], rl(x, k2 + 1), s1);
          s2 = fmaf(g4row[k2 + 2], rl(x, k2 + 2), s2);
          s3 = fmaf(g4row[k2 + 3], rl(x, k2 + 3), s3);
        }
        x = (s0 + s1) + (s2 + s3);
        if (lane < 16) rvs1[k * 16 + r] = x;
        d0 = d1; d1 = d2;
      }
    }
    __syncthreads();
    // ---- RV-R1: rvs[a+1], rvs[a+2] ----
    {
      float gtrow[16], gt2row[16];
#pragma unroll
      for (int k2 = 0; k2 < 16; ++k2) {
        gtrow[k2] = Gm[k2 * 16 + r16];
        gt2row[k2] = HW[k2 * 16 + r16];
      }
      for (int a = 4 * kslot; a <= NT; a += 64) {
        const float* rp = rvs1 + a * 16;
        if (a + 1 <= NT) {
          float s = uB1[(a + 1) * 16 + r16];
#pragma unroll
          for (int k2 = 0; k2 < 16; ++k2) s = fmaf(gtrow[k2], rp[k2], s);
          rvs1[(a + 1) * 16 + r16] = s;
        }
        if (a + 2 <= NT) {
          float s = pB1[(a + 2) * 16 + r16];
#pragma unroll
          for (int k2 = 0; k2 < 16; ++k2) s = fmaf(gt2row[k2], rp[k2], s);
          rvs1[(a + 2) * 16 + r16] = s;
        }
      }
    }
    __syncthreads();
    // ---- RV-R2: rvs[a+3] ----
    {
      float gt2row[16];
#pragma unroll
      for (int k2 = 0; k2 < 16; ++k2) gt2row[k2] = HW[k2 * 16 + r16];
      for (int a = 4 * kslot; a <= NT; a += 64) {
        if (a + 3 <= NT) {
          const float* rp = rvs1 + (a + 1) * 16;
          float s = pB1[(a + 3) * 16 + r16];
#pragma unroll
          for (int k2 = 0; k2 < 16; ++k2) s = fmaf(gt2row[k2], rp[k2], s);
          rvs1[(a + 3) * 16 + r16] = s;
        }
      }
    }
    __syncthreads();
    // ---- OUT: facc = sum_k (Av mf + ca)^T (MAv mf + 2 rv + qc - 2 EOm y) ----
    {
      float avrow[16], mavrow[16], eorow[16];
#pragma unroll
      for (int k2 = 0; k2 < 16; ++k2) {
        avrow[k2] = NGm[r16 * 16 + k2];
        mavrow[k2] = Pi[r16 * 16 + k2];
        eorow[k2] = EOm[r16 * 16 + k2];
      }
      const float car = ca[r16], qcr = qc[r16];
      for (int k = 1 + kslot; k <= NT; k += 16) {
        const float* mfp = mfs1 + (k - 1) * 16;
        const float* yp = sObs + (tb - 2 + k) * 16;
        float avr = car, qr = qcr + 2.f * rvs1[(k - 1) * 16 + r16];
#pragma unroll
        for (int k2 = 0; k2 < 16; ++k2) {
          avr = fmaf(avrow[k2], mfp[k2], avr);
          qr = fmaf(mavrow[k2], mfp[k2], qr);
          qr = fmaf(-2.f * eorow[k2], yp[k2], qr);
        }
        facc = fmaf(avr, qr, facc);
      }
    }
    if (e < 16) rv[e] = rvs1[NT * 16 + e];
    __syncthreads();
  } else {
    // never froze (fallback): closure of step 255
    const float sN = dATB(Gm, T1m, i, j) - NGm[j * 16 + i] - NGm[e] + Omt[e];
    Sm[e] = sN;
    d1acc = fmaf(Mm[e] * av[i], av[j], d1acc);
    if (e < 16) {
      float s = -q2[e];
#pragma unroll
      for (int k = 0; k < 16; ++k) {
        s = fmaf(T1m[k * 16 + e], av[k], s);
        s = fmaf(Gm[k * 16 + e], hv[k], s);
        s = fmaf(-Nm[e * 16 + k], av[k], s);
      }
      rv[e] = s;
    } else if (e < 32) {
      fd2 = fmaf(av[e - 16], hv[e - 16], fd2);
      mf[e - 16] = mfN[e - 16];
    }
    __syncthreads();
  }

  // ---- E1: parallel logs (in-place) + the three deferred reductions ----
  const int n = tb - 1;
  if (e >= 1 && e <= n) {
    detPArr[e] = logf(detPArr[e]);
    detSArr[e] = logf(detSArr[e]);
  }
  {
    const float vA = d1acc + 2.f * fd2 + facc;
    const float vB = tacc;
    const float vC = (e < 255) ? d3all[e] : 0.f;
    const float sA = wave_sum(vA);
    const float sB = wave_sum(vB);
    const float sC = wave_sum(vC);
    if (lane == 0) { red[wid] = sA; red2[wid] = sB; red3[wid] = sC; }
  }
  __syncthreads();
  // ---- E2: serial epilogue (tiny) ----
  if (e == 0) {
    const float dsum = red[0] + red[1] + red[2] + red[3];
    const float tsum = red2[0] + red2[1] + red2[2] + red2[3];
    const float d3tot = red3[0] + red3[1] + red3[2] + red3[3];
    float lpf = ld_Pf;
    float sum_ldb = 0.f, ldbl = 0.f;
    for (int s2 = 1; s2 <= n; ++s2) {
      ldbl = lpf + ld_Q - detPArr[s2];
      sum_ldb += ldbl;
      lpf = detPArr[s2] + ld_R - detSArr[s2];
    }
    float sc = sc_const + tsum + (float)n * sh_cstep + 0.5f * sum_ldb;
    if (tb < 256) sc += (float)(256 - tb) * (sh_tstep_inf + sh_cstep + 0.5f * ldbl);
    sc_const = sc;
    ld_Pf = lpf;
    sc_c += dsum + d3tot + 255.f * ctb;
  }
  __syncthreads();

  // ---- final terms ----
  g_Pff[e] = Pf[e];
  g_Ginf[e] = Gm[e];
  if (e == 0) g_tb = tb;
  WP[e] = dAB(Pf, Em, i, j);  // PE = Pf * E
  if (e < 16) tv1[e] = mv(Sm, mf, e);
  else if (e < 32) tv2[e - 16] = pb[e - 16] + mv(Em, mf, e - 16);
  __syncthreads();
  {
    const float v = wave_sum(EOm[e] * WP[e]);
    if (lane == 0) red[wid] = v;
  }
  if (e < 16) Opf[e] = mv(Omo, tv2, e);
  __syncthreads();
  if (e == 0) {
    const float tr_p = red[0] + red[1] + red[2] + red[3];
    float ev1 = 0.f, ev2 = 0.f, evp = 0.f;
    for (int k = 0; k < 16; ++k) {
      ev1 = fmaf(mf[k], tv1[k], ev1);
      ev2 = fmaf(rv[k], mf[k], ev2);
      evp = fmaf(tv2[k], Opf[k], evp);
    }
    g_partial = sc_const + 0.5f * (CT16 + ld_Pf) + (ev1 + 2.f * ev2 + sc_c)
                + tr_p + evp + 8.f;
  }
}

// One block per t. Each block builds its OWN suffix product (binary powering
// of Ginf + short chain over stored G's), computes its trace terms, and the
// last finishing block writes the final output.
__global__ void __launch_bounds__(256)
lgq_trace(const float* __restrict__ pew, const float* __restrict__ ptw,
          float* __restrict__ out) {
  const int e = threadIdx.x, i = e >> 4, j = e & 15, b = blockIdx.x;
  const int lane = e & 63, wid = e >> 6;
  __shared__ float Pfs[256], OmA[256], OmtS[256], EmS[256], PwS[256], GinfS[256];
  __shared__ float Xb[2][256], Bb[2][256];
  __shared__ float Sm1[256], Sf[256], A1[256], A2[256];
  __shared__ float T1v[256], NGv[256], Kxv[256], S2v[256];
  __shared__ float redt[4];
  int tb = g_tb;
  tb = (tb < 1) ? 1 : (tb > 256 ? 256 : tb);  // robustness (rocprof replay)
  Pfs[e] = g_Pff[e];
  OmtS[e] = g_Omt[e];
  EmS[e] = pew[e];
  PwS[e] = ptw[e];
  GinfS[e] = g_Ginf[e];
  OmA[e] = (b == 0) ? g_Om0[e] : g_Omo[e];
  Xb[0][e] = (i == j) ? 1.f : 0.f;
  Bb[0][e] = g_Ginf[e];
  __syncthreads();
  // binary powering: X = Ginf^E0
  int E = (b >= tb) ? (255 - b) : (256 - tb);
  int xc = 0, bc2 = 0;
  while (E) {
    Xb[xc ^ 1][e] = (E & 1) ? dAB(Xb[xc], Bb[bc2], i, j) : Xb[xc][e];
    if (E > 1) Bb[bc2 ^ 1][e] = dAB(Bb[bc2], Bb[bc2], i, j);
    __syncthreads();
    xc ^= 1; bc2 ^= 1;
    E >>= 1;
  }
  if (b >= tb) {
    Sf[e] = Xb[xc][e];                       // Suf_b = Ginf^(255-b)
    Sm1[e] = dAB(GinfS, Xb[xc], i, j);       // Suf_{b-1}
    __syncthreads();
  } else {
    // chain: Suf_b = G_{b+1} ... G_{tb-1} * Ginf^(256-tb)
    int cur = xc;
    for (int s2 = tb - 1; s2 >= b + 1; --s2) {
      const float4* gr = (const float4*)(g_Gstore + (s2 - 1) * 256 + i * 16);
      const float4 a0 = gr[0], a1 = gr[1], a2 = gr[2], a3 = gr[3];
      const float* Xc = Xb[cur];
      float s = 0.f;
      s = fmaf(a0.x, Xc[0 * 16 + j], s);  s = fmaf(a0.y, Xc[1 * 16 + j], s);
      s = fmaf(a0.z, Xc[2 * 16 + j], s);  s = fmaf(a0.w, Xc[3 * 16 + j], s);
      s = fmaf(a1.x, Xc[4 * 16 + j], s);  s = fmaf(a1.y, Xc[5 * 16 + j], s);
      s = fmaf(a1.z, Xc[6 * 16 + j], s);  s = fmaf(a1.w, Xc[7 * 16 + j], s);
      s = fmaf(a2.x, Xc[8 * 16 + j], s);  s = fmaf(a2.y, Xc[9 * 16 + j], s);
      s = fmaf(a2.z, Xc[10 * 16 + j], s); s = fmaf(a2.w, Xc[11 * 16 + j], s);
      s = fmaf(a3.x, Xc[12 * 16 + j], s); s = fmaf(a3.y, Xc[13 * 16 + j], s);
      s = fmaf(a3.z, Xc[14 * 16 + j], s); s = fmaf(a3.w, Xc[15 * 16 + j], s);
      Xb[cur ^ 1][e] = s;
      __syncthreads();
      cur ^= 1;
    }
    Sf[e] = Xb[cur][e];  // Suf_b
    if (b >= 1) {
      const float4* gr = (const float4*)(g_Gstore + (b - 1) * 256 + i * 16);
      const float4 a0 = gr[0], a1 = gr[1], a2 = gr[2], a3 = gr[3];
      const float* Xc = Xb[cur];
      float s = 0.f;
      s = fmaf(a0.x, Xc[0 * 16 + j], s);  s = fmaf(a0.y, Xc[1 * 16 + j], s);
      s = fmaf(a0.z, Xc[2 * 16 + j], s);  s = fmaf(a0.w, Xc[3 * 16 + j], s);
      s = fmaf(a1.x, Xc[4 * 16 + j], s);  s = fmaf(a1.y, Xc[5 * 16 + j], s);
      s = fmaf(a1.z, Xc[6 * 16 + j], s);  s = fmaf(a1.w, Xc[7 * 16 + j], s);
      s = fmaf(a2.x, Xc[8 * 16 + j], s);  s = fmaf(a2.y, Xc[9 * 16 + j], s);
      s = fmaf(a2.z, Xc[10 * 16 + j], s); s = fmaf(a2.w, Xc[11 * 16 + j], s);
      s = fmaf(a3.x, Xc[12 * 16 + j], s); s = fmaf(a3.y, Xc[13 * 16 + j], s);
      s = fmaf(a3.z, Xc[14 * 16 + j], s); s = fmaf(a3.w, Xc[15 * 16 + j], s);
      Sm1[e] = s;          // Suf_{b-1} = G_b * Suf_b
    } else {
      Sm1[e] = Xb[cur][e]; // Suf_0
    }
    __syncthreads();
  }
  if (b == 0) {
    A1[e] = Sm1[e];
    A2[e] = 0.f;
  } else {
    A1[e] = dAB(EmS, Sm1, i, j);
    A2[e] = dAB(PwS, Sm1, i, j) - Sf[e];
  }
  __syncthreads();
  T1v[e] = dAB(OmA, A1, i, j);
  NGv[e] = dAB(Pfs, A1, i, j);
  Kxv[e] = dAB(OmtS, A2, i, j);
  S2v[e] = dAB(Pfs, A2, i, j);
  __syncthreads();
  float val = T1v[e] * NGv[j * 16 + i] + Kxv[e] * S2v[j * 16 + i];
  val = wave_sum(val);
  if (lane == 0) redt[wid] = val;
  __syncthreads();
  if (e == 0) {
    atomicAdd(&g_acc, redt[0] + redt[1] + redt[2] + redt[3]);
    __threadfence();
    const unsigned o = atomicAdd(&g_cnt, 1u);
    if (o == 255u) {
      const float acc = atomicAdd(&g_acc, 0.f);  // final value (all adds done)
      out[0] = g_partial + acc;
    }
  }
}

extern "C" void kernel_launch(void* const* d_in, const int* in_sizes, int n_in,
                              void* d_out, int out_size, void* d_ws, size_t ws_size,
                              hipStream_t stream) {
  (void)in_sizes; (void)n_in; (void)out_size; (void)d_ws; (void)ws_size;
  lgq_fwd<<<dim3(1), dim3(256), 0, stream>>>(
      (const float*)d_in[0], (const float*)d_in[1], (const float*)d_in[2],
      (const float*)d_in[3], (const float*)d_in[4], (const float*)d_in[5],
      (const float*)d_in[6], (const float*)d_in[7], (const float*)d_in[8],
      (const float*)d_in[9], (const float*)d_in[10], (const float*)d_in[11],
      (const float*)d_in[12], (const float*)d_in[13], (const float*)d_in[14],
      (const float*)d_in[15], (const float*)d_in[16]);
  lgq_trace<<<dim3(256), dim3(256), 0, stream>>>((const float*)d_in[6],
                                                 (const float*)d_in[3],
                                                 (float*)d_out);
}